// Round 1
// baseline (2687.048 us; speedup 1.0000x reference)
//
#include <hip/hip_runtime.h>
#include <hip/hip_bf16.h>
#include <math.h>

#define BB 4
#define TT 512
#define HID 2048
#define NH 6
#define DK 256
#define DV 512
#define ROWS (BB*TT)          /* 2048 */
#define KEY_DIM (NH*DK)       /* 1536 */
#define VAL_DIM (NH*DV)       /* 3072 */

// ---------------------------------------------------------------------------
// Generic fp32 NT GEMM: C[m,n] = sum_k X[m*K+k] * W[n*K+k]
// 128x128 tile, BK=16, 256 threads, 8x8 per-thread microtile.
// M,N multiples of 128; K multiple of 16 (all true here).
// ---------------------------------------------------------------------------
__global__ __launch_bounds__(256) void gemm_nt_f32(
    const float* __restrict__ X, const float* __restrict__ W,
    float* __restrict__ C, int M, int N, int K)
{
    __shared__ float Xs[16][132];   // k-major, stride 132 keeps float4 16B-aligned
    __shared__ float Ws[16][132];
    const int tid = threadIdx.x;
    const int bm = blockIdx.y * 128;
    const int bn = blockIdx.x * 128;
    const int tx = tid & 15, ty = tid >> 4;
    float acc[8][8] = {{0.f}};

    for (int k0 = 0; k0 < K; k0 += 16) {
        #pragma unroll
        for (int s = 0; s < 2; ++s) {
            int f  = tid * 2 + s;        // 0..511
            int r  = f >> 2;             // row 0..127
            int c4 = (f & 3) * 4;        // k sub-offset
            float4 xv = *(const float4*)(X + (size_t)(bm + r) * K + k0 + c4);
            Xs[c4+0][r] = xv.x; Xs[c4+1][r] = xv.y; Xs[c4+2][r] = xv.z; Xs[c4+3][r] = xv.w;
            float4 wv = *(const float4*)(W + (size_t)(bn + r) * K + k0 + c4);
            Ws[c4+0][r] = wv.x; Ws[c4+1][r] = wv.y; Ws[c4+2][r] = wv.z; Ws[c4+3][r] = wv.w;
        }
        __syncthreads();
        #pragma unroll
        for (int kk = 0; kk < 16; ++kk) {
            float4 a0 = *(const float4*)&Xs[kk][ty*8];
            float4 a1 = *(const float4*)&Xs[kk][ty*8+4];
            float4 b0 = *(const float4*)&Ws[kk][tx*8];
            float4 b1 = *(const float4*)&Ws[kk][tx*8+4];
            float av[8] = {a0.x,a0.y,a0.z,a0.w,a1.x,a1.y,a1.z,a1.w};
            float bv[8] = {b0.x,b0.y,b0.z,b0.w,b1.x,b1.y,b1.z,b1.w};
            #pragma unroll
            for (int i = 0; i < 8; ++i)
                #pragma unroll
                for (int j = 0; j < 8; ++j)
                    acc[i][j] += av[i] * bv[j];
        }
        __syncthreads();
    }
    #pragma unroll
    for (int i = 0; i < 8; ++i) {
        float4 c0 = make_float4(acc[i][0], acc[i][1], acc[i][2], acc[i][3]);
        float4 c1 = make_float4(acc[i][4], acc[i][5], acc[i][6], acc[i][7]);
        size_t off = (size_t)(bm + ty*8 + i) * N + bn + tx*8;
        *(float4*)(C + off)     = c0;
        *(float4*)(C + off + 4) = c1;
    }
}

// ---------------------------------------------------------------------------
// Small projections a,b -> eg = exp(g), beta. grid (ROWS, 12), 64 threads.
// ---------------------------------------------------------------------------
__global__ __launch_bounds__(64) void proj_ab(
    const float* __restrict__ x, const float* __restrict__ Wa, const float* __restrict__ Wb,
    const float* __restrict__ A_log, const float* __restrict__ dt_bias,
    float* __restrict__ beta, float* __restrict__ eg)
{
    const int row = blockIdx.x;
    const int j   = blockIdx.y;           // 0..11
    const bool is_a = (j < NH);
    const int h = is_a ? j : j - NH;
    const float* wrow = (is_a ? Wa : Wb) + (size_t)h * HID;
    const float4* x4 = (const float4*)(x + (size_t)row * HID);
    const float4* w4 = (const float4*)wrow;
    float s = 0.f;
    for (int i = threadIdx.x; i < HID/4; i += 64) {
        float4 a = x4[i], b = w4[i];
        s += a.x*b.x + a.y*b.y + a.z*b.z + a.w*b.w;
    }
    #pragma unroll
    for (int off = 32; off >= 1; off >>= 1) s += __shfl_xor(s, off);
    if (threadIdx.x == 0) {
        if (is_a) {
            float a  = s + dt_bias[h];
            float sp = (a > 20.f) ? a : log1pf(expf(a));
            float g  = -expf(A_log[h]) * sp;
            eg[(size_t)row * NH + h] = expf(g);
        } else {
            beta[(size_t)row * NH + h] = 1.f / (1.f + expf(-s));
        }
    }
}

// ---------------------------------------------------------------------------
// Pointwise: silu(q,k), q-correction, l2norm (q scaled by K^-0.5), silu(v).
// In-place over the raw GEMM outputs. One block per (b,t) row.
// Note: l2norm(p) == l2norm(k) since p = k * sigmoid(decay[h]) (positive
// scalar per head) -> p never needs to be materialized for the scan.
// ---------------------------------------------------------------------------
__global__ __launch_bounds__(256) void prep_norm(
    float* __restrict__ q, float* __restrict__ k, float* __restrict__ v,
    const float* __restrict__ decay, const float* __restrict__ D)
{
    const int row  = blockIdx.x;
    const int tid  = threadIdx.x;
    const int lane = tid & 63, wid = tid >> 6;
    __shared__ float red[8];
    #pragma unroll 1
    for (int h = 0; h < NH; ++h) {
        size_t idx = (size_t)row * KEY_DIM + h * DK + tid;
        float qr = q[idx], kr = k[idx];
        float ksil = kr / (1.f + expf(-kr));
        float qsil = qr / (1.f + expf(-qr));
        float coef = D[h] * (1.f / (1.f + expf(-decay[h])));
        float qc = qsil - coef * ksil;
        float sq = qc*qc, sk = ksil*ksil;
        #pragma unroll
        for (int off = 32; off >= 1; off >>= 1) {
            sq += __shfl_xor(sq, off);
            sk += __shfl_xor(sk, off);
        }
        if (lane == 0) { red[wid] = sq; red[4+wid] = sk; }
        __syncthreads();
        sq = red[0]+red[1]+red[2]+red[3];
        sk = red[4]+red[5]+red[6]+red[7];
        __syncthreads();
        float qinv = 0.0625f / fmaxf(sqrtf(sq), 1e-12f);   // K^-0.5 = 1/16
        float kinv = 1.f     / fmaxf(sqrtf(sk), 1e-12f);
        q[idx] = qc   * qinv;
        k[idx] = ksil * kinv;
    }
    for (int jj = tid; jj < VAL_DIM; jj += 256) {
        size_t id2 = (size_t)row * VAL_DIM + jj;
        float xv = v[id2];
        v[id2] = xv / (1.f + expf(-xv));
    }
}

// ---------------------------------------------------------------------------
// Gated delta-rule scan. Block = (b, h, v-chunk of 64). 256 threads:
// kq = tid&3 (4-way split of K=256), vv = tid>>2 (64 v columns).
// State h[256,64] slice lives in registers: 64 floats/thread.
// k-reductions via shfl_xor over lane bits 0-1 (kq lives in-wave).
// o_t overwrites v_t in place (read-before-write within each step).
// ---------------------------------------------------------------------------
__global__ __launch_bounds__(256) void recurrence(
    const float* __restrict__ qn, const float* __restrict__ kn,
    float* __restrict__ vo, const float* __restrict__ beta, const float* __restrict__ eg)
{
    const int blk = blockIdx.x;
    const int vc = blk & 7;
    const int bh = blk >> 3;
    const int h = bh % NH, b = bh / NH;
    const int tid = threadIdx.x;
    const int kq = tid & 3;
    const int vv = tid >> 2;
    const int v_idx = vc * 64 + vv;
    __shared__ float qs[DK], ks[DK];
    float hS[64];
    #pragma unroll
    for (int i = 0; i < 64; ++i) hS[i] = 0.f;

    size_t rb = (size_t)(b * TT) * NH + h;     // (b,t=0,h) flat index
    float qr  = qn[rb * DK + tid];
    float kr  = kn[rb * DK + tid];
    float vt  = vo[rb * DV + v_idx];
    float bt  = beta[rb];
    float egt = eg[rb];

    for (int t = 0; t < TT; ++t) {
        qs[tid] = qr; ks[tid] = kr;
        __syncthreads();
        float vcur = vt, bcur = bt, egcur = egt;
        size_t rcur = rb;
        if (t + 1 < TT) {                       // prefetch next step
            rb += NH;
            qr  = qn[rb * DK + tid];
            kr  = kn[rb * DK + tid];
            vt  = vo[rb * DV + v_idx];
            bt  = beta[rb];
            egt = eg[rb];
        }
        const float4* k4 = (const float4*)&ks[kq * 64];
        const float4* q4 = (const float4*)&qs[kq * 64];
        float pred = 0.f;
        float kc[64];
        #pragma unroll
        for (int i = 0; i < 16; ++i) {
            float4 kv = k4[i];
            kc[4*i+0] = kv.x; kc[4*i+1] = kv.y; kc[4*i+2] = kv.z; kc[4*i+3] = kv.w;
            pred += hS[4*i+0]*kv.x + hS[4*i+1]*kv.y + hS[4*i+2]*kv.z + hS[4*i+3]*kv.w;
        }
        pred += __shfl_xor(pred, 1);
        pred += __shfl_xor(pred, 2);
        float vnew = (vcur - pred) * bcur;
        float oacc = 0.f;
        #pragma unroll
        for (int i = 0; i < 16; ++i) {
            float4 qv = q4[i];
            float h0 = hS[4*i+0]*egcur + kc[4*i+0]*vnew; hS[4*i+0] = h0; oacc += h0*qv.x;
            float h1 = hS[4*i+1]*egcur + kc[4*i+1]*vnew; hS[4*i+1] = h1; oacc += h1*qv.y;
            float h2 = hS[4*i+2]*egcur + kc[4*i+2]*vnew; hS[4*i+2] = h2; oacc += h2*qv.z;
            float h3 = hS[4*i+3]*egcur + kc[4*i+3]*vnew; hS[4*i+3] = h3; oacc += h3*qv.w;
        }
        oacc += __shfl_xor(oacc, 1);
        oacc += __shfl_xor(oacc, 2);
        if (kq == 0) vo[rcur * DV + v_idx] = oacc;
        __syncthreads();
    }
}

// ---------------------------------------------------------------------------
// Gated RMSNorm epilogue (in place over o). One block per (b,t) row.
// ---------------------------------------------------------------------------
__global__ __launch_bounds__(256) void epilogue(
    float* __restrict__ o, const float* __restrict__ gate,
    const float* __restrict__ wnorm)
{
    const int row  = blockIdx.x;
    const int tid  = threadIdx.x;
    const int lane = tid & 63, wid = tid >> 6;
    __shared__ float red[4];
    #pragma unroll 1
    for (int h = 0; h < NH; ++h) {
        size_t base = ((size_t)row * NH + h) * DV;
        float o0 = o[base + tid], o1 = o[base + 256 + tid];
        float ss = o0*o0 + o1*o1;
        #pragma unroll
        for (int off = 32; off >= 1; off >>= 1) ss += __shfl_xor(ss, off);
        if (lane == 0) red[wid] = ss;
        __syncthreads();
        ss = red[0] + red[1] + red[2] + red[3];
        __syncthreads();
        float irms = rsqrtf(ss * (1.f / DV) + 1e-6f);
        size_t gbase = (size_t)row * VAL_DIM + h * DV;
        float g0 = gate[gbase + tid], g1 = gate[gbase + 256 + tid];
        o[base + tid]       = o0 * irms * wnorm[tid]       * (1.f / (1.f + expf(-g0)));
        o[base + 256 + tid] = o1 * irms * wnorm[256 + tid] * (1.f / (1.f + expf(-g1)));
    }
}

// ---------------------------------------------------------------------------
extern "C" void kernel_launch(void* const* d_in, const int* in_sizes, int n_in,
                              void* d_out, int out_size, void* d_ws, size_t ws_size,
                              hipStream_t stream)
{
    const float* x     = (const float*)d_in[0];
    const float* Wq    = (const float*)d_in[1];
    const float* Wk    = (const float*)d_in[2];
    const float* Wv    = (const float*)d_in[3];
    const float* Wa    = (const float*)d_in[4];
    const float* Wb    = (const float*)d_in[5];
    const float* decay = (const float*)d_in[6];
    const float* Dp    = (const float*)d_in[7];
    const float* A_log = (const float*)d_in[8];
    const float* dtb   = (const float*)d_in[9];
    const float* Wg    = (const float*)d_in[10];
    const float* Wo    = (const float*)d_in[11];
    const float* onw   = (const float*)d_in[12];
    float* out = (float*)d_out;

    float* ws   = (float*)d_ws;
    float* q    = ws;                                  // ROWS*KEY_DIM
    float* k    = q    + (size_t)ROWS * KEY_DIM;       // ROWS*KEY_DIM
    float* v    = k    + (size_t)ROWS * KEY_DIM;       // ROWS*VAL_DIM (v -> o -> gated o)
    float* gate = v    + (size_t)ROWS * VAL_DIM;       // ROWS*VAL_DIM
    float* beta = gate + (size_t)ROWS * VAL_DIM;       // ROWS*NH
    float* eg   = beta + (size_t)ROWS * NH;            // ROWS*NH
    // total: 18,898,944 floats = 75.6 MB

    dim3 blk(256);
    gemm_nt_f32<<<dim3(KEY_DIM/128, ROWS/128), blk, 0, stream>>>(x, Wq, q,    ROWS, KEY_DIM, HID);
    gemm_nt_f32<<<dim3(KEY_DIM/128, ROWS/128), blk, 0, stream>>>(x, Wk, k,    ROWS, KEY_DIM, HID);
    gemm_nt_f32<<<dim3(VAL_DIM/128, ROWS/128), blk, 0, stream>>>(x, Wv, v,    ROWS, VAL_DIM, HID);
    gemm_nt_f32<<<dim3(VAL_DIM/128, ROWS/128), blk, 0, stream>>>(x, Wg, gate, ROWS, VAL_DIM, HID);
    proj_ab<<<dim3(ROWS, 12), dim3(64), 0, stream>>>(x, Wa, Wb, A_log, dtb, beta, eg);
    prep_norm<<<dim3(ROWS), blk, 0, stream>>>(q, k, v, decay, Dp);
    recurrence<<<dim3(BB*NH*8), blk, 0, stream>>>(q, k, v, beta, eg);
    epilogue<<<dim3(ROWS), blk, 0, stream>>>(v, gate, onw);
    gemm_nt_f32<<<dim3(HID/128, ROWS/128), blk, 0, stream>>>(v, Wo, out, ROWS, HID, VAL_DIM);
}

// Round 2
// 1086.284 us; speedup vs baseline: 2.4736x; 2.4736x over previous
//
#include <hip/hip_runtime.h>
#include <hip/hip_bf16.h>
#include <math.h>

#define BB 4
#define TT 512
#define HID 2048
#define NH 6
#define DK 256
#define DV 512
#define ROWS (BB*TT)          /* 2048 */
#define KEY_DIM (NH*DK)       /* 1536 */
#define VAL_DIM (NH*DV)       /* 3072 */

typedef __bf16 bf16x8 __attribute__((ext_vector_type(8)));
typedef float  f32x4  __attribute__((ext_vector_type(4)));

// ---------------------------------------------------------------------------
// fp32 -> bf16 cast (RNE), vectorized float4 -> ushort4, grid-stride.
// ---------------------------------------------------------------------------
__device__ __forceinline__ unsigned short f2bf(float f) {
    unsigned int u = __float_as_uint(f);
    u = (u + 0x7FFFu + ((u >> 16) & 1u)) >> 16;
    return (unsigned short)u;
}

__global__ __launch_bounds__(256) void cast_f32_bf16(
    const float* __restrict__ src, unsigned short* __restrict__ dst, int n4)
{
    int stride = gridDim.x * 256;
    for (int i = blockIdx.x * 256 + threadIdx.x; i < n4; i += stride) {
        float4 v = ((const float4*)src)[i];
        ushort4 o;
        o.x = f2bf(v.x); o.y = f2bf(v.y); o.z = f2bf(v.z); o.w = f2bf(v.w);
        ((ushort4*)dst)[i] = o;
    }
}

// ---------------------------------------------------------------------------
// bf16 NT GEMM: C[m,n] = sum_k A[m*K+k]*B[n*K+k], fp32 accumulate/output.
// 128x128 tile, BK=32, 256 threads = 4 waves in 2x2; 4x4 mfma 16x16x32 each.
// A,B row-major bf16 (ushort), K % 32 == 0, M,N % 128 == 0.
// ---------------------------------------------------------------------------
__global__ __launch_bounds__(256) void gemm_nt_bf16(
    const unsigned short* __restrict__ A, const unsigned short* __restrict__ B,
    float* __restrict__ C, int M, int N, int K)
{
    __shared__ __align__(16) unsigned short As[128 * 32];
    __shared__ __align__(16) unsigned short Bs[128 * 32];
    const int tid  = threadIdx.x;
    const int lane = tid & 63;
    const int wave = tid >> 6;
    const int bm = blockIdx.y * 128;
    const int bn = blockIdx.x * 128;
    const int wr = (wave >> 1) * 64;     // wave row offset in tile
    const int wc = (wave & 1) * 64;      // wave col offset in tile
    const int fr = lane & 15;            // fragment row/col within 16
    const int kg = lane >> 4;            // k-group (0..3) * 8

    f32x4 acc[4][4] = {};

    for (int k0 = 0; k0 < K; k0 += 32) {
        // stage A,B tiles (128x32 bf16 = 8KB each) via global_load_lds x16B
        #pragma unroll
        for (int s = 0; s < 2; ++s) {
            int e  = s * 256 + tid;          // 0..511 16B-chunks
            int r  = e >> 2;                 // row 0..127
            int c8 = (e & 3) * 8;            // bf16 col offset
            const unsigned short* ga = A + (size_t)(bm + r) * K + k0 + c8;
            const unsigned short* gb = B + (size_t)(bn + r) * K + k0 + c8;
            unsigned short* la = As + (size_t)(s * 256 + wave * 64) * 8;  // wave-uniform
            unsigned short* lb = Bs + (size_t)(s * 256 + wave * 64) * 8;
            __builtin_amdgcn_global_load_lds(
                (const __attribute__((address_space(1))) void*)ga,
                (__attribute__((address_space(3))) void*)la, 16, 0, 0);
            __builtin_amdgcn_global_load_lds(
                (const __attribute__((address_space(1))) void*)gb,
                (__attribute__((address_space(3))) void*)lb, 16, 0, 0);
        }
        __syncthreads();

        bf16x8 a[4], b[4];
        #pragma unroll
        for (int f = 0; f < 4; ++f) {
            a[f] = *(const bf16x8*)&As[(wr + f * 16 + fr) * 32 + kg * 8];
            b[f] = *(const bf16x8*)&Bs[(wc + f * 16 + fr) * 32 + kg * 8];
        }
        #pragma unroll
        for (int fm = 0; fm < 4; ++fm)
            #pragma unroll
            for (int fn = 0; fn < 4; ++fn)
                acc[fm][fn] = __builtin_amdgcn_mfma_f32_16x16x32_bf16(
                    a[fm], b[fn], acc[fm][fn], 0, 0, 0);
        __syncthreads();
    }

    // store: lane's acc[fm][fn][i] -> C[bm+wr+fm*16 + kg*4+i][bn+wc+fn*16 + fr]
    #pragma unroll
    for (int fm = 0; fm < 4; ++fm)
        #pragma unroll
        for (int fn = 0; fn < 4; ++fn) {
            int col = bn + wc + fn * 16 + fr;
            #pragma unroll
            for (int i = 0; i < 4; ++i) {
                int row = bm + wr + fm * 16 + kg * 4 + i;
                C[(size_t)row * N + col] = acc[fm][fn][i];
            }
        }
}

// ---------------------------------------------------------------------------
// Small projections a,b -> eg = exp(g), beta. grid (ROWS, 12), 64 threads.
// ---------------------------------------------------------------------------
__global__ __launch_bounds__(64) void proj_ab(
    const float* __restrict__ x, const float* __restrict__ Wa, const float* __restrict__ Wb,
    const float* __restrict__ A_log, const float* __restrict__ dt_bias,
    float* __restrict__ beta, float* __restrict__ eg)
{
    const int row = blockIdx.x;
    const int j   = blockIdx.y;
    const bool is_a = (j < NH);
    const int h = is_a ? j : j - NH;
    const float* wrow = (is_a ? Wa : Wb) + (size_t)h * HID;
    const float4* x4 = (const float4*)(x + (size_t)row * HID);
    const float4* w4 = (const float4*)wrow;
    float s = 0.f;
    for (int i = threadIdx.x; i < HID/4; i += 64) {
        float4 a = x4[i], b = w4[i];
        s += a.x*b.x + a.y*b.y + a.z*b.z + a.w*b.w;
    }
    #pragma unroll
    for (int off = 32; off >= 1; off >>= 1) s += __shfl_xor(s, off);
    if (threadIdx.x == 0) {
        if (is_a) {
            float a  = s + dt_bias[h];
            float sp = (a > 20.f) ? a : log1pf(expf(a));
            float g  = -expf(A_log[h]) * sp;
            eg[(size_t)row * NH + h] = expf(g);
        } else {
            beta[(size_t)row * NH + h] = 1.f / (1.f + expf(-s));
        }
    }
}

// ---------------------------------------------------------------------------
// Pointwise: silu(q,k), q-correction, l2norm (q scaled K^-0.5), silu(v).
// l2norm(p)==l2norm(k) since p = k*sigmoid(decay[h]) (positive scalar/head).
// ---------------------------------------------------------------------------
__global__ __launch_bounds__(256) void prep_norm(
    float* __restrict__ q, float* __restrict__ k, float* __restrict__ v,
    const float* __restrict__ decay, const float* __restrict__ D)
{
    const int row  = blockIdx.x;
    const int tid  = threadIdx.x;
    const int lane = tid & 63, wid = tid >> 6;
    __shared__ float red[8];
    #pragma unroll 1
    for (int h = 0; h < NH; ++h) {
        size_t idx = (size_t)row * KEY_DIM + h * DK + tid;
        float qr = q[idx], kr = k[idx];
        float ksil = kr / (1.f + expf(-kr));
        float qsil = qr / (1.f + expf(-qr));
        float coef = D[h] * (1.f / (1.f + expf(-decay[h])));
        float qc = qsil - coef * ksil;
        float sq = qc*qc, sk = ksil*ksil;
        #pragma unroll
        for (int off = 32; off >= 1; off >>= 1) {
            sq += __shfl_xor(sq, off);
            sk += __shfl_xor(sk, off);
        }
        if (lane == 0) { red[wid] = sq; red[4+wid] = sk; }
        __syncthreads();
        sq = red[0]+red[1]+red[2]+red[3];
        sk = red[4]+red[5]+red[6]+red[7];
        __syncthreads();
        float qinv = 0.0625f / fmaxf(sqrtf(sq), 1e-12f);
        float kinv = 1.f     / fmaxf(sqrtf(sk), 1e-12f);
        q[idx] = qc   * qinv;
        k[idx] = ksil * kinv;
    }
    for (int jj = tid; jj < VAL_DIM; jj += 256) {
        size_t id2 = (size_t)row * VAL_DIM + jj;
        float xv = v[id2];
        v[id2] = xv / (1.f + expf(-xv));
    }
}

// ---------------------------------------------------------------------------
// Gated delta-rule scan, wave-local. One wave handles (b,h, 4 v-columns):
// lane: kq = lane&15 (16-way K split, 16 state floats), vv = lane>>4.
// Reductions over kq via 4x shfl_xor (lanes bits 0-3). No LDS, no barriers.
// Next-step q/k/v/beta/eg prefetched into registers during compute.
// ---------------------------------------------------------------------------
__global__ __launch_bounds__(256) void recurrence(
    const float* __restrict__ qn, const float* __restrict__ kn,
    float* __restrict__ vo, const float* __restrict__ beta, const float* __restrict__ eg)
{
    const int gw   = (blockIdx.x * 256 + threadIdx.x) >> 6;  // 0..3071
    const int lane = threadIdx.x & 63;
    const int kq   = lane & 15;
    const int vv   = lane >> 4;
    const int vc   = gw & 127;          // 128 groups of 4 v-columns
    const int bh   = gw >> 7;           // 0..23
    const int h = bh % NH, b = bh / NH;
    const int v_idx = vc * 4 + vv;

    float hS[16];
    #pragma unroll
    for (int i = 0; i < 16; ++i) hS[i] = 0.f;

    size_t rb = (size_t)(b * TT) * NH + h;
    const float* qp = qn + rb * DK + kq * 16;
    const float* kp = kn + rb * DK + kq * 16;
    float4 qf[4], kf[4];
    #pragma unroll
    for (int i = 0; i < 4; ++i) { qf[i] = ((const float4*)qp)[i]; kf[i] = ((const float4*)kp)[i]; }
    float vt  = vo[rb * DV + v_idx];
    float bt  = beta[rb];
    float egt = eg[rb];

    for (int t = 0; t < TT; ++t) {
        float4 qc[4], kc[4];
        #pragma unroll
        for (int i = 0; i < 4; ++i) { qc[i] = qf[i]; kc[i] = kf[i]; }
        float vcur = vt, bcur = bt, ecur = egt;
        size_t rcur = rb;
        if (t + 1 < TT) {
            rb += NH;
            const float* qn2 = qn + rb * DK + kq * 16;
            const float* kn2 = kn + rb * DK + kq * 16;
            #pragma unroll
            for (int i = 0; i < 4; ++i) { qf[i] = ((const float4*)qn2)[i]; kf[i] = ((const float4*)kn2)[i]; }
            vt  = vo[rb * DV + v_idx];
            bt  = beta[rb];
            egt = eg[rb];
        }

        float pred = 0.f;
        #pragma unroll
        for (int i = 0; i < 4; ++i)
            pred += hS[4*i+0]*kc[i].x + hS[4*i+1]*kc[i].y + hS[4*i+2]*kc[i].z + hS[4*i+3]*kc[i].w;
        pred += __shfl_xor(pred, 1);
        pred += __shfl_xor(pred, 2);
        pred += __shfl_xor(pred, 4);
        pred += __shfl_xor(pred, 8);

        float vnew = (vcur - pred) * bcur;
        float oacc = 0.f;
        #pragma unroll
        for (int i = 0; i < 4; ++i) {
            float h0 = hS[4*i+0]*ecur + kc[i].x*vnew; hS[4*i+0] = h0; oacc += h0*qc[i].x;
            float h1 = hS[4*i+1]*ecur + kc[i].y*vnew; hS[4*i+1] = h1; oacc += h1*qc[i].y;
            float h2 = hS[4*i+2]*ecur + kc[i].z*vnew; hS[4*i+2] = h2; oacc += h2*qc[i].z;
            float h3 = hS[4*i+3]*ecur + kc[i].w*vnew; hS[4*i+3] = h3; oacc += h3*qc[i].w;
        }
        oacc += __shfl_xor(oacc, 1);
        oacc += __shfl_xor(oacc, 2);
        oacc += __shfl_xor(oacc, 4);
        oacc += __shfl_xor(oacc, 8);
        if (kq == 0) vo[rcur * DV + v_idx] = oacc;
    }
}

// ---------------------------------------------------------------------------
// Gated RMSNorm epilogue (in place over o).
// ---------------------------------------------------------------------------
__global__ __launch_bounds__(256) void epilogue(
    float* __restrict__ o, const float* __restrict__ gate,
    const float* __restrict__ wnorm)
{
    const int row  = blockIdx.x;
    const int tid  = threadIdx.x;
    const int lane = tid & 63, wid = tid >> 6;
    __shared__ float red[4];
    #pragma unroll 1
    for (int h = 0; h < NH; ++h) {
        size_t base = ((size_t)row * NH + h) * DV;
        float o0 = o[base + tid], o1 = o[base + 256 + tid];
        float ss = o0*o0 + o1*o1;
        #pragma unroll
        for (int off = 32; off >= 1; off >>= 1) ss += __shfl_xor(ss, off);
        if (lane == 0) red[wid] = ss;
        __syncthreads();
        ss = red[0] + red[1] + red[2] + red[3];
        __syncthreads();
        float irms = rsqrtf(ss * (1.f / DV) + 1e-6f);
        size_t gbase = (size_t)row * VAL_DIM + h * DV;
        float g0 = gate[gbase + tid], g1 = gate[gbase + 256 + tid];
        o[base + tid]       = o0 * irms * wnorm[tid]       * (1.f / (1.f + expf(-g0)));
        o[base + 256 + tid] = o1 * irms * wnorm[256 + tid] * (1.f / (1.f + expf(-g1)));
    }
}

// ---------------------------------------------------------------------------
extern "C" void kernel_launch(void* const* d_in, const int* in_sizes, int n_in,
                              void* d_out, int out_size, void* d_ws, size_t ws_size,
                              hipStream_t stream)
{
    const float* x     = (const float*)d_in[0];
    const float* Wq    = (const float*)d_in[1];
    const float* Wk    = (const float*)d_in[2];
    const float* Wv    = (const float*)d_in[3];
    const float* Wa    = (const float*)d_in[4];
    const float* Wb    = (const float*)d_in[5];
    const float* decay = (const float*)d_in[6];
    const float* Dp    = (const float*)d_in[7];
    const float* A_log = (const float*)d_in[8];
    const float* dtb   = (const float*)d_in[9];
    const float* Wg    = (const float*)d_in[10];
    const float* Wo    = (const float*)d_in[11];
    const float* onw   = (const float*)d_in[12];
    float* out = (float*)d_out;

    float* ws   = (float*)d_ws;
    float* q    = ws;                                  // ROWS*KEY_DIM
    float* k    = q    + (size_t)ROWS * KEY_DIM;
    float* v    = k    + (size_t)ROWS * KEY_DIM;       // v -> o -> gated o
    float* gate = v    + (size_t)ROWS * VAL_DIM;
    float* beta = gate + (size_t)ROWS * VAL_DIM;       // ROWS*NH
    float* eg   = beta + (size_t)ROWS * NH;            // ROWS*NH
    unsigned short* bf = (unsigned short*)(eg + (size_t)ROWS * NH);  // 16B-aligned
    // phase 1 bf16 buffers
    unsigned short* xb  = bf;                                   // ROWS*HID
    unsigned short* Wqb = xb  + (size_t)ROWS * HID;             // KEY_DIM*HID
    unsigned short* Wkb = Wqb + (size_t)KEY_DIM * HID;
    unsigned short* Wvb = Wkb + (size_t)KEY_DIM * HID;          // VAL_DIM*HID
    unsigned short* Wgb = Wvb + (size_t)VAL_DIM * HID;
    // phase 2 aliases phase 1 (xb region dead by then)
    unsigned short* ob  = bf;                                   // ROWS*VAL_DIM
    unsigned short* Wob = ob + (size_t)ROWS * VAL_DIM;          // HID*VAL_DIM
    // peak ws: 75.6 MB fp32 + 46.2 MB bf16 = ~122 MB

    dim3 blk(256);
    auto cblocks = [](size_t n) { size_t b = (n / 4 + 255) / 256; return (int)(b > 4096 ? 4096 : b); };

    // casts
    cast_f32_bf16<<<cblocks((size_t)ROWS*HID),    blk, 0, stream>>>(x,  xb,  ROWS*HID/4);
    cast_f32_bf16<<<cblocks((size_t)KEY_DIM*HID), blk, 0, stream>>>(Wq, Wqb, KEY_DIM*HID/4);
    cast_f32_bf16<<<cblocks((size_t)KEY_DIM*HID), blk, 0, stream>>>(Wk, Wkb, KEY_DIM*HID/4);
    cast_f32_bf16<<<cblocks((size_t)VAL_DIM*HID), blk, 0, stream>>>(Wv, Wvb, VAL_DIM*HID/4);
    cast_f32_bf16<<<cblocks((size_t)VAL_DIM*HID), blk, 0, stream>>>(Wg, Wgb, VAL_DIM*HID/4);

    // projections (bf16 MFMA)
    gemm_nt_bf16<<<dim3(KEY_DIM/128, ROWS/128), blk, 0, stream>>>(xb, Wqb, q,    ROWS, KEY_DIM, HID);
    gemm_nt_bf16<<<dim3(KEY_DIM/128, ROWS/128), blk, 0, stream>>>(xb, Wkb, k,    ROWS, KEY_DIM, HID);
    gemm_nt_bf16<<<dim3(VAL_DIM/128, ROWS/128), blk, 0, stream>>>(xb, Wvb, v,    ROWS, VAL_DIM, HID);
    gemm_nt_bf16<<<dim3(VAL_DIM/128, ROWS/128), blk, 0, stream>>>(xb, Wgb, gate, ROWS, VAL_DIM, HID);
    proj_ab<<<dim3(ROWS, 12), dim3(64), 0, stream>>>(x, Wa, Wb, A_log, dtb, beta, eg);

    prep_norm<<<dim3(ROWS), blk, 0, stream>>>(q, k, v, decay, Dp);
    recurrence<<<dim3(BB*NH*128/4), blk, 0, stream>>>(q, k, v, beta, eg);   // 768 blocks
    epilogue<<<dim3(ROWS), blk, 0, stream>>>(v, gate, onw);

    // output projection (bf16 MFMA)
    cast_f32_bf16<<<cblocks((size_t)ROWS*VAL_DIM), blk, 0, stream>>>(v,  ob,  ROWS*VAL_DIM/4);
    cast_f32_bf16<<<cblocks((size_t)HID*VAL_DIM),  blk, 0, stream>>>(Wo, Wob, HID*VAL_DIM/4);
    gemm_nt_bf16<<<dim3(HID/128, ROWS/128), blk, 0, stream>>>(ob, Wob, out, ROWS, HID, VAL_DIM);
}

// Round 3
// 1070.965 us; speedup vs baseline: 2.5090x; 1.0143x over previous
//
#include <hip/hip_runtime.h>
#include <hip/hip_bf16.h>
#include <math.h>

#define BB 4
#define TT 512
#define HID 2048
#define NH 6
#define DK 256
#define DV 512
#define ROWS (BB*TT)          /* 2048 */
#define KEY_DIM (NH*DK)       /* 1536 */
#define VAL_DIM (NH*DV)       /* 3072 */

typedef __bf16 bf16x8 __attribute__((ext_vector_type(8)));
typedef float  f32x4  __attribute__((ext_vector_type(4)));

// ---------------------------------------------------------------------------
// fp32 -> bf16 cast (RNE), vectorized float4 -> ushort4, grid-stride.
// ---------------------------------------------------------------------------
__device__ __forceinline__ unsigned short f2bf(float f) {
    unsigned int u = __float_as_uint(f);
    u = (u + 0x7FFFu + ((u >> 16) & 1u)) >> 16;
    return (unsigned short)u;
}

__global__ __launch_bounds__(256) void cast_f32_bf16(
    const float* __restrict__ src, unsigned short* __restrict__ dst, int n4)
{
    int stride = gridDim.x * 256;
    for (int i = blockIdx.x * 256 + threadIdx.x; i < n4; i += stride) {
        float4 v = ((const float4*)src)[i];
        ushort4 o;
        o.x = f2bf(v.x); o.y = f2bf(v.y); o.z = f2bf(v.z); o.w = f2bf(v.w);
        ((ushort4*)dst)[i] = o;
    }
}

// ---------------------------------------------------------------------------
// bf16 NT GEMM: C[m,n] = sum_k A[m*K+k]*B[n*K+k], fp32 accumulate/output.
// 128x128 tile, BK=32, 256 threads = 4 waves in 2x2; 4x4 mfma 16x16x32 each.
// ---------------------------------------------------------------------------
__global__ __launch_bounds__(256) void gemm_nt_bf16(
    const unsigned short* __restrict__ A, const unsigned short* __restrict__ B,
    float* __restrict__ C, int M, int N, int K)
{
    __shared__ __align__(16) unsigned short As[128 * 32];
    __shared__ __align__(16) unsigned short Bs[128 * 32];
    const int tid  = threadIdx.x;
    const int lane = tid & 63;
    const int wave = tid >> 6;
    const int bm = blockIdx.y * 128;
    const int bn = blockIdx.x * 128;
    const int wr = (wave >> 1) * 64;
    const int wc = (wave & 1) * 64;
    const int fr = lane & 15;
    const int kg = lane >> 4;

    f32x4 acc[4][4] = {};

    for (int k0 = 0; k0 < K; k0 += 32) {
        #pragma unroll
        for (int s = 0; s < 2; ++s) {
            int e  = s * 256 + tid;
            int r  = e >> 2;
            int c8 = (e & 3) * 8;
            const unsigned short* ga = A + (size_t)(bm + r) * K + k0 + c8;
            const unsigned short* gb = B + (size_t)(bn + r) * K + k0 + c8;
            unsigned short* la = As + (size_t)(s * 256 + wave * 64) * 8;
            unsigned short* lb = Bs + (size_t)(s * 256 + wave * 64) * 8;
            __builtin_amdgcn_global_load_lds(
                (const __attribute__((address_space(1))) void*)ga,
                (__attribute__((address_space(3))) void*)la, 16, 0, 0);
            __builtin_amdgcn_global_load_lds(
                (const __attribute__((address_space(1))) void*)gb,
                (__attribute__((address_space(3))) void*)lb, 16, 0, 0);
        }
        __syncthreads();

        bf16x8 a[4], b[4];
        #pragma unroll
        for (int f = 0; f < 4; ++f) {
            a[f] = *(const bf16x8*)&As[(wr + f * 16 + fr) * 32 + kg * 8];
            b[f] = *(const bf16x8*)&Bs[(wc + f * 16 + fr) * 32 + kg * 8];
        }
        #pragma unroll
        for (int fm = 0; fm < 4; ++fm)
            #pragma unroll
            for (int fn = 0; fn < 4; ++fn)
                acc[fm][fn] = __builtin_amdgcn_mfma_f32_16x16x32_bf16(
                    a[fm], b[fn], acc[fm][fn], 0, 0, 0);
        __syncthreads();
    }

    #pragma unroll
    for (int fm = 0; fm < 4; ++fm)
        #pragma unroll
        for (int fn = 0; fn < 4; ++fn) {
            int col = bn + wc + fn * 16 + fr;
            #pragma unroll
            for (int i = 0; i < 4; ++i) {
                int row = bm + wr + fm * 16 + kg * 4 + i;
                C[(size_t)row * N + col] = acc[fm][fn][i];
            }
        }
}

// ---------------------------------------------------------------------------
// Small projections a,b -> eg = exp(g), beta. grid (ROWS, 12), 64 threads.
// ---------------------------------------------------------------------------
__global__ __launch_bounds__(64) void proj_ab(
    const float* __restrict__ x, const float* __restrict__ Wa, const float* __restrict__ Wb,
    const float* __restrict__ A_log, const float* __restrict__ dt_bias,
    float* __restrict__ beta, float* __restrict__ eg)
{
    const int row = blockIdx.x;
    const int j   = blockIdx.y;
    const bool is_a = (j < NH);
    const int h = is_a ? j : j - NH;
    const float* wrow = (is_a ? Wa : Wb) + (size_t)h * HID;
    const float4* x4 = (const float4*)(x + (size_t)row * HID);
    const float4* w4 = (const float4*)wrow;
    float s = 0.f;
    for (int i = threadIdx.x; i < HID/4; i += 64) {
        float4 a = x4[i], b = w4[i];
        s += a.x*b.x + a.y*b.y + a.z*b.z + a.w*b.w;
    }
    #pragma unroll
    for (int off = 32; off >= 1; off >>= 1) s += __shfl_xor(s, off);
    if (threadIdx.x == 0) {
        if (is_a) {
            float a  = s + dt_bias[h];
            float sp = (a > 20.f) ? a : log1pf(expf(a));
            float g  = -expf(A_log[h]) * sp;
            eg[(size_t)row * NH + h] = expf(g);
        } else {
            beta[(size_t)row * NH + h] = 1.f / (1.f + expf(-s));
        }
    }
}

// ---------------------------------------------------------------------------
// Pointwise: silu(q,k), q-correction, l2norm (q scaled K^-0.5), silu(v).
// l2norm(p)==l2norm(k) since p = k*sigmoid(decay[h]) (positive scalar/head).
// ---------------------------------------------------------------------------
__global__ __launch_bounds__(256) void prep_norm(
    float* __restrict__ q, float* __restrict__ k, float* __restrict__ v,
    const float* __restrict__ decay, const float* __restrict__ D)
{
    const int row  = blockIdx.x;
    const int tid  = threadIdx.x;
    const int lane = tid & 63, wid = tid >> 6;
    __shared__ float red[8];
    #pragma unroll 1
    for (int h = 0; h < NH; ++h) {
        size_t idx = (size_t)row * KEY_DIM + h * DK + tid;
        float qr = q[idx], kr = k[idx];
        float ksil = kr / (1.f + expf(-kr));
        float qsil = qr / (1.f + expf(-qr));
        float coef = D[h] * (1.f / (1.f + expf(-decay[h])));
        float qc = qsil - coef * ksil;
        float sq = qc*qc, sk = ksil*ksil;
        #pragma unroll
        for (int off = 32; off >= 1; off >>= 1) {
            sq += __shfl_xor(sq, off);
            sk += __shfl_xor(sk, off);
        }
        if (lane == 0) { red[wid] = sq; red[4+wid] = sk; }
        __syncthreads();
        sq = red[0]+red[1]+red[2]+red[3];
        sk = red[4]+red[5]+red[6]+red[7];
        __syncthreads();
        float qinv = 0.0625f / fmaxf(sqrtf(sq), 1e-12f);
        float kinv = 1.f     / fmaxf(sqrtf(sk), 1e-12f);
        q[idx] = qc   * qinv;
        k[idx] = ksil * kinv;
    }
    for (int jj = tid; jj < VAL_DIM; jj += 256) {
        size_t id2 = (size_t)row * VAL_DIM + jj;
        float xv = v[id2];
        v[id2] = xv / (1.f + expf(-xv));
    }
}

// ---------------------------------------------------------------------------
// Gated delta-rule scan, wave-local. One wave = (b,h, 4 v-columns):
// kq = lane&15 (16-way K split, 16 state floats/lane), vv = lane>>4.
// Reductions over kq via 4-stage DPP butterfly (VALU-latency, no LDS pipe):
//   quad_perm xor1 -> quad_perm xor2 -> row_half_mirror -> row_mirror.
// t-loop unrolled by 2 with static A/B buffers (no reg copies, 1-step
// prefetch distance). Prefetch over-reads <=2 rows past the q/k/v buffers —
// lands in the adjacent ws buffer (valid memory), values never consumed.
// ---------------------------------------------------------------------------
#define DPP_ADD(x, ctrl) \
    ((x) + __int_as_float(__builtin_amdgcn_mov_dpp(__float_as_int(x), (ctrl), 0xF, 0xF, true)))

#define R16(x) do { \
    x = DPP_ADD(x, 0xB1);  /* quad_perm [1,0,3,2]  = xor 1 */ \
    x = DPP_ADD(x, 0x4E);  /* quad_perm [2,3,0,1]  = xor 2 */ \
    x = DPP_ADD(x, 0x141); /* row_half_mirror      = xor 4 (quads uniform) */ \
    x = DPP_ADD(x, 0x140); /* row_mirror           = xor 8 (octs uniform) */ \
} while (0)

__global__ __launch_bounds__(256) void recurrence(
    const float* __restrict__ qn, const float* __restrict__ kn,
    float* __restrict__ vo, const float* __restrict__ beta, const float* __restrict__ eg)
{
    const int gw   = (blockIdx.x * 256 + threadIdx.x) >> 6;  // 0..3071
    const int lane = threadIdx.x & 63;
    const int kq   = lane & 15;
    const int vv   = lane >> 4;
    const int vc   = gw & 127;
    const int bh   = gw >> 7;
    const int h = bh % NH, b = bh / NH;
    const int v_idx = vc * 4 + vv;

    float hS[16];
    #pragma unroll
    for (int i = 0; i < 16; ++i) hS[i] = 0.f;

    const size_t rb = (size_t)(b * TT) * NH + h;
    const float* qbase = qn + rb * DK + kq * 16;
    const float* kbase = kn + rb * DK + kq * 16;
    const float* vbase = vo + rb * DV + v_idx;
    const float* bbase = beta + rb;
    const float* ebase = eg + rb;
    float*       obase = vo + rb * DV + v_idx;
    const int strK = NH * DK;   // 1536: t -> t+1 stride in floats
    const int strV = NH * DV;   // 3072
    const int strS = NH;

#define LOADSTEP(Q, Kk, Vv, Bb, Ee, tt) do { \
    const float4* q4_ = (const float4*)(qbase + (size_t)(tt) * strK); \
    const float4* k4_ = (const float4*)(kbase + (size_t)(tt) * strK); \
    Q[0] = q4_[0]; Q[1] = q4_[1]; Q[2] = q4_[2]; Q[3] = q4_[3]; \
    Kk[0] = k4_[0]; Kk[1] = k4_[1]; Kk[2] = k4_[2]; Kk[3] = k4_[3]; \
    Vv = vbase[(size_t)(tt) * strV]; \
    Bb = bbase[(size_t)(tt) * strS]; \
    Ee = ebase[(size_t)(tt) * strS]; \
} while (0)

#define STEP(Q, Kk, Vv, Bb, Ee, tt) do { \
    float p0 = hS[ 0]*Kk[0].x + hS[ 1]*Kk[0].y + hS[ 2]*Kk[0].z + hS[ 3]*Kk[0].w; \
    float p1 = hS[ 4]*Kk[1].x + hS[ 5]*Kk[1].y + hS[ 6]*Kk[1].z + hS[ 7]*Kk[1].w; \
    float p2 = hS[ 8]*Kk[2].x + hS[ 9]*Kk[2].y + hS[10]*Kk[2].z + hS[11]*Kk[2].w; \
    float p3 = hS[12]*Kk[3].x + hS[13]*Kk[3].y + hS[14]*Kk[3].z + hS[15]*Kk[3].w; \
    float pr = (p0 + p1) + (p2 + p3); \
    R16(pr); \
    float vnew = (Vv - pr) * Bb; \
    float oa = 0.f; \
    _Pragma("unroll") \
    for (int i = 0; i < 4; ++i) { \
        float h0 = hS[4*i+0]*Ee + Kk[i].x*vnew; hS[4*i+0] = h0; oa += h0*Q[i].x; \
        float h1 = hS[4*i+1]*Ee + Kk[i].y*vnew; hS[4*i+1] = h1; oa += h1*Q[i].y; \
        float h2 = hS[4*i+2]*Ee + Kk[i].z*vnew; hS[4*i+2] = h2; oa += h2*Q[i].z; \
        float h3 = hS[4*i+3]*Ee + Kk[i].w*vnew; hS[4*i+3] = h3; oa += h3*Q[i].w; \
    } \
    R16(oa); \
    if (kq == 0) obase[(size_t)(tt) * strV] = oa; \
} while (0)

    float4 qA[4], kA[4], qB[4], kB[4];
    float vA, bA, eA, vB, bB, eB;
    LOADSTEP(qA, kA, vA, bA, eA, 0);
    LOADSTEP(qB, kB, vB, bB, eB, 1);

    for (int t = 0; t < TT; t += 2) {
        STEP(qA, kA, vA, bA, eA, t);
        LOADSTEP(qA, kA, vA, bA, eA, t + 2);   // over-reads 2 rows at t=510 (safe, unused)
        STEP(qB, kB, vB, bB, eB, t + 1);
        LOADSTEP(qB, kB, vB, bB, eB, t + 3);
    }
#undef LOADSTEP
#undef STEP
}

// ---------------------------------------------------------------------------
// Gated RMSNorm epilogue (in place over o).
// ---------------------------------------------------------------------------
__global__ __launch_bounds__(256) void epilogue(
    float* __restrict__ o, const float* __restrict__ gate,
    const float* __restrict__ wnorm)
{
    const int row  = blockIdx.x;
    const int tid  = threadIdx.x;
    const int lane = tid & 63, wid = tid >> 6;
    __shared__ float red[4];
    #pragma unroll 1
    for (int h = 0; h < NH; ++h) {
        size_t base = ((size_t)row * NH + h) * DV;
        float o0 = o[base + tid], o1 = o[base + 256 + tid];
        float ss = o0*o0 + o1*o1;
        #pragma unroll
        for (int off = 32; off >= 1; off >>= 1) ss += __shfl_xor(ss, off);
        if (lane == 0) red[wid] = ss;
        __syncthreads();
        ss = red[0] + red[1] + red[2] + red[3];
        __syncthreads();
        float irms = rsqrtf(ss * (1.f / DV) + 1e-6f);
        size_t gbase = (size_t)row * VAL_DIM + h * DV;
        float g0 = gate[gbase + tid], g1 = gate[gbase + 256 + tid];
        o[base + tid]       = o0 * irms * wnorm[tid]       * (1.f / (1.f + expf(-g0)));
        o[base + 256 + tid] = o1 * irms * wnorm[256 + tid] * (1.f / (1.f + expf(-g1)));
    }
}

// ---------------------------------------------------------------------------
extern "C" void kernel_launch(void* const* d_in, const int* in_sizes, int n_in,
                              void* d_out, int out_size, void* d_ws, size_t ws_size,
                              hipStream_t stream)
{
    const float* x     = (const float*)d_in[0];
    const float* Wq    = (const float*)d_in[1];
    const float* Wk    = (const float*)d_in[2];
    const float* Wv    = (const float*)d_in[3];
    const float* Wa    = (const float*)d_in[4];
    const float* Wb    = (const float*)d_in[5];
    const float* decay = (const float*)d_in[6];
    const float* Dp    = (const float*)d_in[7];
    const float* A_log = (const float*)d_in[8];
    const float* dtb   = (const float*)d_in[9];
    const float* Wg    = (const float*)d_in[10];
    const float* Wo    = (const float*)d_in[11];
    const float* onw   = (const float*)d_in[12];
    float* out = (float*)d_out;

    float* ws   = (float*)d_ws;
    float* q    = ws;                                  // ROWS*KEY_DIM
    float* k    = q    + (size_t)ROWS * KEY_DIM;
    float* v    = k    + (size_t)ROWS * KEY_DIM;       // v -> o -> gated o
    float* gate = v    + (size_t)ROWS * VAL_DIM;
    float* beta = gate + (size_t)ROWS * VAL_DIM;       // ROWS*NH
    float* eg   = beta + (size_t)ROWS * NH;            // ROWS*NH
    unsigned short* bf = (unsigned short*)(eg + (size_t)ROWS * NH);
    unsigned short* xb  = bf;                                   // ROWS*HID
    unsigned short* Wqb = xb  + (size_t)ROWS * HID;
    unsigned short* Wkb = Wqb + (size_t)KEY_DIM * HID;
    unsigned short* Wvb = Wkb + (size_t)KEY_DIM * HID;
    unsigned short* Wgb = Wvb + (size_t)VAL_DIM * HID;
    unsigned short* ob  = bf;                                   // phase 2 aliases
    unsigned short* Wob = ob + (size_t)ROWS * VAL_DIM;

    dim3 blk(256);
    auto cblocks = [](size_t n) { size_t b = (n / 4 + 255) / 256; return (int)(b > 4096 ? 4096 : b); };

    cast_f32_bf16<<<cblocks((size_t)ROWS*HID),    blk, 0, stream>>>(x,  xb,  ROWS*HID/4);
    cast_f32_bf16<<<cblocks((size_t)KEY_DIM*HID), blk, 0, stream>>>(Wq, Wqb, KEY_DIM*HID/4);
    cast_f32_bf16<<<cblocks((size_t)KEY_DIM*HID), blk, 0, stream>>>(Wk, Wkb, KEY_DIM*HID/4);
    cast_f32_bf16<<<cblocks((size_t)VAL_DIM*HID), blk, 0, stream>>>(Wv, Wvb, VAL_DIM*HID/4);
    cast_f32_bf16<<<cblocks((size_t)VAL_DIM*HID), blk, 0, stream>>>(Wg, Wgb, VAL_DIM*HID/4);

    gemm_nt_bf16<<<dim3(KEY_DIM/128, ROWS/128), blk, 0, stream>>>(xb, Wqb, q,    ROWS, KEY_DIM, HID);
    gemm_nt_bf16<<<dim3(KEY_DIM/128, ROWS/128), blk, 0, stream>>>(xb, Wkb, k,    ROWS, KEY_DIM, HID);
    gemm_nt_bf16<<<dim3(VAL_DIM/128, ROWS/128), blk, 0, stream>>>(xb, Wvb, v,    ROWS, VAL_DIM, HID);
    gemm_nt_bf16<<<dim3(VAL_DIM/128, ROWS/128), blk, 0, stream>>>(xb, Wgb, gate, ROWS, VAL_DIM, HID);
    proj_ab<<<dim3(ROWS, 12), dim3(64), 0, stream>>>(x, Wa, Wb, A_log, dtb, beta, eg);

    prep_norm<<<dim3(ROWS), blk, 0, stream>>>(q, k, v, decay, Dp);
    recurrence<<<dim3(BB*NH*128/4), blk, 0, stream>>>(q, k, v, beta, eg);   // 768 blocks
    epilogue<<<dim3(ROWS), blk, 0, stream>>>(v, gate, onw);

    cast_f32_bf16<<<cblocks((size_t)ROWS*VAL_DIM), blk, 0, stream>>>(v,  ob,  ROWS*VAL_DIM/4);
    cast_f32_bf16<<<cblocks((size_t)HID*VAL_DIM),  blk, 0, stream>>>(Wo, Wob, HID*VAL_DIM/4);
    gemm_nt_bf16<<<dim3(HID/128, ROWS/128), blk, 0, stream>>>(ob, Wob, out, ROWS, HID, VAL_DIM);
}

// Round 4
// 818.713 us; speedup vs baseline: 3.2820x; 1.3081x over previous
//
#include <hip/hip_runtime.h>
#include <hip/hip_bf16.h>
#include <math.h>

#define BB 4
#define TT 512
#define HID 2048
#define NH 6
#define DK 256
#define DV 512
#define ROWS (BB*TT)          /* 2048 */
#define KEY_DIM (NH*DK)       /* 1536 */
#define VAL_DIM (NH*DV)       /* 3072 */

typedef __bf16 bf16x8 __attribute__((ext_vector_type(8)));
typedef float  f32x4  __attribute__((ext_vector_type(4)));

// ---------------------------------------------------------------------------
// fp32 -> bf16 cast (RNE), vectorized float4 -> ushort4, grid-stride.
// ---------------------------------------------------------------------------
__device__ __forceinline__ unsigned short f2bf(float f) {
    unsigned int u = __float_as_uint(f);
    u = (u + 0x7FFFu + ((u >> 16) & 1u)) >> 16;
    return (unsigned short)u;
}

__global__ __launch_bounds__(256) void cast_f32_bf16(
    const float* __restrict__ src, unsigned short* __restrict__ dst, int n4)
{
    int stride = gridDim.x * 256;
    for (int i = blockIdx.x * 256 + threadIdx.x; i < n4; i += stride) {
        float4 v = ((const float4*)src)[i];
        ushort4 o;
        o.x = f2bf(v.x); o.y = f2bf(v.y); o.z = f2bf(v.z); o.w = f2bf(v.w);
        ((ushort4*)dst)[i] = o;
    }
}

// ---------------------------------------------------------------------------
// bf16 NT GEMM: C[m,n] = sum_k A[m*K+k]*B[n*K+k], fp32 accumulate/output.
// 128x128 tile, BK=32, 256 threads = 4 waves in 2x2; 4x4 mfma 16x16x32 each.
// ---------------------------------------------------------------------------
__global__ __launch_bounds__(256) void gemm_nt_bf16(
    const unsigned short* __restrict__ A, const unsigned short* __restrict__ B,
    float* __restrict__ C, int M, int N, int K)
{
    __shared__ __align__(16) unsigned short As[128 * 32];
    __shared__ __align__(16) unsigned short Bs[128 * 32];
    const int tid  = threadIdx.x;
    const int lane = tid & 63;
    const int wave = tid >> 6;
    const int bm = blockIdx.y * 128;
    const int bn = blockIdx.x * 128;
    const int wr = (wave >> 1) * 64;
    const int wc = (wave & 1) * 64;
    const int fr = lane & 15;
    const int kg = lane >> 4;

    f32x4 acc[4][4] = {};

    for (int k0 = 0; k0 < K; k0 += 32) {
        #pragma unroll
        for (int s = 0; s < 2; ++s) {
            int e  = s * 256 + tid;
            int r  = e >> 2;
            int c8 = (e & 3) * 8;
            const unsigned short* ga = A + (size_t)(bm + r) * K + k0 + c8;
            const unsigned short* gb = B + (size_t)(bn + r) * K + k0 + c8;
            unsigned short* la = As + (size_t)(s * 256 + wave * 64) * 8;
            unsigned short* lb = Bs + (size_t)(s * 256 + wave * 64) * 8;
            __builtin_amdgcn_global_load_lds(
                (const __attribute__((address_space(1))) void*)ga,
                (__attribute__((address_space(3))) void*)la, 16, 0, 0);
            __builtin_amdgcn_global_load_lds(
                (const __attribute__((address_space(1))) void*)gb,
                (__attribute__((address_space(3))) void*)lb, 16, 0, 0);
        }
        __syncthreads();

        bf16x8 a[4], b[4];
        #pragma unroll
        for (int f = 0; f < 4; ++f) {
            a[f] = *(const bf16x8*)&As[(wr + f * 16 + fr) * 32 + kg * 8];
            b[f] = *(const bf16x8*)&Bs[(wc + f * 16 + fr) * 32 + kg * 8];
        }
        #pragma unroll
        for (int fm = 0; fm < 4; ++fm)
            #pragma unroll
            for (int fn = 0; fn < 4; ++fn)
                acc[fm][fn] = __builtin_amdgcn_mfma_f32_16x16x32_bf16(
                    a[fm], b[fn], acc[fm][fn], 0, 0, 0);
        __syncthreads();
    }

    #pragma unroll
    for (int fm = 0; fm < 4; ++fm)
        #pragma unroll
        for (int fn = 0; fn < 4; ++fn) {
            int col = bn + wc + fn * 16 + fr;
            #pragma unroll
            for (int i = 0; i < 4; ++i) {
                int row = bm + wr + fm * 16 + kg * 4 + i;
                C[(size_t)row * N + col] = acc[fm][fn][i];
            }
        }
}

// ---------------------------------------------------------------------------
// Small projections a,b -> eg = exp(g), beta. grid (ROWS, 12), 64 threads.
// ---------------------------------------------------------------------------
__global__ __launch_bounds__(64) void proj_ab(
    const float* __restrict__ x, const float* __restrict__ Wa, const float* __restrict__ Wb,
    const float* __restrict__ A_log, const float* __restrict__ dt_bias,
    float* __restrict__ beta, float* __restrict__ eg)
{
    const int row = blockIdx.x;
    const int j   = blockIdx.y;
    const bool is_a = (j < NH);
    const int h = is_a ? j : j - NH;
    const float* wrow = (is_a ? Wa : Wb) + (size_t)h * HID;
    const float4* x4 = (const float4*)(x + (size_t)row * HID);
    const float4* w4 = (const float4*)wrow;
    float s = 0.f;
    for (int i = threadIdx.x; i < HID/4; i += 64) {
        float4 a = x4[i], b = w4[i];
        s += a.x*b.x + a.y*b.y + a.z*b.z + a.w*b.w;
    }
    #pragma unroll
    for (int off = 32; off >= 1; off >>= 1) s += __shfl_xor(s, off);
    if (threadIdx.x == 0) {
        if (is_a) {
            float a  = s + dt_bias[h];
            float sp = (a > 20.f) ? a : log1pf(expf(a));
            float g  = -expf(A_log[h]) * sp;
            eg[(size_t)row * NH + h] = expf(g);
        } else {
            beta[(size_t)row * NH + h] = 1.f / (1.f + expf(-s));
        }
    }
}

// ---------------------------------------------------------------------------
// Pointwise: silu(q,k), q-correction, l2norm (q scaled K^-0.5), silu(v).
// l2norm(p)==l2norm(k) since p = k*sigmoid(decay[h]) (positive scalar/head).
// ---------------------------------------------------------------------------
__global__ __launch_bounds__(256) void prep_norm(
    float* __restrict__ q, float* __restrict__ k, float* __restrict__ v,
    const float* __restrict__ decay, const float* __restrict__ D)
{
    const int row  = blockIdx.x;
    const int tid  = threadIdx.x;
    const int lane = tid & 63, wid = tid >> 6;
    __shared__ float red[8];
    #pragma unroll 1
    for (int h = 0; h < NH; ++h) {
        size_t idx = (size_t)row * KEY_DIM + h * DK + tid;
        float qr = q[idx], kr = k[idx];
        float ksil = kr / (1.f + expf(-kr));
        float qsil = qr / (1.f + expf(-qr));
        float coef = D[h] * (1.f / (1.f + expf(-decay[h])));
        float qc = qsil - coef * ksil;
        float sq = qc*qc, sk = ksil*ksil;
        #pragma unroll
        for (int off = 32; off >= 1; off >>= 1) {
            sq += __shfl_xor(sq, off);
            sk += __shfl_xor(sk, off);
        }
        if (lane == 0) { red[wid] = sq; red[4+wid] = sk; }
        __syncthreads();
        sq = red[0]+red[1]+red[2]+red[3];
        sk = red[4]+red[5]+red[6]+red[7];
        __syncthreads();
        float qinv = 0.0625f / fmaxf(sqrtf(sq), 1e-12f);
        float kinv = 1.f     / fmaxf(sqrtf(sk), 1e-12f);
        q[idx] = qc   * qinv;
        k[idx] = ksil * kinv;
    }
    for (int jj = tid; jj < VAL_DIM; jj += 256) {
        size_t id2 = (size_t)row * VAL_DIM + jj;
        float xv = v[id2];
        v[id2] = xv / (1.f + expf(-xv));
    }
}

// ---------------------------------------------------------------------------
// Gated delta-rule scan, wave-local, 64-way K split x 2 v-cols per wave.
// lane = kq (owns k[lane*4 .. lane*4+3]); state hS[8] = h[4k x 2cols].
// 6144 waves total (6/SIMD) -> latency hiding via TLP; per-lane loads only
// 10 floats/step (q4,k4,v2 + 2 scalars). Full 64-lane reductions:
// 4 DPP butterfly hops + shfl_xor(16) + shfl_xor(32), per v-col.
// XCD-pinned mapping: each (b,h) group's 64 blocks land on one XCD so its
// q/k stream stays L2-resident (3 groups x ~2MB window per XCD).
// Prefetch over-reads <=3 rows past buffers (adjacent ws buffers, unused).
// ---------------------------------------------------------------------------
#define DPP_ADD(x, ctrl) \
    ((x) + __int_as_float(__builtin_amdgcn_mov_dpp(__float_as_int(x), (ctrl), 0xF, 0xF, true)))

__device__ __forceinline__ float r64(float x) {
    x = DPP_ADD(x, 0xB1);   // quad_perm xor1
    x = DPP_ADD(x, 0x4E);   // quad_perm xor2
    x = DPP_ADD(x, 0x141);  // row_half_mirror == xor4 (quads uniform)
    x = DPP_ADD(x, 0x140);  // row_mirror      == xor8 (octs uniform)
    x += __shfl_xor(x, 16);
    x += __shfl_xor(x, 32);
    return x;
}

__global__ __launch_bounds__(256, 6) void recurrence(
    const float* __restrict__ qn, const float* __restrict__ kn,
    float* __restrict__ vo, const float* __restrict__ beta, const float* __restrict__ eg)
{
    // XCD-pinned decode: idx = xcd + 8*(gsub*64 + j), group g = gsub*8 + xcd
    const int idx  = blockIdx.x;
    const int xcd  = idx & 7;
    const int rem  = idx >> 3;
    const int gsub = rem >> 6;          // 0..2
    const int j    = rem & 63;          // block within group
    const int g    = gsub * 8 + xcd;    // 0..23 = (b,h)
    const int wave = threadIdx.x >> 6;
    const int lane = threadIdx.x & 63;  // = kq (64-way K split)
    const int vc   = j * 4 + wave;      // 0..255 -> v col pair
    const int h = g % NH, b = g / NH;

    float hS[8];                        // [k 0..3][col] : 0..3 col0, 4..7 col1
    #pragma unroll
    for (int i = 0; i < 8; ++i) hS[i] = 0.f;

    const size_t rb = (size_t)(b * TT) * NH + h;
    const float* qbase = qn + rb * DK + lane * 4;
    const float* kbase = kn + rb * DK + lane * 4;
    const float* vbase = vo + rb * DV + vc * 2;
    const float* bbase = beta + rb;
    const float* ebase = eg + rb;
    float*       obase = vo + rb * DV + vc * 2;
    const int strK = NH * DK;   // 1536
    const int strV = NH * DV;   // 3072
    const int strS = NH;

#define LOADSTEP(Q, Kk, Vv, Bb, Ee, tt) do { \
    Q  = *(const float4*)(qbase + (size_t)(tt) * strK); \
    Kk = *(const float4*)(kbase + (size_t)(tt) * strK); \
    Vv = *(const float2*)(vbase + (size_t)(tt) * strV); \
    Bb = bbase[(size_t)(tt) * strS]; \
    Ee = ebase[(size_t)(tt) * strS]; \
} while (0)

#define STEP(Q, Kk, Vv, Bb, Ee, tt) do { \
    float p0 = hS[0]*Kk.x + hS[1]*Kk.y + hS[2]*Kk.z + hS[3]*Kk.w; \
    float p1 = hS[4]*Kk.x + hS[5]*Kk.y + hS[6]*Kk.z + hS[7]*Kk.w; \
    p0 = r64(p0); p1 = r64(p1); \
    float vn0 = (Vv.x - p0) * Bb; \
    float vn1 = (Vv.y - p1) * Bb; \
    float o0, o1; \
    hS[0] = hS[0]*Ee + Kk.x*vn0; o0  = hS[0]*Q.x; \
    hS[1] = hS[1]*Ee + Kk.y*vn0; o0 += hS[1]*Q.y; \
    hS[2] = hS[2]*Ee + Kk.z*vn0; o0 += hS[2]*Q.z; \
    hS[3] = hS[3]*Ee + Kk.w*vn0; o0 += hS[3]*Q.w; \
    hS[4] = hS[4]*Ee + Kk.x*vn1; o1  = hS[4]*Q.x; \
    hS[5] = hS[5]*Ee + Kk.y*vn1; o1 += hS[5]*Q.y; \
    hS[6] = hS[6]*Ee + Kk.z*vn1; o1 += hS[6]*Q.z; \
    hS[7] = hS[7]*Ee + Kk.w*vn1; o1 += hS[7]*Q.w; \
    o0 = r64(o0); o1 = r64(o1); \
    if (lane == 0) *(float2*)(obase + (size_t)(tt) * strV) = make_float2(o0, o1); \
} while (0)

    float4 qA, kA, qB, kB;
    float2 vA, vB;
    float bA, eA, bB, eB;
    LOADSTEP(qA, kA, vA, bA, eA, 0);
    LOADSTEP(qB, kB, vB, bB, eB, 1);

    for (int t = 0; t < TT; t += 2) {
        STEP(qA, kA, vA, bA, eA, t);
        LOADSTEP(qA, kA, vA, bA, eA, t + 2);   // over-read at tail: safe, unused
        STEP(qB, kB, vB, bB, eB, t + 1);
        LOADSTEP(qB, kB, vB, bB, eB, t + 3);
    }
#undef LOADSTEP
#undef STEP
}

// ---------------------------------------------------------------------------
// Gated RMSNorm epilogue (in place over o).
// ---------------------------------------------------------------------------
__global__ __launch_bounds__(256) void epilogue(
    float* __restrict__ o, const float* __restrict__ gate,
    const float* __restrict__ wnorm)
{
    const int row  = blockIdx.x;
    const int tid  = threadIdx.x;
    const int lane = tid & 63, wid = tid >> 6;
    __shared__ float red[4];
    #pragma unroll 1
    for (int h = 0; h < NH; ++h) {
        size_t base = ((size_t)row * NH + h) * DV;
        float o0 = o[base + tid], o1 = o[base + 256 + tid];
        float ss = o0*o0 + o1*o1;
        #pragma unroll
        for (int off = 32; off >= 1; off >>= 1) ss += __shfl_xor(ss, off);
        if (lane == 0) red[wid] = ss;
        __syncthreads();
        ss = red[0] + red[1] + red[2] + red[3];
        __syncthreads();
        float irms = rsqrtf(ss * (1.f / DV) + 1e-6f);
        size_t gbase = (size_t)row * VAL_DIM + h * DV;
        float g0 = gate[gbase + tid], g1 = gate[gbase + 256 + tid];
        o[base + tid]       = o0 * irms * wnorm[tid]       * (1.f / (1.f + expf(-g0)));
        o[base + 256 + tid] = o1 * irms * wnorm[256 + tid] * (1.f / (1.f + expf(-g1)));
    }
}

// ---------------------------------------------------------------------------
extern "C" void kernel_launch(void* const* d_in, const int* in_sizes, int n_in,
                              void* d_out, int out_size, void* d_ws, size_t ws_size,
                              hipStream_t stream)
{
    const float* x     = (const float*)d_in[0];
    const float* Wq    = (const float*)d_in[1];
    const float* Wk    = (const float*)d_in[2];
    const float* Wv    = (const float*)d_in[3];
    const float* Wa    = (const float*)d_in[4];
    const float* Wb    = (const float*)d_in[5];
    const float* decay = (const float*)d_in[6];
    const float* Dp    = (const float*)d_in[7];
    const float* A_log = (const float*)d_in[8];
    const float* dtb   = (const float*)d_in[9];
    const float* Wg    = (const float*)d_in[10];
    const float* Wo    = (const float*)d_in[11];
    const float* onw   = (const float*)d_in[12];
    float* out = (float*)d_out;

    float* ws   = (float*)d_ws;
    float* q    = ws;                                  // ROWS*KEY_DIM
    float* k    = q    + (size_t)ROWS * KEY_DIM;
    float* v    = k    + (size_t)ROWS * KEY_DIM;       // v -> o -> gated o
    float* gate = v    + (size_t)ROWS * VAL_DIM;
    float* beta = gate + (size_t)ROWS * VAL_DIM;       // ROWS*NH
    float* eg   = beta + (size_t)ROWS * NH;            // ROWS*NH
    unsigned short* bf = (unsigned short*)(eg + (size_t)ROWS * NH);
    unsigned short* xb  = bf;                                   // ROWS*HID
    unsigned short* Wqb = xb  + (size_t)ROWS * HID;
    unsigned short* Wkb = Wqb + (size_t)KEY_DIM * HID;
    unsigned short* Wvb = Wkb + (size_t)KEY_DIM * HID;
    unsigned short* Wgb = Wvb + (size_t)VAL_DIM * HID;
    unsigned short* ob  = bf;                                   // phase 2 aliases
    unsigned short* Wob = ob + (size_t)ROWS * VAL_DIM;

    dim3 blk(256);
    auto cblocks = [](size_t n) { size_t b = (n / 4 + 255) / 256; return (int)(b > 4096 ? 4096 : b); };

    cast_f32_bf16<<<cblocks((size_t)ROWS*HID),    blk, 0, stream>>>(x,  xb,  ROWS*HID/4);
    cast_f32_bf16<<<cblocks((size_t)KEY_DIM*HID), blk, 0, stream>>>(Wq, Wqb, KEY_DIM*HID/4);
    cast_f32_bf16<<<cblocks((size_t)KEY_DIM*HID), blk, 0, stream>>>(Wk, Wkb, KEY_DIM*HID/4);
    cast_f32_bf16<<<cblocks((size_t)VAL_DIM*HID), blk, 0, stream>>>(Wv, Wvb, VAL_DIM*HID/4);
    cast_f32_bf16<<<cblocks((size_t)VAL_DIM*HID), blk, 0, stream>>>(Wg, Wgb, VAL_DIM*HID/4);

    gemm_nt_bf16<<<dim3(KEY_DIM/128, ROWS/128), blk, 0, stream>>>(xb, Wqb, q,    ROWS, KEY_DIM, HID);
    gemm_nt_bf16<<<dim3(KEY_DIM/128, ROWS/128), blk, 0, stream>>>(xb, Wkb, k,    ROWS, KEY_DIM, HID);
    gemm_nt_bf16<<<dim3(VAL_DIM/128, ROWS/128), blk, 0, stream>>>(xb, Wvb, v,    ROWS, VAL_DIM, HID);
    gemm_nt_bf16<<<dim3(VAL_DIM/128, ROWS/128), blk, 0, stream>>>(xb, Wgb, gate, ROWS, VAL_DIM, HID);
    proj_ab<<<dim3(ROWS, 12), dim3(64), 0, stream>>>(x, Wa, Wb, A_log, dtb, beta, eg);

    prep_norm<<<dim3(ROWS), blk, 0, stream>>>(q, k, v, decay, Dp);
    recurrence<<<dim3(24 * 64), blk, 0, stream>>>(q, k, v, beta, eg);   // 1536 blocks, 6144 waves
    epilogue<<<dim3(ROWS), blk, 0, stream>>>(v, gate, onw);

    cast_f32_bf16<<<cblocks((size_t)ROWS*VAL_DIM), blk, 0, stream>>>(v,  ob,  ROWS*VAL_DIM/4);
    cast_f32_bf16<<<cblocks((size_t)HID*VAL_DIM),  blk, 0, stream>>>(Wo, Wob, HID*VAL_DIM/4);
    gemm_nt_bf16<<<dim3(HID/128, ROWS/128), blk, 0, stream>>>(ob, Wob, out, ROWS, HID, VAL_DIM);
}

// Round 5
// 733.203 us; speedup vs baseline: 3.6648x; 1.1166x over previous
//
#include <hip/hip_runtime.h>
#include <hip/hip_bf16.h>
#include <math.h>

#define BB 4
#define TT 512
#define HID 2048
#define NH 6
#define DK 256
#define DV 512
#define ROWS (BB*TT)          /* 2048 */
#define KEY_DIM (NH*DK)       /* 1536 */
#define VAL_DIM (NH*DV)       /* 3072 */
#define NG (BB*NH)            /* 24 groups */
#define NC 8                  /* chunks */
#define CL 64                 /* chunk length */

typedef __bf16 bf16x8 __attribute__((ext_vector_type(8)));
typedef float  f32x4  __attribute__((ext_vector_type(4)));

__device__ __forceinline__ unsigned short f2bf(float f) {
    unsigned int u = __float_as_uint(f);
    u = (u + 0x7FFFu + ((u >> 16) & 1u)) >> 16;
    return (unsigned short)u;
}
__device__ __forceinline__ float b2f(unsigned short u) {
    return __uint_as_float(((unsigned int)u) << 16);
}

// ---------------------------------------------------------------------------
// fp32 -> bf16 cast (RNE), vectorized.
// ---------------------------------------------------------------------------
__global__ __launch_bounds__(256) void cast_f32_bf16(
    const float* __restrict__ src, unsigned short* __restrict__ dst, int n4)
{
    int stride = gridDim.x * 256;
    for (int i = blockIdx.x * 256 + threadIdx.x; i < n4; i += stride) {
        float4 v = ((const float4*)src)[i];
        ushort4 o;
        o.x = f2bf(v.x); o.y = f2bf(v.y); o.z = f2bf(v.z); o.w = f2bf(v.w);
        ((ushort4*)dst)[i] = o;
    }
}

// ---------------------------------------------------------------------------
// bf16 NT GEMM: C[m,n] = sum_k A[m*K+k]*B[n*K+k], fp32 accumulate/output.
// 128x128 tile, BK=32, 256 threads = 4 waves in 2x2; 4x4 mfma 16x16x32 each.
// ---------------------------------------------------------------------------
__global__ __launch_bounds__(256) void gemm_nt_bf16(
    const unsigned short* __restrict__ A, const unsigned short* __restrict__ B,
    float* __restrict__ C, int M, int N, int K)
{
    __shared__ __align__(16) unsigned short As[128 * 32];
    __shared__ __align__(16) unsigned short Bs[128 * 32];
    const int tid  = threadIdx.x;
    const int lane = tid & 63;
    const int wave = tid >> 6;
    const int bm = blockIdx.y * 128;
    const int bn = blockIdx.x * 128;
    const int wr = (wave >> 1) * 64;
    const int wc = (wave & 1) * 64;
    const int fr = lane & 15;
    const int kg = lane >> 4;

    f32x4 acc[4][4] = {};

    for (int k0 = 0; k0 < K; k0 += 32) {
        #pragma unroll
        for (int s = 0; s < 2; ++s) {
            int e  = s * 256 + tid;
            int r  = e >> 2;
            int c8 = (e & 3) * 8;
            const unsigned short* ga = A + (size_t)(bm + r) * K + k0 + c8;
            const unsigned short* gb = B + (size_t)(bn + r) * K + k0 + c8;
            unsigned short* la = As + (size_t)(s * 256 + wave * 64) * 8;
            unsigned short* lb = Bs + (size_t)(s * 256 + wave * 64) * 8;
            __builtin_amdgcn_global_load_lds(
                (const __attribute__((address_space(1))) void*)ga,
                (__attribute__((address_space(3))) void*)la, 16, 0, 0);
            __builtin_amdgcn_global_load_lds(
                (const __attribute__((address_space(1))) void*)gb,
                (__attribute__((address_space(3))) void*)lb, 16, 0, 0);
        }
        __syncthreads();

        bf16x8 a[4], b[4];
        #pragma unroll
        for (int f = 0; f < 4; ++f) {
            a[f] = *(const bf16x8*)&As[(wr + f * 16 + fr) * 32 + kg * 8];
            b[f] = *(const bf16x8*)&Bs[(wc + f * 16 + fr) * 32 + kg * 8];
        }
        #pragma unroll
        for (int fm = 0; fm < 4; ++fm)
            #pragma unroll
            for (int fn = 0; fn < 4; ++fn)
                acc[fm][fn] = __builtin_amdgcn_mfma_f32_16x16x32_bf16(
                    a[fm], b[fn], acc[fm][fn], 0, 0, 0);
        __syncthreads();
    }

    #pragma unroll
    for (int fm = 0; fm < 4; ++fm)
        #pragma unroll
        for (int fn = 0; fn < 4; ++fn) {
            int col = bn + wc + fn * 16 + fr;
            #pragma unroll
            for (int i = 0; i < 4; ++i) {
                int row = bm + wr + fm * 16 + kg * 4 + i;
                C[(size_t)row * N + col] = acc[fm][fn][i];
            }
        }
}

// ---------------------------------------------------------------------------
// Small projections a,b -> graw (log-decay g), beta. grid (ROWS,12), 64 thr.
// ---------------------------------------------------------------------------
__global__ __launch_bounds__(64) void proj_ab(
    const float* __restrict__ x, const float* __restrict__ Wa, const float* __restrict__ Wb,
    const float* __restrict__ A_log, const float* __restrict__ dt_bias,
    float* __restrict__ beta, float* __restrict__ graw)
{
    const int row = blockIdx.x;
    const int j   = blockIdx.y;
    const bool is_a = (j < NH);
    const int h = is_a ? j : j - NH;
    const float* wrow = (is_a ? Wa : Wb) + (size_t)h * HID;
    const float4* x4 = (const float4*)(x + (size_t)row * HID);
    const float4* w4 = (const float4*)wrow;
    float s = 0.f;
    for (int i = threadIdx.x; i < HID/4; i += 64) {
        float4 a = x4[i], b = w4[i];
        s += a.x*b.x + a.y*b.y + a.z*b.z + a.w*b.w;
    }
    #pragma unroll
    for (int off = 32; off >= 1; off >>= 1) s += __shfl_xor(s, off);
    if (threadIdx.x == 0) {
        if (is_a) {
            float a  = s + dt_bias[h];
            float sp = (a > 20.f) ? a : log1pf(expf(a));
            graw[(size_t)row * NH + h] = -expf(A_log[h]) * sp;
        } else {
            beta[(size_t)row * NH + h] = 1.f / (1.f + expf(-s));
        }
    }
}

// ---------------------------------------------------------------------------
// Pointwise prep: silu(q,k), q-correction, l2norm (q scaled K^-0.5), silu(v).
// Writes bf16 per-group layouts: qb,kb [g][t][256], bvb = beta*silu(v)
// [g][t][512].  (l2norm(p)==l2norm(k) since p = k*sigmoid(decay[h]).)
// ---------------------------------------------------------------------------
__global__ __launch_bounds__(256) void prep_norm(
    const float* __restrict__ q, const float* __restrict__ k, const float* __restrict__ v,
    const float* __restrict__ decay, const float* __restrict__ D,
    const float* __restrict__ beta,
    unsigned short* __restrict__ qb, unsigned short* __restrict__ kb,
    unsigned short* __restrict__ bvb)
{
    const int row  = blockIdx.x;
    const int b    = row >> 9, t = row & 511;
    const int tid  = threadIdx.x;
    const int lane = tid & 63, wid = tid >> 6;
    __shared__ float red[8];
    #pragma unroll 1
    for (int h = 0; h < NH; ++h) {
        size_t idx = (size_t)row * KEY_DIM + h * DK + tid;
        float qr = q[idx], kr = k[idx];
        float ksil = kr / (1.f + expf(-kr));
        float qsil = qr / (1.f + expf(-qr));
        float coef = D[h] * (1.f / (1.f + expf(-decay[h])));
        float qc = qsil - coef * ksil;
        float sq = qc*qc, sk = ksil*ksil;
        #pragma unroll
        for (int off = 32; off >= 1; off >>= 1) {
            sq += __shfl_xor(sq, off);
            sk += __shfl_xor(sk, off);
        }
        if (lane == 0) { red[wid] = sq; red[4+wid] = sk; }
        __syncthreads();
        sq = red[0]+red[1]+red[2]+red[3];
        sk = red[4]+red[5]+red[6]+red[7];
        __syncthreads();
        float qinv = 0.0625f / fmaxf(sqrtf(sq), 1e-12f);
        float kinv = 1.f     / fmaxf(sqrtf(sk), 1e-12f);
        size_t gidx = (((size_t)(b*NH + h)) * TT + t) * DK + tid;
        qb[gidx] = f2bf(qc   * qinv);
        kb[gidx] = f2bf(ksil * kinv);
    }
    for (int jj = tid; jj < VAL_DIM; jj += 256) {
        int h2 = jj >> 9, dv = jj & 511;
        float xv = v[(size_t)row * VAL_DIM + jj];
        float sv = xv / (1.f + expf(-xv));
        float bt = beta[(size_t)row * NH + h2];
        bvb[(((size_t)(b*NH + h2)) * TT + t) * DV + dv] = f2bf(bt * sv);
    }
}

// ---------------------------------------------------------------------------
// Per-group cumulative log-decay + beta repack. 24 blocks x 64 threads.
// cinc[t] = sum_{s<=t} g_s ; cexc[t] = cinc[t] - g_t ; barr = beta repacked.
// ---------------------------------------------------------------------------
__global__ __launch_bounds__(64) void cumsum_pack(
    const float* __restrict__ graw, const float* __restrict__ beta,
    float* __restrict__ cinc, float* __restrict__ cexc, float* __restrict__ barr)
{
    const int g = blockIdx.x;
    const int b = g / NH, h = g % NH;
    const int lane = threadIdx.x;
    float carry = 0.f;
    for (int c0 = 0; c0 < TT; c0 += 64) {
        int t = c0 + lane;
        size_t rowi = ((size_t)(b*TT + t)) * NH + h;
        float gv = graw[rowi];
        float x = gv;
        #pragma unroll
        for (int off = 1; off < 64; off <<= 1) {
            float n = __shfl_up(x, off);
            if (lane >= off) x += n;
        }
        float inc = carry + x;
        cinc[(size_t)g*TT + t] = inc;
        cexc[(size_t)g*TT + t] = inc - gv;
        barr[(size_t)g*TT + t] = beta[rowi];
        carry = __shfl(inc, 63);
    }
}

// ---------------------------------------------------------------------------
// A-matrix tiles: A[i,j] = beta_i * exp(cexc_i - cinc_j) * (k_i . k_j), j<i.
// grid = 24 groups x 36 lower-tri chunk pairs (m>=l); 64x64 tile per block.
// MFMA with direct-global bf16 operands (L2-resident). Writes Ab bf16.
// ---------------------------------------------------------------------------
__global__ __launch_bounds__(256) void a_mat(
    const unsigned short* __restrict__ kb, const float* __restrict__ cinc,
    const float* __restrict__ cexc, const float* __restrict__ barr,
    unsigned short* __restrict__ Ab)
{
    const int blk = blockIdx.x;
    const int g = blk / 36;
    int p = blk % 36, m = 0, acc0 = 0;
    while (p >= acc0 + m + 1) { acc0 += m + 1; ++m; }
    const int l = p - acc0;
    const int tid = threadIdx.x, lane = tid & 63, w = tid >> 6;
    const int fr = lane & 15, kg = lane >> 4;
    const unsigned short* Km = kb + (((size_t)g*TT) + m*CL) * DK;
    const unsigned short* Kl = kb + (((size_t)g*TT) + l*CL) * DK;
    f32x4 acc[4] = {};
    #pragma unroll
    for (int ks = 0; ks < 8; ++ks) {
        bf16x8 a = *(const bf16x8*)(Km + (size_t)(w*16 + fr)*DK + ks*32 + kg*8);
        #pragma unroll
        for (int fn = 0; fn < 4; ++fn) {
            bf16x8 b = *(const bf16x8*)(Kl + (size_t)(fn*16 + fr)*DK + ks*32 + kg*8);
            acc[fn] = __builtin_amdgcn_mfma_f32_16x16x32_bf16(a, b, acc[fn], 0, 0, 0);
        }
    }
    const float* ci = cinc + (size_t)g*TT;
    const float* ce = cexc + (size_t)g*TT;
    const float* bb = barr + (size_t)g*TT;
    #pragma unroll
    for (int fn = 0; fn < 4; ++fn) {
        int tj = l*CL + fn*16 + fr;
        float cj = ci[tj];
        #pragma unroll
        for (int r = 0; r < 4; ++r) {
            int ti = m*CL + w*16 + kg*4 + r;
            float val = 0.f;
            if (tj < ti) val = bb[ti] * __expf(ce[ti] - cj) * acc[fn][r];
            Ab[((size_t)g*TT + ti)*TT + tj] = f2bf(val);
        }
    }
}

// ---------------------------------------------------------------------------
// Unit-lower-triangular inverse of (I + A_mm), 64x64, forward substitution.
// 192 blocks (g*8+m) x 64 threads; lane = column. Writes Minvb bf16.
// ---------------------------------------------------------------------------
__global__ __launch_bounds__(64) void minv_kern(
    const unsigned short* __restrict__ Ab, unsigned short* __restrict__ Minvb)
{
    const int blk = blockIdx.x;
    const int g = blk >> 3, m = blk & 7;
    const int col = threadIdx.x;
    __shared__ float X[64][65];
    __shared__ float arow[64];
    #pragma unroll 1
    for (int i = 0; i < 64; ++i) X[i][col] = (i == col) ? 1.f : 0.f;
    const unsigned short* Am = Ab + (((size_t)g*TT) + m*CL)*TT + m*CL;
    for (int i = 1; i < 64; ++i) {
        arow[col] = (col < i) ? b2f(Am[(size_t)i*TT + col]) : 0.f;
        __syncthreads();
        if (col < i) {
            float s = 0.f;
            for (int t = col; t < i; ++t) s += arow[t] * X[t][col];
            X[i][col] = -s;
        }
        __syncthreads();
    }
    unsigned short* out = Minvb + (size_t)blk * 64 * 64;
    #pragma unroll 1
    for (int i = 0; i < 64; ++i) out[(size_t)i*64 + col] = f2bf(X[i][col]);
}

// ---------------------------------------------------------------------------
// U-solve: (I+A) U = beta*V, block forward substitution over 8 chunks.
// grid = 24 groups x 4 v-slices(128); per chunk: U_m = Minv_m*(bv_m - sum_l
// A_ml U_l).  U stored TRANSPOSED: Utb[g][v(512)][t(512)] bf16 (MFMA B-op).
// ---------------------------------------------------------------------------
__global__ __launch_bounds__(256) void usolve(
    const unsigned short* __restrict__ Ab, const unsigned short* __restrict__ Minvb,
    const unsigned short* __restrict__ bvb, unsigned short* __restrict__ Utb)
{
    const int blk = blockIdx.x;
    const int g = blk >> 2, vs = blk & 3;
    const int tid = threadIdx.x, lane = tid & 63, w = tid >> 6;
    const int fr = lane & 15, kg = lane >> 4;
    __shared__ __align__(16) unsigned short TACC[2][128][40];  // [i/32][v][i%32]

    for (int m = 0; m < NC; ++m) {
        f32x4 acc[8] = {};
        for (int l = 0; l < m; ++l) {
            const unsigned short* Aml = Ab + (((size_t)g*TT) + m*CL)*TT + l*CL;
            const unsigned short* Ul  = Utb + (((size_t)g*TT) + vs*128)*TT + l*CL;
            #pragma unroll
            for (int ks = 0; ks < 2; ++ks) {
                bf16x8 a = *(const bf16x8*)(Aml + (size_t)(w*16 + fr)*TT + ks*32 + kg*8);
                #pragma unroll
                for (int fn = 0; fn < 8; ++fn) {
                    bf16x8 b = *(const bf16x8*)(Ul + (size_t)(fn*16 + fr)*TT + ks*32 + kg*8);
                    acc[fn] = __builtin_amdgcn_mfma_f32_16x16x32_bf16(a, b, acc[fn], 0, 0, 0);
                }
            }
        }
        __syncthreads();   // TACC reuse guard
        const unsigned short* bvg = bvb + (((size_t)g*TT) + m*CL)*DV + vs*128;
        #pragma unroll
        for (int fn = 0; fn < 8; ++fn) {
            int v = fn*16 + fr;
            #pragma unroll
            for (int r = 0; r < 4; ++r) {
                int i = w*16 + kg*4 + r;
                float rhs = b2f(bvg[(size_t)i*DV + v]) - acc[fn][r];
                TACC[i >> 5][v][i & 31] = f2bf(rhs);
            }
        }
        __syncthreads();
        const unsigned short* Mi = Minvb + (size_t)(g*8 + m) * 4096;
        f32x4 acc2[8] = {};
        #pragma unroll
        for (int ks = 0; ks < 2; ++ks) {
            bf16x8 a = *(const bf16x8*)(Mi + (size_t)(w*16 + fr)*64 + ks*32 + kg*8);
            #pragma unroll
            for (int fn = 0; fn < 8; ++fn) {
                bf16x8 b = *(const bf16x8*)&TACC[ks][fn*16 + fr][kg*8];
                acc2[fn] = __builtin_amdgcn_mfma_f32_16x16x32_bf16(a, b, acc2[fn], 0, 0, 0);
            }
        }
        unsigned short* Um = Utb + (((size_t)g*TT) + vs*128)*TT + m*CL;
        #pragma unroll
        for (int fn = 0; fn < 8; ++fn) {
            int v = fn*16 + fr;
            #pragma unroll
            for (int r = 0; r < 4; ++r) {
                int i = w*16 + kg*4 + r;
                Um[(size_t)v*TT + i] = f2bf(acc2[fn][r]);
            }
        }
        __syncthreads();   // drain stores (vmcnt) before next chunk reads U
    }
}

// ---------------------------------------------------------------------------
// Output: o_i = sum_{j<=i} exp(c_i - c_j)*(q_i . k_j) * u_j.
// grid = 24 groups x 8 row-chunks x 2 v-halves(256). Decay-masked attention:
// per l-tile: scores (MFMA) -> mask/exp -> Ps bf16 (LDS) -> acc += Ps*Ut.
// Writes o fp32 into the [row][h*512+dv] layout (the old v buffer).
// ---------------------------------------------------------------------------
__global__ __launch_bounds__(256) void o_kern(
    const unsigned short* __restrict__ qb, const unsigned short* __restrict__ kb,
    const unsigned short* __restrict__ Utb, const float* __restrict__ cinc,
    float* __restrict__ o)
{
    const int blk = blockIdx.x;
    const int vh = blk & 1, m = (blk >> 1) & 7, g = blk >> 4;
    const int b = g / NH, h = g % NH;
    const int tid = threadIdx.x, lane = tid & 63, w = tid >> 6;
    const int fr = lane & 15, kg = lane >> 4;
    __shared__ __align__(16) unsigned short Ps[2][64][40];   // [j/32][i][j%32]
    __shared__ float cis[64];
    if (tid < 64) cis[tid] = cinc[(size_t)g*TT + m*CL + tid];

    f32x4 acc[16] = {};
    const unsigned short* Qm = qb + (((size_t)g*TT) + m*CL) * DK;

    for (int l = 0; l <= m; ++l) {
        f32x4 sacc[4] = {};
        const unsigned short* Kl = kb + (((size_t)g*TT) + l*CL) * DK;
        #pragma unroll
        for (int ks = 0; ks < 8; ++ks) {
            bf16x8 a = *(const bf16x8*)(Qm + (size_t)(w*16 + fr)*DK + ks*32 + kg*8);
            #pragma unroll
            for (int fn = 0; fn < 4; ++fn) {
                bf16x8 bq = *(const bf16x8*)(Kl + (size_t)(fn*16 + fr)*DK + ks*32 + kg*8);
                sacc[fn] = __builtin_amdgcn_mfma_f32_16x16x32_bf16(a, bq, sacc[fn], 0, 0, 0);
            }
        }
        __syncthreads();   // Ps reuse guard (also covers cis init on l=0)
        const float* cj = cinc + (size_t)g*TT + l*CL;
        #pragma unroll
        for (int fn = 0; fn < 4; ++fn) {
            int jl = fn*16 + fr;
            int tj = l*CL + jl;
            float cjv = cj[jl];
            #pragma unroll
            for (int r = 0; r < 4; ++r) {
                int il = w*16 + kg*4 + r;
                int ti = m*CL + il;
                float val = (tj <= ti) ? sacc[fn][r] * __expf(cis[il] - cjv) : 0.f;
                Ps[jl >> 5][il][jl & 31] = f2bf(val);
            }
        }
        __syncthreads();
        const unsigned short* Ub = Utb + (((size_t)g*TT) + vh*256)*TT + l*CL;
        #pragma unroll
        for (int ks = 0; ks < 2; ++ks) {
            bf16x8 a = *(const bf16x8*)&Ps[ks][w*16 + fr][kg*8];
            #pragma unroll
            for (int fn = 0; fn < 16; ++fn) {
                bf16x8 bq = *(const bf16x8*)(Ub + (size_t)(fn*16 + fr)*TT + ks*32 + kg*8);
                acc[fn] = __builtin_amdgcn_mfma_f32_16x16x32_bf16(a, bq, acc[fn], 0, 0, 0);
            }
        }
    }
    float* ob = o + ((size_t)(b*TT + m*CL)) * VAL_DIM + h*DV + vh*256;
    #pragma unroll
    for (int fn = 0; fn < 16; ++fn) {
        int v = fn*16 + fr;
        #pragma unroll
        for (int r = 0; r < 4; ++r) {
            int il = w*16 + kg*4 + r;
            ob[(size_t)il*VAL_DIM + v] = acc[fn][r];
        }
    }
}

// ---------------------------------------------------------------------------
// Gated RMSNorm epilogue (in place over o).
// ---------------------------------------------------------------------------
__global__ __launch_bounds__(256) void epilogue(
    float* __restrict__ o, const float* __restrict__ gate,
    const float* __restrict__ wnorm)
{
    const int row  = blockIdx.x;
    const int tid  = threadIdx.x;
    const int lane = tid & 63, wid = tid >> 6;
    __shared__ float red[4];
    #pragma unroll 1
    for (int h = 0; h < NH; ++h) {
        size_t base = ((size_t)row * NH + h) * DV;
        float o0 = o[base + tid], o1 = o[base + 256 + tid];
        float ss = o0*o0 + o1*o1;
        #pragma unroll
        for (int off = 32; off >= 1; off >>= 1) ss += __shfl_xor(ss, off);
        if (lane == 0) red[wid] = ss;
        __syncthreads();
        ss = red[0] + red[1] + red[2] + red[3];
        __syncthreads();
        float irms = rsqrtf(ss * (1.f / DV) + 1e-6f);
        size_t gbase = (size_t)row * VAL_DIM + h * DV;
        float g0 = gate[gbase + tid], g1 = gate[gbase + 256 + tid];
        o[base + tid]       = o0 * irms * wnorm[tid]       * (1.f / (1.f + expf(-g0)));
        o[base + 256 + tid] = o1 * irms * wnorm[256 + tid] * (1.f / (1.f + expf(-g1)));
    }
}

// ---------------------------------------------------------------------------
extern "C" void kernel_launch(void* const* d_in, const int* in_sizes, int n_in,
                              void* d_out, int out_size, void* d_ws, size_t ws_size,
                              hipStream_t stream)
{
    const float* x     = (const float*)d_in[0];
    const float* Wq    = (const float*)d_in[1];
    const float* Wk    = (const float*)d_in[2];
    const float* Wv    = (const float*)d_in[3];
    const float* Wa    = (const float*)d_in[4];
    const float* Wb    = (const float*)d_in[5];
    const float* decay = (const float*)d_in[6];
    const float* Dp    = (const float*)d_in[7];
    const float* A_log = (const float*)d_in[8];
    const float* dtb   = (const float*)d_in[9];
    const float* Wg    = (const float*)d_in[10];
    const float* Wo    = (const float*)d_in[11];
    const float* onw   = (const float*)d_in[12];
    float* out = (float*)d_out;

    float* ws   = (float*)d_ws;
    float* q    = ws;                                   // ROWS*KEY_DIM
    float* k    = q    + (size_t)ROWS * KEY_DIM;
    float* v    = k    + (size_t)ROWS * KEY_DIM;        // silu(v) GEMM out -> later o
    float* gate = v    + (size_t)ROWS * VAL_DIM;
    float* beta = gate + (size_t)ROWS * VAL_DIM;        // ROWS*NH
    float* graw = beta + (size_t)ROWS * NH;             // ROWS*NH (log decay)
    float* cinc = graw + (size_t)ROWS * NH;             // NG*TT
    float* cexc = cinc + (size_t)NG * TT;
    float* barr = cexc + (size_t)NG * TT;
    unsigned short* bf = (unsigned short*)(barr + (size_t)NG * TT);

    // phase 1 (projections)
    unsigned short* xb  = bf;                                   // ROWS*HID
    unsigned short* Wqb = xb  + (size_t)ROWS * HID;
    unsigned short* Wkb = Wqb + (size_t)KEY_DIM * HID;
    unsigned short* Wvb = Wkb + (size_t)KEY_DIM * HID;
    unsigned short* Wgb = Wvb + (size_t)VAL_DIM * HID;
    // phase R (chunked recurrence) — aliases phase 1 (dead by then)
    unsigned short* qb    = bf;                                 // NG*TT*DK
    unsigned short* kb    = qb  + (size_t)NG*TT*DK;
    unsigned short* bvb   = kb  + (size_t)NG*TT*DK;             // NG*TT*DV
    unsigned short* Ab    = bvb + (size_t)NG*TT*DV;             // NG*TT*TT
    unsigned short* Utb   = Ab  + (size_t)NG*TT*TT;             // NG*TT*TT (transposed)
    unsigned short* Minvb = Utb + (size_t)NG*TT*TT;             // NG*8*64*64
    // phase 2 (output projection) — aliases again
    unsigned short* ob  = bf;                                   // ROWS*VAL_DIM
    unsigned short* Wob = ob + (size_t)ROWS * VAL_DIM;

    dim3 blk(256);
    auto cblocks = [](size_t n) { size_t b = (n / 4 + 255) / 256; return (int)(b > 4096 ? 4096 : b); };

    cast_f32_bf16<<<cblocks((size_t)ROWS*HID),    blk, 0, stream>>>(x,  xb,  ROWS*HID/4);
    cast_f32_bf16<<<cblocks((size_t)KEY_DIM*HID), blk, 0, stream>>>(Wq, Wqb, KEY_DIM*HID/4);
    cast_f32_bf16<<<cblocks((size_t)KEY_DIM*HID), blk, 0, stream>>>(Wk, Wkb, KEY_DIM*HID/4);
    cast_f32_bf16<<<cblocks((size_t)VAL_DIM*HID), blk, 0, stream>>>(Wv, Wvb, VAL_DIM*HID/4);
    cast_f32_bf16<<<cblocks((size_t)VAL_DIM*HID), blk, 0, stream>>>(Wg, Wgb, VAL_DIM*HID/4);

    gemm_nt_bf16<<<dim3(KEY_DIM/128, ROWS/128), blk, 0, stream>>>(xb, Wqb, q,    ROWS, KEY_DIM, HID);
    gemm_nt_bf16<<<dim3(KEY_DIM/128, ROWS/128), blk, 0, stream>>>(xb, Wkb, k,    ROWS, KEY_DIM, HID);
    gemm_nt_bf16<<<dim3(VAL_DIM/128, ROWS/128), blk, 0, stream>>>(xb, Wvb, v,    ROWS, VAL_DIM, HID);
    gemm_nt_bf16<<<dim3(VAL_DIM/128, ROWS/128), blk, 0, stream>>>(xb, Wgb, gate, ROWS, VAL_DIM, HID);
    proj_ab<<<dim3(ROWS, 12), dim3(64), 0, stream>>>(x, Wa, Wb, A_log, dtb, beta, graw);

    prep_norm<<<dim3(ROWS), blk, 0, stream>>>(q, k, v, decay, Dp, beta, qb, kb, bvb);
    cumsum_pack<<<dim3(NG), dim3(64), 0, stream>>>(graw, beta, cinc, cexc, barr);
    a_mat<<<dim3(NG*36), blk, 0, stream>>>(kb, cinc, cexc, barr, Ab);
    minv_kern<<<dim3(NG*8), dim3(64), 0, stream>>>(Ab, Minvb);
    usolve<<<dim3(NG*4), blk, 0, stream>>>(Ab, Minvb, bvb, Utb);
    o_kern<<<dim3(NG*16), blk, 0, stream>>>(qb, kb, Utb, cinc, v);
    epilogue<<<dim3(ROWS), blk, 0, stream>>>(v, gate, onw);

    cast_f32_bf16<<<cblocks((size_t)ROWS*VAL_DIM), blk, 0, stream>>>(v,  ob,  ROWS*VAL_DIM/4);
    cast_f32_bf16<<<cblocks((size_t)HID*VAL_DIM),  blk, 0, stream>>>(Wo, Wob, HID*VAL_DIM/4);
    gemm_nt_bf16<<<dim3(HID/128, ROWS/128), blk, 0, stream>>>(ob, Wob, out, ROWS, HID, VAL_DIM);
}

// Round 6
// 599.662 us; speedup vs baseline: 4.4809x; 1.2227x over previous
//
#include <hip/hip_runtime.h>
#include <hip/hip_bf16.h>
#include <math.h>

#define BB 4
#define TT 512
#define HID 2048
#define NH 6
#define DK 256
#define DV 512
#define ROWS (BB*TT)          /* 2048 */
#define KEY_DIM (NH*DK)       /* 1536 */
#define VAL_DIM (NH*DV)       /* 3072 */
#define NG (BB*NH)            /* 24 groups */
#define NC 8                  /* chunks */
#define CL 64                 /* chunk length */

typedef __bf16 bf16x8 __attribute__((ext_vector_type(8)));
typedef float  f32x4  __attribute__((ext_vector_type(4)));

__device__ __forceinline__ unsigned short f2bf(float f) {
    unsigned int u = __float_as_uint(f);
    u = (u + 0x7FFFu + ((u >> 16) & 1u)) >> 16;
    return (unsigned short)u;
}
__device__ __forceinline__ float b2f(unsigned short u) {
    return __uint_as_float(((unsigned int)u) << 16);
}

// ---------------------------------------------------------------------------
// fp32 -> bf16 cast (RNE), vectorized.
// ---------------------------------------------------------------------------
__global__ __launch_bounds__(256) void cast_f32_bf16(
    const float* __restrict__ src, unsigned short* __restrict__ dst, int n4)
{
    int stride = gridDim.x * 256;
    for (int i = blockIdx.x * 256 + threadIdx.x; i < n4; i += stride) {
        float4 v = ((const float4*)src)[i];
        ushort4 o;
        o.x = f2bf(v.x); o.y = f2bf(v.y); o.z = f2bf(v.z); o.w = f2bf(v.w);
        ((ushort4*)dst)[i] = o;
    }
}

// ---------------------------------------------------------------------------
// bf16 NT GEMM: C[m,n] = sum_k A[m*K+k]*B[n*K+k], fp32 accumulate/output.
// 128x128 tile, BK=32, 256 threads = 4 waves in 2x2; 4x4 mfma 16x16x32 each.
// ---------------------------------------------------------------------------
__global__ __launch_bounds__(256) void gemm_nt_bf16(
    const unsigned short* __restrict__ A, const unsigned short* __restrict__ B,
    float* __restrict__ C, int M, int N, int K)
{
    __shared__ __align__(16) unsigned short As[128 * 32];
    __shared__ __align__(16) unsigned short Bs[128 * 32];
    const int tid  = threadIdx.x;
    const int lane = tid & 63;
    const int wave = tid >> 6;
    const int bm = blockIdx.y * 128;
    const int bn = blockIdx.x * 128;
    const int wr = (wave >> 1) * 64;
    const int wc = (wave & 1) * 64;
    const int fr = lane & 15;
    const int kg = lane >> 4;

    f32x4 acc[4][4] = {};

    for (int k0 = 0; k0 < K; k0 += 32) {
        #pragma unroll
        for (int s = 0; s < 2; ++s) {
            int e  = s * 256 + tid;
            int r  = e >> 2;
            int c8 = (e & 3) * 8;
            const unsigned short* ga = A + (size_t)(bm + r) * K + k0 + c8;
            const unsigned short* gb = B + (size_t)(bn + r) * K + k0 + c8;
            unsigned short* la = As + (size_t)(s * 256 + wave * 64) * 8;
            unsigned short* lb = Bs + (size_t)(s * 256 + wave * 64) * 8;
            __builtin_amdgcn_global_load_lds(
                (const __attribute__((address_space(1))) void*)ga,
                (__attribute__((address_space(3))) void*)la, 16, 0, 0);
            __builtin_amdgcn_global_load_lds(
                (const __attribute__((address_space(1))) void*)gb,
                (__attribute__((address_space(3))) void*)lb, 16, 0, 0);
        }
        __syncthreads();

        bf16x8 a[4], b[4];
        #pragma unroll
        for (int f = 0; f < 4; ++f) {
            a[f] = *(const bf16x8*)&As[(wr + f * 16 + fr) * 32 + kg * 8];
            b[f] = *(const bf16x8*)&Bs[(wc + f * 16 + fr) * 32 + kg * 8];
        }
        #pragma unroll
        for (int fm = 0; fm < 4; ++fm)
            #pragma unroll
            for (int fn = 0; fn < 4; ++fn)
                acc[fm][fn] = __builtin_amdgcn_mfma_f32_16x16x32_bf16(
                    a[fm], b[fn], acc[fm][fn], 0, 0, 0);
        __syncthreads();
    }

    #pragma unroll
    for (int fm = 0; fm < 4; ++fm)
        #pragma unroll
        for (int fn = 0; fn < 4; ++fn) {
            int col = bn + wc + fn * 16 + fr;
            #pragma unroll
            for (int i = 0; i < 4; ++i) {
                int row = bm + wr + fm * 16 + kg * 4 + i;
                C[(size_t)row * N + col] = acc[fm][fn][i];
            }
        }
}

// ---------------------------------------------------------------------------
// Small projections a,b -> graw (log-decay g), beta. grid (ROWS,12), 64 thr.
// ---------------------------------------------------------------------------
__global__ __launch_bounds__(64) void proj_ab(
    const float* __restrict__ x, const float* __restrict__ Wa, const float* __restrict__ Wb,
    const float* __restrict__ A_log, const float* __restrict__ dt_bias,
    float* __restrict__ beta, float* __restrict__ graw)
{
    const int row = blockIdx.x;
    const int j   = blockIdx.y;
    const bool is_a = (j < NH);
    const int h = is_a ? j : j - NH;
    const float* wrow = (is_a ? Wa : Wb) + (size_t)h * HID;
    const float4* x4 = (const float4*)(x + (size_t)row * HID);
    const float4* w4 = (const float4*)wrow;
    float s = 0.f;
    for (int i = threadIdx.x; i < HID/4; i += 64) {
        float4 a = x4[i], b = w4[i];
        s += a.x*b.x + a.y*b.y + a.z*b.z + a.w*b.w;
    }
    #pragma unroll
    for (int off = 32; off >= 1; off >>= 1) s += __shfl_xor(s, off);
    if (threadIdx.x == 0) {
        if (is_a) {
            float a  = s + dt_bias[h];
            float sp = (a > 20.f) ? a : log1pf(expf(a));
            graw[(size_t)row * NH + h] = -expf(A_log[h]) * sp;
        } else {
            beta[(size_t)row * NH + h] = 1.f / (1.f + expf(-s));
        }
    }
}

// ---------------------------------------------------------------------------
// Pointwise prep: silu(q,k), q-correction, l2norm (q scaled K^-0.5), silu(v).
// Writes bf16 per-group layouts: qb,kb [g][t][256], bvb = beta*silu(v).
// ---------------------------------------------------------------------------
__global__ __launch_bounds__(256) void prep_norm(
    const float* __restrict__ q, const float* __restrict__ k, const float* __restrict__ v,
    const float* __restrict__ decay, const float* __restrict__ D,
    const float* __restrict__ beta,
    unsigned short* __restrict__ qb, unsigned short* __restrict__ kb,
    unsigned short* __restrict__ bvb)
{
    const int row  = blockIdx.x;
    const int b    = row >> 9, t = row & 511;
    const int tid  = threadIdx.x;
    const int lane = tid & 63, wid = tid >> 6;
    __shared__ float red[8];
    #pragma unroll 1
    for (int h = 0; h < NH; ++h) {
        size_t idx = (size_t)row * KEY_DIM + h * DK + tid;
        float qr = q[idx], kr = k[idx];
        float ksil = kr / (1.f + expf(-kr));
        float qsil = qr / (1.f + expf(-qr));
        float coef = D[h] * (1.f / (1.f + expf(-decay[h])));
        float qc = qsil - coef * ksil;
        float sq = qc*qc, sk = ksil*ksil;
        #pragma unroll
        for (int off = 32; off >= 1; off >>= 1) {
            sq += __shfl_xor(sq, off);
            sk += __shfl_xor(sk, off);
        }
        if (lane == 0) { red[wid] = sq; red[4+wid] = sk; }
        __syncthreads();
        sq = red[0]+red[1]+red[2]+red[3];
        sk = red[4]+red[5]+red[6]+red[7];
        __syncthreads();
        float qinv = 0.0625f / fmaxf(sqrtf(sq), 1e-12f);
        float kinv = 1.f     / fmaxf(sqrtf(sk), 1e-12f);
        size_t gidx = (((size_t)(b*NH + h)) * TT + t) * DK + tid;
        qb[gidx] = f2bf(qc   * qinv);
        kb[gidx] = f2bf(ksil * kinv);
    }
    for (int jj = tid; jj < VAL_DIM; jj += 256) {
        int h2 = jj >> 9, dv = jj & 511;
        float xv = v[(size_t)row * VAL_DIM + jj];
        float sv = xv / (1.f + expf(-xv));
        float bt = beta[(size_t)row * NH + h2];
        bvb[(((size_t)(b*NH + h2)) * TT + t) * DV + dv] = f2bf(bt * sv);
    }
}

// ---------------------------------------------------------------------------
// Per-group cumulative log-decay + beta repack. 24 blocks x 64 threads.
// ---------------------------------------------------------------------------
__global__ __launch_bounds__(64) void cumsum_pack(
    const float* __restrict__ graw, const float* __restrict__ beta,
    float* __restrict__ cinc, float* __restrict__ cexc, float* __restrict__ barr)
{
    const int g = blockIdx.x;
    const int b = g / NH, h = g % NH;
    const int lane = threadIdx.x;
    float carry = 0.f;
    for (int c0 = 0; c0 < TT; c0 += 64) {
        int t = c0 + lane;
        size_t rowi = ((size_t)(b*TT + t)) * NH + h;
        float gv = graw[rowi];
        float x = gv;
        #pragma unroll
        for (int off = 1; off < 64; off <<= 1) {
            float n = __shfl_up(x, off);
            if (lane >= off) x += n;
        }
        float inc = carry + x;
        cinc[(size_t)g*TT + t] = inc;
        cexc[(size_t)g*TT + t] = inc - gv;
        barr[(size_t)g*TT + t] = beta[rowi];
        carry = __shfl(inc, 63);
    }
}

// ---------------------------------------------------------------------------
// A-matrix tiles: A[i,j] = beta_i * exp(cexc_i - cinc_j) * (k_i . k_j), j<i.
// grid = 24 groups x 36 lower-tri chunk pairs; batched fragment loads.
// ---------------------------------------------------------------------------
__global__ __launch_bounds__(256) void a_mat(
    const unsigned short* __restrict__ kb, const float* __restrict__ cinc,
    const float* __restrict__ cexc, const float* __restrict__ barr,
    unsigned short* __restrict__ Ab)
{
    const int blk = blockIdx.x;
    const int g = blk / 36;
    int p = blk % 36, m = 0, acc0 = 0;
    while (p >= acc0 + m + 1) { acc0 += m + 1; ++m; }
    const int l = p - acc0;
    const int tid = threadIdx.x, lane = tid & 63, w = tid >> 6;
    const int fr = lane & 15, kg = lane >> 4;
    const unsigned short* Km = kb + (((size_t)g*TT) + m*CL) * DK;
    const unsigned short* Kl = kb + (((size_t)g*TT) + l*CL) * DK;
    f32x4 acc[4] = {};
    #pragma unroll
    for (int ks = 0; ks < 8; ++ks) {
        bf16x8 a = *(const bf16x8*)(Km + (size_t)(w*16 + fr)*DK + ks*32 + kg*8);
        bf16x8 bb[4];
        #pragma unroll
        for (int fn = 0; fn < 4; ++fn)
            bb[fn] = *(const bf16x8*)(Kl + (size_t)(fn*16 + fr)*DK + ks*32 + kg*8);
        #pragma unroll
        for (int fn = 0; fn < 4; ++fn)
            acc[fn] = __builtin_amdgcn_mfma_f32_16x16x32_bf16(a, bb[fn], acc[fn], 0, 0, 0);
    }
    const float* ci = cinc + (size_t)g*TT;
    const float* ce = cexc + (size_t)g*TT;
    const float* bb2 = barr + (size_t)g*TT;
    #pragma unroll
    for (int fn = 0; fn < 4; ++fn) {
        int tj = l*CL + fn*16 + fr;
        float cj = ci[tj];
        #pragma unroll
        for (int r = 0; r < 4; ++r) {
            int ti = m*CL + w*16 + kg*4 + r;
            float val = 0.f;
            if (tj < ti) val = bb2[ti] * __expf(ce[ti] - cj) * acc[fn][r];
            Ab[((size_t)g*TT + ti)*TT + tj] = f2bf(val);
        }
    }
}

// ---------------------------------------------------------------------------
// Unit-lower-triangular inverse of (I + A_mm), 64x64, forward substitution.
// ---------------------------------------------------------------------------
__global__ __launch_bounds__(64) void minv_kern(
    const unsigned short* __restrict__ Ab, unsigned short* __restrict__ Minvb)
{
    const int blk = blockIdx.x;
    const int g = blk >> 3, m = blk & 7;
    const int col = threadIdx.x;
    __shared__ float X[64][65];
    __shared__ float arow[64];
    #pragma unroll 1
    for (int i = 0; i < 64; ++i) X[i][col] = (i == col) ? 1.f : 0.f;
    const unsigned short* Am = Ab + (((size_t)g*TT) + m*CL)*TT + m*CL;
    for (int i = 1; i < 64; ++i) {
        arow[col] = (col < i) ? b2f(Am[(size_t)i*TT + col]) : 0.f;
        __syncthreads();
        if (col < i) {
            float s = 0.f;
            for (int t = col; t < i; ++t) s += arow[t] * X[t][col];
            X[i][col] = -s;
        }
        __syncthreads();
    }
    unsigned short* out = Minvb + (size_t)blk * 64 * 64;
    #pragma unroll 1
    for (int i = 0; i < 64; ++i) out[(size_t)i*64 + col] = f2bf(X[i][col]);
}

// ---------------------------------------------------------------------------
// U-solve: (I+A) U = beta*V, block forward substitution over 8 chunks.
// grid = 24 groups x 8 v-slices(64). U stored transposed Utb[g][v][t] bf16.
// ---------------------------------------------------------------------------
__global__ __launch_bounds__(256) void usolve(
    const unsigned short* __restrict__ Ab, const unsigned short* __restrict__ Minvb,
    const unsigned short* __restrict__ bvb, unsigned short* __restrict__ Utb)
{
    const int blk = blockIdx.x;
    const int g = blk >> 3, vs = blk & 7;
    const int tid = threadIdx.x, lane = tid & 63, w = tid >> 6;
    const int fr = lane & 15, kg = lane >> 4;
    __shared__ __align__(16) unsigned short TACC[2][64][40];  // [i/32][v][i%32]

    for (int m = 0; m < NC; ++m) {
        f32x4 acc[4] = {};
        for (int l = 0; l < m; ++l) {
            const unsigned short* Aml = Ab + (((size_t)g*TT) + m*CL)*TT + l*CL;
            const unsigned short* Ul  = Utb + (((size_t)g*TT) + vs*64)*TT + l*CL;
            #pragma unroll
            for (int ks = 0; ks < 2; ++ks) {
                bf16x8 a = *(const bf16x8*)(Aml + (size_t)(w*16 + fr)*TT + ks*32 + kg*8);
                bf16x8 bb[4];
                #pragma unroll
                for (int fn = 0; fn < 4; ++fn)
                    bb[fn] = *(const bf16x8*)(Ul + (size_t)(fn*16 + fr)*TT + ks*32 + kg*8);
                #pragma unroll
                for (int fn = 0; fn < 4; ++fn)
                    acc[fn] = __builtin_amdgcn_mfma_f32_16x16x32_bf16(a, bb[fn], acc[fn], 0, 0, 0);
            }
        }
        __syncthreads();   // TACC reuse guard
        const unsigned short* bvg = bvb + (((size_t)g*TT) + m*CL)*DV + vs*64;
        #pragma unroll
        for (int fn = 0; fn < 4; ++fn) {
            int v = fn*16 + fr;
            #pragma unroll
            for (int r = 0; r < 4; ++r) {
                int i = w*16 + kg*4 + r;
                float rhs = b2f(bvg[(size_t)i*DV + v]) - acc[fn][r];
                TACC[i >> 5][v][i & 31] = f2bf(rhs);
            }
        }
        __syncthreads();
        const unsigned short* Mi = Minvb + (size_t)(g*8 + m) * 4096;
        f32x4 acc2[4] = {};
        #pragma unroll
        for (int ks = 0; ks < 2; ++ks) {
            bf16x8 a = *(const bf16x8*)(Mi + (size_t)(w*16 + fr)*64 + ks*32 + kg*8);
            bf16x8 bb[4];
            #pragma unroll
            for (int fn = 0; fn < 4; ++fn)
                bb[fn] = *(const bf16x8*)&TACC[ks][fn*16 + fr][kg*8];
            #pragma unroll
            for (int fn = 0; fn < 4; ++fn)
                acc2[fn] = __builtin_amdgcn_mfma_f32_16x16x32_bf16(a, bb[fn], acc2[fn], 0, 0, 0);
        }
        unsigned short* Um = Utb + (((size_t)g*TT) + vs*64)*TT + m*CL;
        #pragma unroll
        for (int fn = 0; fn < 4; ++fn) {
            int v = fn*16 + fr;
            #pragma unroll
            for (int r = 0; r < 4; ++r) {
                int i = w*16 + kg*4 + r;
                Um[(size_t)v*TT + i] = f2bf(acc2[fn][r]);
            }
        }
        __syncthreads();   // drain stores before next chunk reads U
    }
}

// ---------------------------------------------------------------------------
// Output: o_i = sum_{j<=i} exp(c_i - c_j)*(q_i . k_j) * u_j.
// Block = (g, m-pair {p, 7-p}, v-quarter 128). 9 balanced l-iters per block.
// K (64x256) and U (128x64) tiles async-staged into double-buffered LDS via
// global_load_lds with XOR bank-swizzle (linear dest + inverse-swizzled
// global source + swizzled ds_read, rule-21 pattern). Q hoisted to regs;
// cumulative decay staged in LDS. 3 barriers per l-iter.
// ---------------------------------------------------------------------------
__global__ __launch_bounds__(256) void o_kern(
    const unsigned short* __restrict__ qb, const unsigned short* __restrict__ kb,
    const unsigned short* __restrict__ Utb, const float* __restrict__ cinc,
    float* __restrict__ o)
{
    __shared__ __align__(16) unsigned short Kls[2][64*256];   // 64 KB
    __shared__ __align__(16) unsigned short Uls[2][128*64];   // 32 KB
    __shared__ __align__(16) unsigned short Ps[2][64][40];    // 10 KB
    __shared__ float cgl[TT];                                 // 2 KB

    const int blk = blockIdx.x;
    const int g  = blk >> 4;
    const int rm = blk & 15;
    const int pr = rm >> 2;          // pair 0..3  -> m in {pr, 7-pr}
    const int vq = rm & 3;           // v-quarter (128 cols)
    const int b = g / NH, h = g % NH;
    const int tid = threadIdx.x, lane = tid & 63, w = tid >> 6;
    const int fr = lane & 15, kg = lane >> 4;

    const unsigned short* kgrp = kb  + (size_t)g*TT*DK;
    const unsigned short* ugrp = Utb + ((size_t)g*TT + vq*128)*TT;

    // K stage: 2048 16B-chunks, contiguous tile; swz: c ^ ((c>>5)&7)
#define STAGE_K(buf, l) do { \
    _Pragma("unroll") \
    for (int s_ = 0; s_ < 8; ++s_) { \
        int slot_ = s_*256 + tid; \
        int gc_ = slot_ ^ ((slot_ >> 5) & 7); \
        const unsigned short* ga_ = kgrp + (size_t)(l)*CL*DK + gc_*8; \
        __builtin_amdgcn_global_load_lds( \
            (const __attribute__((address_space(1))) void*)ga_, \
            (__attribute__((address_space(3))) void*)&Kls[buf][slot_*8], 16, 0, 0); \
    } \
} while (0)

    // U stage: 1024 chunks, rows stride TT; swz: c ^ ((c>>3)&7)
#define STAGE_U(buf, l) do { \
    _Pragma("unroll") \
    for (int s_ = 0; s_ < 4; ++s_) { \
        int slot_ = s_*256 + tid; \
        int gc_ = slot_ ^ ((slot_ >> 3) & 7); \
        const unsigned short* ga_ = ugrp + (size_t)(gc_ >> 3)*TT + (l)*CL + (gc_ & 7)*8; \
        __builtin_amdgcn_global_load_lds( \
            (const __attribute__((address_space(1))) void*)ga_, \
            (__attribute__((address_space(3))) void*)&Uls[buf][slot_*8], 16, 0, 0); \
    } \
} while (0)

    // prologue: cumulative decay + first tiles
    cgl[tid]       = cinc[(size_t)g*TT + tid];
    cgl[tid + 256] = cinc[(size_t)g*TT + tid + 256];
    STAGE_K(0, 0);
    STAGE_U(0, 0);
    __syncthreads();

    int cur = 0;
    #pragma unroll 1
    for (int mi_idx = 0; mi_idx < 2; ++mi_idx) {
        const int mi = mi_idx ? (7 - pr) : pr;
        // hoist Q fragments for this m-chunk
        const unsigned short* Qm = qb + (((size_t)g*TT) + mi*CL) * DK + (size_t)(w*16 + fr)*DK;
        bf16x8 qf[8];
        #pragma unroll
        for (int ks = 0; ks < 8; ++ks) qf[ks] = *(const bf16x8*)(Qm + ks*32 + kg*8);

        f32x4 acc[8] = {};
        #pragma unroll 1
        for (int l = 0; l <= mi; ++l) {
            // issue next-tile stage (overlaps this iter's compute)
            if (l < mi)            { STAGE_K(cur^1, l+1); STAGE_U(cur^1, l+1); }
            else if (mi_idx == 0)  { STAGE_K(cur^1, 0);   STAGE_U(cur^1, 0);   }

            // scores: S = Q K^T from swizzled LDS
            f32x4 sacc[4] = {};
            #pragma unroll
            for (int ks = 0; ks < 8; ++ks) {
                bf16x8 bbf[4];
                #pragma unroll
                for (int fn = 0; fn < 4; ++fn) {
                    int row = fn*16 + fr;
                    int slot = (row*32 + ks*4 + kg) ^ (row & 7);
                    bbf[fn] = *(const bf16x8*)&Kls[cur][slot*8];
                }
                #pragma unroll
                for (int fn = 0; fn < 4; ++fn)
                    sacc[fn] = __builtin_amdgcn_mfma_f32_16x16x32_bf16(qf[ks], bbf[fn], sacc[fn], 0, 0, 0);
            }
            __syncthreads();   // Ps reuse guard (also orders cgl writes)

            // mask + decay-exp -> Ps (bf16)
            #pragma unroll
            for (int fn = 0; fn < 4; ++fn) {
                int jl = fn*16 + fr;
                float cjv = cgl[l*CL + jl];
                #pragma unroll
                for (int r = 0; r < 4; ++r) {
                    int il = w*16 + kg*4 + r;
                    float val = ((l*CL + jl) <= (mi*CL + il))
                              ? sacc[fn][r] * __expf(cgl[mi*CL + il] - cjv) : 0.f;
                    Ps[jl >> 5][il][jl & 31] = f2bf(val);
                }
            }
            __syncthreads();

            // PV: acc += Ps * U  (U from swizzled LDS)
            #pragma unroll
            for (int ks = 0; ks < 2; ++ks) {
                bf16x8 a = *(const bf16x8*)&Ps[ks][w*16 + fr][kg*8];
                bf16x8 bbf[8];
                #pragma unroll
                for (int fn = 0; fn < 8; ++fn) {
                    int vrow = fn*16 + fr;
                    int slot = (vrow*8 + ks*4 + kg) ^ (vrow & 7);
                    bbf[fn] = *(const bf16x8*)&Uls[cur][slot*8];
                }
                #pragma unroll
                for (int fn = 0; fn < 8; ++fn)
                    acc[fn] = __builtin_amdgcn_mfma_f32_16x16x32_bf16(a, bbf[fn], acc[fn], 0, 0, 0);
            }
            __syncthreads();   // buf overwrite guard + drains async stage
            cur ^= 1;
        }

        // store o for this m-chunk
        float* ob = o + ((size_t)(b*TT + mi*CL)) * VAL_DIM + h*DV + vq*128;
        #pragma unroll
        for (int fn = 0; fn < 8; ++fn) {
            int v = fn*16 + fr;
            #pragma unroll
            for (int r = 0; r < 4; ++r) {
                int il = w*16 + kg*4 + r;
                ob[(size_t)il*VAL_DIM + v] = acc[fn][r];
            }
        }
    }
#undef STAGE_K
#undef STAGE_U
}

// ---------------------------------------------------------------------------
// Gated RMSNorm epilogue (in place over o).
// ---------------------------------------------------------------------------
__global__ __launch_bounds__(256) void epilogue(
    float* __restrict__ o, const float* __restrict__ gate,
    const float* __restrict__ wnorm)
{
    const int row  = blockIdx.x;
    const int tid  = threadIdx.x;
    const int lane = tid & 63, wid = tid >> 6;
    __shared__ float red[4];
    #pragma unroll 1
    for (int h = 0; h < NH; ++h) {
        size_t base = ((size_t)row * NH + h) * DV;
        float o0 = o[base + tid], o1 = o[base + 256 + tid];
        float ss = o0*o0 + o1*o1;
        #pragma unroll
        for (int off = 32; off >= 1; off >>= 1) ss += __shfl_xor(ss, off);
        if (lane == 0) red[wid] = ss;
        __syncthreads();
        ss = red[0] + red[1] + red[2] + red[3];
        __syncthreads();
        float irms = rsqrtf(ss * (1.f / DV) + 1e-6f);
        size_t gbase = (size_t)row * VAL_DIM + h * DV;
        float g0 = gate[gbase + tid], g1 = gate[gbase + 256 + tid];
        o[base + tid]       = o0 * irms * wnorm[tid]       * (1.f / (1.f + expf(-g0)));
        o[base + 256 + tid] = o1 * irms * wnorm[256 + tid] * (1.f / (1.f + expf(-g1)));
    }
}

// ---------------------------------------------------------------------------
extern "C" void kernel_launch(void* const* d_in, const int* in_sizes, int n_in,
                              void* d_out, int out_size, void* d_ws, size_t ws_size,
                              hipStream_t stream)
{
    const float* x     = (const float*)d_in[0];
    const float* Wq    = (const float*)d_in[1];
    const float* Wk    = (const float*)d_in[2];
    const float* Wv    = (const float*)d_in[3];
    const float* Wa    = (const float*)d_in[4];
    const float* Wb    = (const float*)d_in[5];
    const float* decay = (const float*)d_in[6];
    const float* Dp    = (const float*)d_in[7];
    const float* A_log = (const float*)d_in[8];
    const float* dtb   = (const float*)d_in[9];
    const float* Wg    = (const float*)d_in[10];
    const float* Wo    = (const float*)d_in[11];
    const float* onw   = (const float*)d_in[12];
    float* out = (float*)d_out;

    float* ws   = (float*)d_ws;
    float* q    = ws;                                   // ROWS*KEY_DIM
    float* k    = q    + (size_t)ROWS * KEY_DIM;
    float* v    = k    + (size_t)ROWS * KEY_DIM;        // silu(v) GEMM out -> later o
    float* gate = v    + (size_t)ROWS * VAL_DIM;
    float* beta = gate + (size_t)ROWS * VAL_DIM;        // ROWS*NH
    float* graw = beta + (size_t)ROWS * NH;             // ROWS*NH (log decay)
    float* cinc = graw + (size_t)ROWS * NH;             // NG*TT
    float* cexc = cinc + (size_t)NG * TT;
    float* barr = cexc + (size_t)NG * TT;
    unsigned short* bf = (unsigned short*)(barr + (size_t)NG * TT);

    // phase 1 (projections)
    unsigned short* xb  = bf;                                   // ROWS*HID
    unsigned short* Wqb = xb  + (size_t)ROWS * HID;
    unsigned short* Wkb = Wqb + (size_t)KEY_DIM * HID;
    unsigned short* Wvb = Wkb + (size_t)KEY_DIM * HID;
    unsigned short* Wgb = Wvb + (size_t)VAL_DIM * HID;
    // phase R (chunked recurrence) — aliases phase 1 (dead by then)
    unsigned short* qb    = bf;                                 // NG*TT*DK
    unsigned short* kb    = qb  + (size_t)NG*TT*DK;
    unsigned short* bvb   = kb  + (size_t)NG*TT*DK;             // NG*TT*DV
    unsigned short* Ab    = bvb + (size_t)NG*TT*DV;             // NG*TT*TT
    unsigned short* Utb   = Ab  + (size_t)NG*TT*TT;             // NG*TT*TT (transposed)
    unsigned short* Minvb = Utb + (size_t)NG*TT*TT;             // NG*8*64*64
    // phase 2 (output projection) — aliases again
    unsigned short* ob  = bf;                                   // ROWS*VAL_DIM
    unsigned short* Wob = ob + (size_t)ROWS * VAL_DIM;

    dim3 blk(256);
    auto cblocks = [](size_t n) { size_t b = (n / 4 + 255) / 256; return (int)(b > 4096 ? 4096 : b); };

    cast_f32_bf16<<<cblocks((size_t)ROWS*HID),    blk, 0, stream>>>(x,  xb,  ROWS*HID/4);
    cast_f32_bf16<<<cblocks((size_t)KEY_DIM*HID), blk, 0, stream>>>(Wq, Wqb, KEY_DIM*HID/4);
    cast_f32_bf16<<<cblocks((size_t)KEY_DIM*HID), blk, 0, stream>>>(Wk, Wkb, KEY_DIM*HID/4);
    cast_f32_bf16<<<cblocks((size_t)VAL_DIM*HID), blk, 0, stream>>>(Wv, Wvb, VAL_DIM*HID/4);
    cast_f32_bf16<<<cblocks((size_t)VAL_DIM*HID), blk, 0, stream>>>(Wg, Wgb, VAL_DIM*HID/4);

    gemm_nt_bf16<<<dim3(KEY_DIM/128, ROWS/128), blk, 0, stream>>>(xb, Wqb, q,    ROWS, KEY_DIM, HID);
    gemm_nt_bf16<<<dim3(KEY_DIM/128, ROWS/128), blk, 0, stream>>>(xb, Wkb, k,    ROWS, KEY_DIM, HID);
    gemm_nt_bf16<<<dim3(VAL_DIM/128, ROWS/128), blk, 0, stream>>>(xb, Wvb, v,    ROWS, VAL_DIM, HID);
    gemm_nt_bf16<<<dim3(VAL_DIM/128, ROWS/128), blk, 0, stream>>>(xb, Wgb, gate, ROWS, VAL_DIM, HID);
    proj_ab<<<dim3(ROWS, 12), dim3(64), 0, stream>>>(x, Wa, Wb, A_log, dtb, beta, graw);

    prep_norm<<<dim3(ROWS), blk, 0, stream>>>(q, k, v, decay, Dp, beta, qb, kb, bvb);
    cumsum_pack<<<dim3(NG), dim3(64), 0, stream>>>(graw, beta, cinc, cexc, barr);
    a_mat<<<dim3(NG*36), blk, 0, stream>>>(kb, cinc, cexc, barr, Ab);
    minv_kern<<<dim3(NG*8), dim3(64), 0, stream>>>(Ab, Minvb);
    usolve<<<dim3(NG*8), blk, 0, stream>>>(Ab, Minvb, bvb, Utb);
    o_kern<<<dim3(NG*16), blk, 0, stream>>>(qb, kb, Utb, cinc, v);
    epilogue<<<dim3(ROWS), blk, 0, stream>>>(v, gate, onw);

    cast_f32_bf16<<<cblocks((size_t)ROWS*VAL_DIM), blk, 0, stream>>>(v,  ob,  ROWS*VAL_DIM/4);
    cast_f32_bf16<<<cblocks((size_t)HID*VAL_DIM),  blk, 0, stream>>>(Wo, Wob, HID*VAL_DIM/4);
    gemm_nt_bf16<<<dim3(HID/128, ROWS/128), blk, 0, stream>>>(ob, Wob, out, ROWS, HID, VAL_DIM);
}

// Round 7
// 529.610 us; speedup vs baseline: 5.0736x; 1.1323x over previous
//
#include <hip/hip_runtime.h>
#include <hip/hip_bf16.h>
#include <math.h>

#define BB 4
#define TT 512
#define HID 2048
#define NH 6
#define DK 256
#define DV 512
#define ROWS (BB*TT)          /* 2048 */
#define KEY_DIM (NH*DK)       /* 1536 */
#define VAL_DIM (NH*DV)       /* 3072 */
#define NG (BB*NH)            /* 24 groups */
#define NC 8                  /* chunks */
#define CL 64                 /* chunk length */

typedef __bf16 bf16x8 __attribute__((ext_vector_type(8)));
typedef float  f32x4  __attribute__((ext_vector_type(4)));

__device__ __forceinline__ unsigned short f2bf(float f) {
    unsigned int u = __float_as_uint(f);
    u = (u + 0x7FFFu + ((u >> 16) & 1u)) >> 16;
    return (unsigned short)u;
}
__device__ __forceinline__ float b2f(unsigned short u) {
    return __uint_as_float(((unsigned int)u) << 16);
}

// ---------------------------------------------------------------------------
// fp32 -> bf16 cast (RNE), vectorized.
// ---------------------------------------------------------------------------
__global__ __launch_bounds__(256) void cast_f32_bf16(
    const float* __restrict__ src, unsigned short* __restrict__ dst, int n4)
{
    int stride = gridDim.x * 256;
    for (int i = blockIdx.x * 256 + threadIdx.x; i < n4; i += stride) {
        float4 v = ((const float4*)src)[i];
        ushort4 o;
        o.x = f2bf(v.x); o.y = f2bf(v.y); o.z = f2bf(v.z); o.w = f2bf(v.w);
        ((ushort4*)dst)[i] = o;
    }
}

// ---------------------------------------------------------------------------
// bf16 NT GEMM: C[m,n] = sum_k A[m*K+k]*B[n*K+k], fp32 accumulate/output.
// 128x128 tile, BK=32, 256 threads = 4 waves in 2x2; 4x4 mfma 16x16x32 each.
// ---------------------------------------------------------------------------
__global__ __launch_bounds__(256) void gemm_nt_bf16(
    const unsigned short* __restrict__ A, const unsigned short* __restrict__ B,
    float* __restrict__ C, int M, int N, int K)
{
    __shared__ __align__(16) unsigned short As[128 * 32];
    __shared__ __align__(16) unsigned short Bs[128 * 32];
    const int tid  = threadIdx.x;
    const int lane = tid & 63;
    const int wave = tid >> 6;
    const int bm = blockIdx.y * 128;
    const int bn = blockIdx.x * 128;
    const int wr = (wave >> 1) * 64;
    const int wc = (wave & 1) * 64;
    const int fr = lane & 15;
    const int kg = lane >> 4;

    f32x4 acc[4][4] = {};

    for (int k0 = 0; k0 < K; k0 += 32) {
        #pragma unroll
        for (int s = 0; s < 2; ++s) {
            int e  = s * 256 + tid;
            int r  = e >> 2;
            int c8 = (e & 3) * 8;
            const unsigned short* ga = A + (size_t)(bm + r) * K + k0 + c8;
            const unsigned short* gb = B + (size_t)(bn + r) * K + k0 + c8;
            unsigned short* la = As + (size_t)(s * 256 + wave * 64) * 8;
            unsigned short* lb = Bs + (size_t)(s * 256 + wave * 64) * 8;
            __builtin_amdgcn_global_load_lds(
                (const __attribute__((address_space(1))) void*)ga,
                (__attribute__((address_space(3))) void*)la, 16, 0, 0);
            __builtin_amdgcn_global_load_lds(
                (const __attribute__((address_space(1))) void*)gb,
                (__attribute__((address_space(3))) void*)lb, 16, 0, 0);
        }
        __syncthreads();

        bf16x8 a[4], b[4];
        #pragma unroll
        for (int f = 0; f < 4; ++f) {
            a[f] = *(const bf16x8*)&As[(wr + f * 16 + fr) * 32 + kg * 8];
            b[f] = *(const bf16x8*)&Bs[(wc + f * 16 + fr) * 32 + kg * 8];
        }
        #pragma unroll
        for (int fm = 0; fm < 4; ++fm)
            #pragma unroll
            for (int fn = 0; fn < 4; ++fn)
                acc[fm][fn] = __builtin_amdgcn_mfma_f32_16x16x32_bf16(
                    a[fm], b[fn], acc[fm][fn], 0, 0, 0);
        __syncthreads();
    }

    #pragma unroll
    for (int fm = 0; fm < 4; ++fm)
        #pragma unroll
        for (int fn = 0; fn < 4; ++fn) {
            int col = bn + wc + fn * 16 + fr;
            #pragma unroll
            for (int i = 0; i < 4; ++i) {
                int row = bm + wr + fm * 16 + kg * 4 + i;
                C[(size_t)row * N + col] = acc[fm][fn][i];
            }
        }
}

// ---------------------------------------------------------------------------
// Small projections a,b -> graw (log-decay g), beta. grid (ROWS,12), 64 thr.
// ---------------------------------------------------------------------------
__global__ __launch_bounds__(64) void proj_ab(
    const float* __restrict__ x, const float* __restrict__ Wa, const float* __restrict__ Wb,
    const float* __restrict__ A_log, const float* __restrict__ dt_bias,
    float* __restrict__ beta, float* __restrict__ graw)
{
    const int row = blockIdx.x;
    const int j   = blockIdx.y;
    const bool is_a = (j < NH);
    const int h = is_a ? j : j - NH;
    const float* wrow = (is_a ? Wa : Wb) + (size_t)h * HID;
    const float4* x4 = (const float4*)(x + (size_t)row * HID);
    const float4* w4 = (const float4*)wrow;
    float s = 0.f;
    for (int i = threadIdx.x; i < HID/4; i += 64) {
        float4 a = x4[i], b = w4[i];
        s += a.x*b.x + a.y*b.y + a.z*b.z + a.w*b.w;
    }
    #pragma unroll
    for (int off = 32; off >= 1; off >>= 1) s += __shfl_xor(s, off);
    if (threadIdx.x == 0) {
        if (is_a) {
            float a  = s + dt_bias[h];
            float sp = (a > 20.f) ? a : log1pf(expf(a));
            graw[(size_t)row * NH + h] = -expf(A_log[h]) * sp;
        } else {
            beta[(size_t)row * NH + h] = 1.f / (1.f + expf(-s));
        }
    }
}

// ---------------------------------------------------------------------------
// Pointwise prep: silu(q,k), q-correction, l2norm (q scaled K^-0.5), silu(v).
// Writes bf16 per-group layouts: qb,kb [g][t][256], bvb = beta*silu(v).
// ---------------------------------------------------------------------------
__global__ __launch_bounds__(256) void prep_norm(
    const float* __restrict__ q, const float* __restrict__ k, const float* __restrict__ v,
    const float* __restrict__ decay, const float* __restrict__ D,
    const float* __restrict__ beta,
    unsigned short* __restrict__ qb, unsigned short* __restrict__ kb,
    unsigned short* __restrict__ bvb)
{
    const int row  = blockIdx.x;
    const int b    = row >> 9, t = row & 511;
    const int tid  = threadIdx.x;
    const int lane = tid & 63, wid = tid >> 6;
    __shared__ float red[8];
    #pragma unroll 1
    for (int h = 0; h < NH; ++h) {
        size_t idx = (size_t)row * KEY_DIM + h * DK + tid;
        float qr = q[idx], kr = k[idx];
        float ksil = kr / (1.f + expf(-kr));
        float qsil = qr / (1.f + expf(-qr));
        float coef = D[h] * (1.f / (1.f + expf(-decay[h])));
        float qc = qsil - coef * ksil;
        float sq = qc*qc, sk = ksil*ksil;
        #pragma unroll
        for (int off = 32; off >= 1; off >>= 1) {
            sq += __shfl_xor(sq, off);
            sk += __shfl_xor(sk, off);
        }
        if (lane == 0) { red[wid] = sq; red[4+wid] = sk; }
        __syncthreads();
        sq = red[0]+red[1]+red[2]+red[3];
        sk = red[4]+red[5]+red[6]+red[7];
        __syncthreads();
        float qinv = 0.0625f / fmaxf(sqrtf(sq), 1e-12f);
        float kinv = 1.f     / fmaxf(sqrtf(sk), 1e-12f);
        size_t gidx = (((size_t)(b*NH + h)) * TT + t) * DK + tid;
        qb[gidx] = f2bf(qc   * qinv);
        kb[gidx] = f2bf(ksil * kinv);
    }
    for (int jj = tid; jj < VAL_DIM; jj += 256) {
        int h2 = jj >> 9, dv = jj & 511;
        float xv = v[(size_t)row * VAL_DIM + jj];
        float sv = xv / (1.f + expf(-xv));
        float bt = beta[(size_t)row * NH + h2];
        bvb[(((size_t)(b*NH + h2)) * TT + t) * DV + dv] = f2bf(bt * sv);
    }
}

// ---------------------------------------------------------------------------
// Per-group cumulative log-decay + beta repack. 24 blocks x 64 threads.
// ---------------------------------------------------------------------------
__global__ __launch_bounds__(64) void cumsum_pack(
    const float* __restrict__ graw, const float* __restrict__ beta,
    float* __restrict__ cinc, float* __restrict__ cexc, float* __restrict__ barr)
{
    const int g = blockIdx.x;
    const int b = g / NH, h = g % NH;
    const int lane = threadIdx.x;
    float carry = 0.f;
    for (int c0 = 0; c0 < TT; c0 += 64) {
        int t = c0 + lane;
        size_t rowi = ((size_t)(b*TT + t)) * NH + h;
        float gv = graw[rowi];
        float x = gv;
        #pragma unroll
        for (int off = 1; off < 64; off <<= 1) {
            float n = __shfl_up(x, off);
            if (lane >= off) x += n;
        }
        float inc = carry + x;
        cinc[(size_t)g*TT + t] = inc;
        cexc[(size_t)g*TT + t] = inc - gv;
        barr[(size_t)g*TT + t] = beta[rowi];
        carry = __shfl(inc, 63);
    }
}

// ---------------------------------------------------------------------------
// A-matrix tiles: A[i,j] = beta_i * exp(cexc_i - cinc_j) * (k_i . k_j), j<i.
// grid = 24 groups x 36 lower-tri chunk pairs; batched fragment loads.
// Diagonal tiles have exact 0 for j>=i (minv_kern relies on this).
// ---------------------------------------------------------------------------
__global__ __launch_bounds__(256) void a_mat(
    const unsigned short* __restrict__ kb, const float* __restrict__ cinc,
    const float* __restrict__ cexc, const float* __restrict__ barr,
    unsigned short* __restrict__ Ab)
{
    const int blk = blockIdx.x;
    const int g = blk / 36;
    int p = blk % 36, m = 0, acc0 = 0;
    while (p >= acc0 + m + 1) { acc0 += m + 1; ++m; }
    const int l = p - acc0;
    const int tid = threadIdx.x, lane = tid & 63, w = tid >> 6;
    const int fr = lane & 15, kg = lane >> 4;
    const unsigned short* Km = kb + (((size_t)g*TT) + m*CL) * DK;
    const unsigned short* Kl = kb + (((size_t)g*TT) + l*CL) * DK;
    f32x4 acc[4] = {};
    #pragma unroll
    for (int ks = 0; ks < 8; ++ks) {
        bf16x8 a = *(const bf16x8*)(Km + (size_t)(w*16 + fr)*DK + ks*32 + kg*8);
        bf16x8 bb[4];
        #pragma unroll
        for (int fn = 0; fn < 4; ++fn)
            bb[fn] = *(const bf16x8*)(Kl + (size_t)(fn*16 + fr)*DK + ks*32 + kg*8);
        #pragma unroll
        for (int fn = 0; fn < 4; ++fn)
            acc[fn] = __builtin_amdgcn_mfma_f32_16x16x32_bf16(a, bb[fn], acc[fn], 0, 0, 0);
    }
    const float* ci = cinc + (size_t)g*TT;
    const float* ce = cexc + (size_t)g*TT;
    const float* bb2 = barr + (size_t)g*TT;
    #pragma unroll
    for (int fn = 0; fn < 4; ++fn) {
        int tj = l*CL + fn*16 + fr;
        float cj = ci[tj];
        #pragma unroll
        for (int r = 0; r < 4; ++r) {
            int ti = m*CL + w*16 + kg*4 + r;
            float val = 0.f;
            if (tj < ti) val = bb2[ti] * __expf(ce[ti] - cj) * acc[fn][r];
            Ab[((size_t)g*TT + ti)*TT + tj] = f2bf(val);
        }
    }
}

// ---------------------------------------------------------------------------
// Unit-lower-triangular inverse of (I + A_mm), 64x64, forward substitution.
// v2: wave-synchronous, fully LDS-resident. 192 blocks x 64 threads.
// Lane col owns column col of X (stored as Xt[col][t] -> lane-private row:
// no cross-lane communication, no barriers in the serial loop). A staged
// once into LDS ([64][72] bf16, 16B-aligned rows, broadcast b128 reads).
// Dot runs over full 8-chunks; A's exact zeros (j>=i) make the extra terms
// contribute +0.0 -> bit-identical to strict sequential substitution.
// ---------------------------------------------------------------------------
__global__ __launch_bounds__(64) void minv_kern(
    const unsigned short* __restrict__ Ab, unsigned short* __restrict__ Minvb)
{
    const int blk = blockIdx.x;
    const int g = blk >> 3, m = blk & 7;
    const int col = threadIdx.x;
    __shared__ __align__(16) unsigned short Asub[64][72];  // bf16, padded rows
    __shared__ __align__(16) float Xt[64][68];             // Xt[col][t] = X[t][col]

    const unsigned short* Am = Ab + (((size_t)g*TT) + m*CL)*TT + m*CL;
    // stage A: row r loaded by all 64 lanes (128B coalesced per row)
    #pragma unroll 4
    for (int r = 0; r < 64; ++r)
        Asub[r][col] = Am[(size_t)r*TT + col];
    // init Xt: lane col owns column col (identity)
    #pragma unroll
    for (int t4 = 0; t4 < 17; ++t4)
        *(float4*)&Xt[col][t4*4] = make_float4(0.f, 0.f, 0.f, 0.f);
    Xt[col][col] = 1.f;
    __syncthreads();

    #pragma unroll 1
    for (int i = 1; i < 64; ++i) {
        const int nch = (i + 7) >> 3;
        float s = 0.f;
        #pragma unroll 1
        for (int c8 = 0; c8 < nch; ++c8) {
            ushort4 a0 = *(const ushort4*)&Asub[i][c8*8];
            ushort4 a1 = *(const ushort4*)&Asub[i][c8*8 + 4];
            float4  x0 = *(const float4*)&Xt[col][c8*8];
            float4  x1 = *(const float4*)&Xt[col][c8*8 + 4];
            s += b2f(a0.x)*x0.x; s += b2f(a0.y)*x0.y;
            s += b2f(a0.z)*x0.z; s += b2f(a0.w)*x0.w;
            s += b2f(a1.x)*x1.x; s += b2f(a1.y)*x1.y;
            s += b2f(a1.z)*x1.z; s += b2f(a1.w)*x1.w;
        }
        if (col < i) Xt[col][i] = -s;
    }

    // write out (row-major Minv, coalesced: lane = col)
    unsigned short* out = Minvb + (size_t)blk * 4096;
    #pragma unroll 4
    for (int r = 0; r < 64; ++r)
        out[(size_t)r*64 + col] = f2bf(Xt[col][r]);
}

// ---------------------------------------------------------------------------
// U-solve: (I+A) U = beta*V, block forward substitution over 8 chunks.
// grid = 24 groups x 8 v-slices(64). U stored transposed Utb[g][v][t] bf16.
// ---------------------------------------------------------------------------
__global__ __launch_bounds__(256) void usolve(
    const unsigned short* __restrict__ Ab, const unsigned short* __restrict__ Minvb,
    const unsigned short* __restrict__ bvb, unsigned short* __restrict__ Utb)
{
    const int blk = blockIdx.x;
    const int g = blk >> 3, vs = blk & 7;
    const int tid = threadIdx.x, lane = tid & 63, w = tid >> 6;
    const int fr = lane & 15, kg = lane >> 4;
    __shared__ __align__(16) unsigned short TACC[2][64][40];  // [i/32][v][i%32]

    for (int m = 0; m < NC; ++m) {
        f32x4 acc[4] = {};
        for (int l = 0; l < m; ++l) {
            const unsigned short* Aml = Ab + (((size_t)g*TT) + m*CL)*TT + l*CL;
            const unsigned short* Ul  = Utb + (((size_t)g*TT) + vs*64)*TT + l*CL;
            #pragma unroll
            for (int ks = 0; ks < 2; ++ks) {
                bf16x8 a = *(const bf16x8*)(Aml + (size_t)(w*16 + fr)*TT + ks*32 + kg*8);
                bf16x8 bb[4];
                #pragma unroll
                for (int fn = 0; fn < 4; ++fn)
                    bb[fn] = *(const bf16x8*)(Ul + (size_t)(fn*16 + fr)*TT + ks*32 + kg*8);
                #pragma unroll
                for (int fn = 0; fn < 4; ++fn)
                    acc[fn] = __builtin_amdgcn_mfma_f32_16x16x32_bf16(a, bb[fn], acc[fn], 0, 0, 0);
            }
        }
        __syncthreads();   // TACC reuse guard
        const unsigned short* bvg = bvb + (((size_t)g*TT) + m*CL)*DV + vs*64;
        #pragma unroll
        for (int fn = 0; fn < 4; ++fn) {
            int v = fn*16 + fr;
            #pragma unroll
            for (int r = 0; r < 4; ++r) {
                int i = w*16 + kg*4 + r;
                float rhs = b2f(bvg[(size_t)i*DV + v]) - acc[fn][r];
                TACC[i >> 5][v][i & 31] = f2bf(rhs);
            }
        }
        __syncthreads();
        const unsigned short* Mi = Minvb + (size_t)(g*8 + m) * 4096;
        f32x4 acc2[4] = {};
        #pragma unroll
        for (int ks = 0; ks < 2; ++ks) {
            bf16x8 a = *(const bf16x8*)(Mi + (size_t)(w*16 + fr)*64 + ks*32 + kg*8);
            bf16x8 bb[4];
            #pragma unroll
            for (int fn = 0; fn < 4; ++fn)
                bb[fn] = *(const bf16x8*)&TACC[ks][fn*16 + fr][kg*8];
            #pragma unroll
            for (int fn = 0; fn < 4; ++fn)
                acc2[fn] = __builtin_amdgcn_mfma_f32_16x16x32_bf16(a, bb[fn], acc2[fn], 0, 0, 0);
        }
        unsigned short* Um = Utb + (((size_t)g*TT) + vs*64)*TT + m*CL;
        #pragma unroll
        for (int fn = 0; fn < 4; ++fn) {
            int v = fn*16 + fr;
            #pragma unroll
            for (int r = 0; r < 4; ++r) {
                int i = w*16 + kg*4 + r;
                Um[(size_t)v*TT + i] = f2bf(acc2[fn][r]);
            }
        }
        __syncthreads();   // drain stores before next chunk reads U
    }
}

// ---------------------------------------------------------------------------
// Output: o_i = sum_{j<=i} exp(c_i - c_j)*(q_i . k_j) * u_j.
// Block = (g, m-pair {p, 7-p}, v-quarter 128). 9 balanced l-iters per block.
// K (64x256) and U (128x64) tiles async-staged into double-buffered LDS via
// global_load_lds with XOR bank-swizzle (linear dest + inverse-swizzled
// global source + swizzled ds_read, rule-21 pattern). Q hoisted to regs;
// cumulative decay staged in LDS. 3 barriers per l-iter.
// ---------------------------------------------------------------------------
__global__ __launch_bounds__(256) void o_kern(
    const unsigned short* __restrict__ qb, const unsigned short* __restrict__ kb,
    const unsigned short* __restrict__ Utb, const float* __restrict__ cinc,
    float* __restrict__ o)
{
    __shared__ __align__(16) unsigned short Kls[2][64*256];   // 64 KB
    __shared__ __align__(16) unsigned short Uls[2][128*64];   // 32 KB
    __shared__ __align__(16) unsigned short Ps[2][64][40];    // 10 KB
    __shared__ float cgl[TT];                                 // 2 KB

    const int blk = blockIdx.x;
    const int g  = blk >> 4;
    const int rm = blk & 15;
    const int pr = rm >> 2;          // pair 0..3  -> m in {pr, 7-pr}
    const int vq = rm & 3;           // v-quarter (128 cols)
    const int b = g / NH, h = g % NH;
    const int tid = threadIdx.x, lane = tid & 63, w = tid >> 6;
    const int fr = lane & 15, kg = lane >> 4;

    const unsigned short* kgrp = kb  + (size_t)g*TT*DK;
    const unsigned short* ugrp = Utb + ((size_t)g*TT + vq*128)*TT;

    // K stage: 2048 16B-chunks, contiguous tile; swz: c ^ ((c>>5)&7)
#define STAGE_K(buf, l) do { \
    _Pragma("unroll") \
    for (int s_ = 0; s_ < 8; ++s_) { \
        int slot_ = s_*256 + tid; \
        int gc_ = slot_ ^ ((slot_ >> 5) & 7); \
        const unsigned short* ga_ = kgrp + (size_t)(l)*CL*DK + gc_*8; \
        __builtin_amdgcn_global_load_lds( \
            (const __attribute__((address_space(1))) void*)ga_, \
            (__attribute__((address_space(3))) void*)&Kls[buf][slot_*8], 16, 0, 0); \
    } \
} while (0)

    // U stage: 1024 chunks, rows stride TT; swz: c ^ ((c>>3)&7)
#define STAGE_U(buf, l) do { \
    _Pragma("unroll") \
    for (int s_ = 0; s_ < 4; ++s_) { \
        int slot_ = s_*256 + tid; \
        int gc_ = slot_ ^ ((slot_ >> 3) & 7); \
        const unsigned short* ga_ = ugrp + (size_t)(gc_ >> 3)*TT + (l)*CL + (gc_ & 7)*8; \
        __builtin_amdgcn_global_load_lds( \
            (const __attribute__((address_space(1))) void*)ga_, \
            (__attribute__((address_space(3))) void*)&Uls[buf][slot_*8], 16, 0, 0); \
    } \
} while (0)

    // prologue: cumulative decay + first tiles
    cgl[tid]       = cinc[(size_t)g*TT + tid];
    cgl[tid + 256] = cinc[(size_t)g*TT + tid + 256];
    STAGE_K(0, 0);
    STAGE_U(0, 0);
    __syncthreads();

    int cur = 0;
    #pragma unroll 1
    for (int mi_idx = 0; mi_idx < 2; ++mi_idx) {
        const int mi = mi_idx ? (7 - pr) : pr;
        // hoist Q fragments for this m-chunk
        const unsigned short* Qm = qb + (((size_t)g*TT) + mi*CL) * DK + (size_t)(w*16 + fr)*DK;
        bf16x8 qf[8];
        #pragma unroll
        for (int ks = 0; ks < 8; ++ks) qf[ks] = *(const bf16x8*)(Qm + ks*32 + kg*8);

        f32x4 acc[8] = {};
        #pragma unroll 1
        for (int l = 0; l <= mi; ++l) {
            // issue next-tile stage (overlaps this iter's compute)
            if (l < mi)            { STAGE_K(cur^1, l+1); STAGE_U(cur^1, l+1); }
            else if (mi_idx == 0)  { STAGE_K(cur^1, 0);   STAGE_U(cur^1, 0);   }

            // scores: S = Q K^T from swizzled LDS
            f32x4 sacc[4] = {};
            #pragma unroll
            for (int ks = 0; ks < 8; ++ks) {
                bf16x8 bbf[4];
                #pragma unroll
                for (int fn = 0; fn < 4; ++fn) {
                    int row = fn*16 + fr;
                    int slot = (row*32 + ks*4 + kg) ^ (row & 7);
                    bbf[fn] = *(const bf16x8*)&Kls[cur][slot*8];
                }
                #pragma unroll
                for (int fn = 0; fn < 4; ++fn)
                    sacc[fn] = __builtin_amdgcn_mfma_f32_16x16x32_bf16(qf[ks], bbf[fn], sacc[fn], 0, 0, 0);
            }
            __syncthreads();   // Ps reuse guard (also orders cgl writes)

            // mask + decay-exp -> Ps (bf16)
            #pragma unroll
            for (int fn = 0; fn < 4; ++fn) {
                int jl = fn*16 + fr;
                float cjv = cgl[l*CL + jl];
                #pragma unroll
                for (int r = 0; r < 4; ++r) {
                    int il = w*16 + kg*4 + r;
                    float val = ((l*CL + jl) <= (mi*CL + il))
                              ? sacc[fn][r] * __expf(cgl[mi*CL + il] - cjv) : 0.f;
                    Ps[jl >> 5][il][jl & 31] = f2bf(val);
                }
            }
            __syncthreads();

            // PV: acc += Ps * U  (U from swizzled LDS)
            #pragma unroll
            for (int ks = 0; ks < 2; ++ks) {
                bf16x8 a = *(const bf16x8*)&Ps[ks][w*16 + fr][kg*8];
                bf16x8 bbf[8];
                #pragma unroll
                for (int fn = 0; fn < 8; ++fn) {
                    int vrow = fn*16 + fr;
                    int slot = (vrow*8 + ks*4 + kg) ^ (vrow & 7);
                    bbf[fn] = *(const bf16x8*)&Uls[cur][slot*8];
                }
                #pragma unroll
                for (int fn = 0; fn < 8; ++fn)
                    acc[fn] = __builtin_amdgcn_mfma_f32_16x16x32_bf16(a, bbf[fn], acc[fn], 0, 0, 0);
            }
            __syncthreads();   // buf overwrite guard + drains async stage
            cur ^= 1;
        }

        // store o for this m-chunk
        float* ob = o + ((size_t)(b*TT + mi*CL)) * VAL_DIM + h*DV + vq*128;
        #pragma unroll
        for (int fn = 0; fn < 8; ++fn) {
            int v = fn*16 + fr;
            #pragma unroll
            for (int r = 0; r < 4; ++r) {
                int il = w*16 + kg*4 + r;
                ob[(size_t)il*VAL_DIM + v] = acc[fn][r];
            }
        }
    }
#undef STAGE_K
#undef STAGE_U
}

// ---------------------------------------------------------------------------
// Gated RMSNorm epilogue (in place over o).
// ---------------------------------------------------------------------------
__global__ __launch_bounds__(256) void epilogue(
    float* __restrict__ o, const float* __restrict__ gate,
    const float* __restrict__ wnorm)
{
    const int row  = blockIdx.x;
    const int tid  = threadIdx.x;
    const int lane = tid & 63, wid = tid >> 6;
    __shared__ float red[4];
    #pragma unroll 1
    for (int h = 0; h < NH; ++h) {
        size_t base = ((size_t)row * NH + h) * DV;
        float o0 = o[base + tid], o1 = o[base + 256 + tid];
        float ss = o0*o0 + o1*o1;
        #pragma unroll
        for (int off = 32; off >= 1; off >>= 1) ss += __shfl_xor(ss, off);
        if (lane == 0) red[wid] = ss;
        __syncthreads();
        ss = red[0] + red[1] + red[2] + red[3];
        __syncthreads();
        float irms = rsqrtf(ss * (1.f / DV) + 1e-6f);
        size_t gbase = (size_t)row * VAL_DIM + h * DV;
        float g0 = gate[gbase + tid], g1 = gate[gbase + 256 + tid];
        o[base + tid]       = o0 * irms * wnorm[tid]       * (1.f / (1.f + expf(-g0)));
        o[base + 256 + tid] = o1 * irms * wnorm[256 + tid] * (1.f / (1.f + expf(-g1)));
    }
}

// ---------------------------------------------------------------------------
extern "C" void kernel_launch(void* const* d_in, const int* in_sizes, int n_in,
                              void* d_out, int out_size, void* d_ws, size_t ws_size,
                              hipStream_t stream)
{
    const float* x     = (const float*)d_in[0];
    const float* Wq    = (const float*)d_in[1];
    const float* Wk    = (const float*)d_in[2];
    const float* Wv    = (const float*)d_in[3];
    const float* Wa    = (const float*)d_in[4];
    const float* Wb    = (const float*)d_in[5];
    const float* decay = (const float*)d_in[6];
    const float* Dp    = (const float*)d_in[7];
    const float* A_log = (const float*)d_in[8];
    const float* dtb   = (const float*)d_in[9];
    const float* Wg    = (const float*)d_in[10];
    const float* Wo    = (const float*)d_in[11];
    const float* onw   = (const float*)d_in[12];
    float* out = (float*)d_out;

    float* ws   = (float*)d_ws;
    float* q    = ws;                                   // ROWS*KEY_DIM
    float* k    = q    + (size_t)ROWS * KEY_DIM;
    float* v    = k    + (size_t)ROWS * KEY_DIM;        // silu(v) GEMM out -> later o
    float* gate = v    + (size_t)ROWS * VAL_DIM;
    float* beta = gate + (size_t)ROWS * VAL_DIM;        // ROWS*NH
    float* graw = beta + (size_t)ROWS * NH;             // ROWS*NH (log decay)
    float* cinc = graw + (size_t)ROWS * NH;             // NG*TT
    float* cexc = cinc + (size_t)NG * TT;
    float* barr = cexc + (size_t)NG * TT;
    unsigned short* bf = (unsigned short*)(barr + (size_t)NG * TT);

    // phase 1 (projections)
    unsigned short* xb  = bf;                                   // ROWS*HID
    unsigned short* Wqb = xb  + (size_t)ROWS * HID;
    unsigned short* Wkb = Wqb + (size_t)KEY_DIM * HID;
    unsigned short* Wvb = Wkb + (size_t)KEY_DIM * HID;
    unsigned short* Wgb = Wvb + (size_t)VAL_DIM * HID;
    // phase R (chunked recurrence) — aliases phase 1 (dead by then)
    unsigned short* qb    = bf;                                 // NG*TT*DK
    unsigned short* kb    = qb  + (size_t)NG*TT*DK;
    unsigned short* bvb   = kb  + (size_t)NG*TT*DK;             // NG*TT*DV
    unsigned short* Ab    = bvb + (size_t)NG*TT*DV;             // NG*TT*TT
    unsigned short* Utb   = Ab  + (size_t)NG*TT*TT;             // NG*TT*TT (transposed)
    unsigned short* Minvb = Utb + (size_t)NG*TT*TT;             // NG*8*64*64
    // phase 2 (output projection) — aliases again
    unsigned short* ob  = bf;                                   // ROWS*VAL_DIM
    unsigned short* Wob = ob + (size_t)ROWS * VAL_DIM;

    dim3 blk(256);
    auto cblocks = [](size_t n) { size_t b = (n / 4 + 255) / 256; return (int)(b > 4096 ? 4096 : b); };

    cast_f32_bf16<<<cblocks((size_t)ROWS*HID),    blk, 0, stream>>>(x,  xb,  ROWS*HID/4);
    cast_f32_bf16<<<cblocks((size_t)KEY_DIM*HID), blk, 0, stream>>>(Wq, Wqb, KEY_DIM*HID/4);
    cast_f32_bf16<<<cblocks((size_t)KEY_DIM*HID), blk, 0, stream>>>(Wk, Wkb, KEY_DIM*HID/4);
    cast_f32_bf16<<<cblocks((size_t)VAL_DIM*HID), blk, 0, stream>>>(Wv, Wvb, VAL_DIM*HID/4);
    cast_f32_bf16<<<cblocks((size_t)VAL_DIM*HID), blk, 0, stream>>>(Wg, Wgb, VAL_DIM*HID/4);

    gemm_nt_bf16<<<dim3(KEY_DIM/128, ROWS/128), blk, 0, stream>>>(xb, Wqb, q,    ROWS, KEY_DIM, HID);
    gemm_nt_bf16<<<dim3(KEY_DIM/128, ROWS/128), blk, 0, stream>>>(xb, Wkb, k,    ROWS, KEY_DIM, HID);
    gemm_nt_bf16<<<dim3(VAL_DIM/128, ROWS/128), blk, 0, stream>>>(xb, Wvb, v,    ROWS, VAL_DIM, HID);
    gemm_nt_bf16<<<dim3(VAL_DIM/128, ROWS/128), blk, 0, stream>>>(xb, Wgb, gate, ROWS, VAL_DIM, HID);
    proj_ab<<<dim3(ROWS, 12), dim3(64), 0, stream>>>(x, Wa, Wb, A_log, dtb, beta, graw);

    prep_norm<<<dim3(ROWS), blk, 0, stream>>>(q, k, v, decay, Dp, beta, qb, kb, bvb);
    cumsum_pack<<<dim3(NG), dim3(64), 0, stream>>>(graw, beta, cinc, cexc, barr);
    a_mat<<<dim3(NG*36), blk, 0, stream>>>(kb, cinc, cexc, barr, Ab);
    minv_kern<<<dim3(NG*8), dim3(64), 0, stream>>>(Ab, Minvb);
    usolve<<<dim3(NG*8), blk, 0, stream>>>(Ab, Minvb, bvb, Utb);
    o_kern<<<dim3(NG*16), blk, 0, stream>>>(qb, kb, Utb, cinc, v);
    epilogue<<<dim3(ROWS), blk, 0, stream>>>(v, gate, onw);

    cast_f32_bf16<<<cblocks((size_t)ROWS*VAL_DIM), blk, 0, stream>>>(v,  ob,  ROWS*VAL_DIM/4);
    cast_f32_bf16<<<cblocks((size_t)HID*VAL_DIM),  blk, 0, stream>>>(Wo, Wob, HID*VAL_DIM/4);
    gemm_nt_bf16<<<dim3(HID/128, ROWS/128), blk, 0, stream>>>(ob, Wob, out, ROWS, HID, VAL_DIM);
}

// Round 8
// 436.964 us; speedup vs baseline: 6.1494x; 1.2120x over previous
//
#include <hip/hip_runtime.h>
#include <hip/hip_bf16.h>
#include <math.h>

#define BB 4
#define TT 512
#define HID 2048
#define NH 6
#define DK 256
#define DV 512
#define ROWS (BB*TT)          /* 2048 */
#define KEY_DIM (NH*DK)       /* 1536 */
#define VAL_DIM (NH*DV)       /* 3072 */
#define NG (BB*NH)            /* 24 groups */
#define NC 8                  /* chunks */
#define CL 64                 /* chunk length */
#define QKVG 9216             /* fused projection width: q|k|v|gate */

typedef __bf16 bf16x8 __attribute__((ext_vector_type(8)));
typedef float  f32x4  __attribute__((ext_vector_type(4)));

__device__ __forceinline__ unsigned short f2bf(float f) {
    unsigned int u = __float_as_uint(f);
    u = (u + 0x7FFFu + ((u >> 16) & 1u)) >> 16;
    return (unsigned short)u;
}
__device__ __forceinline__ float b2f(unsigned short u) {
    return __uint_as_float(((unsigned int)u) << 16);
}

// ---------------------------------------------------------------------------
// fp32 -> bf16 cast (RNE), vectorized.
// ---------------------------------------------------------------------------
__global__ __launch_bounds__(256) void cast_f32_bf16(
    const float* __restrict__ src, unsigned short* __restrict__ dst, int n4)
{
    int stride = gridDim.x * 256;
    for (int i = blockIdx.x * 256 + threadIdx.x; i < n4; i += stride) {
        float4 v = ((const float4*)src)[i];
        ushort4 o;
        o.x = f2bf(v.x); o.y = f2bf(v.y); o.z = f2bf(v.z); o.w = f2bf(v.w);
        ((ushort4*)dst)[i] = o;
    }
}

// ---------------------------------------------------------------------------
// bf16 NT GEMM: C[m,n] = sum_k A[m*K+k]*B[n*K+k], fp32 accumulate/output.
// 128x128 tile, BK=32, 256 threads = 4 waves in 2x2; 4x4 mfma 16x16x32 each.
// ---------------------------------------------------------------------------
__global__ __launch_bounds__(256) void gemm_nt_bf16(
    const unsigned short* __restrict__ A, const unsigned short* __restrict__ B,
    float* __restrict__ C, int M, int N, int K)
{
    __shared__ __align__(16) unsigned short As[128 * 32];
    __shared__ __align__(16) unsigned short Bs[128 * 32];
    const int tid  = threadIdx.x;
    const int lane = tid & 63;
    const int wave = tid >> 6;
    const int bm = blockIdx.y * 128;
    const int bn = blockIdx.x * 128;
    const int wr = (wave >> 1) * 64;
    const int wc = (wave & 1) * 64;
    const int fr = lane & 15;
    const int kg = lane >> 4;

    f32x4 acc[4][4] = {};

    for (int k0 = 0; k0 < K; k0 += 32) {
        #pragma unroll
        for (int s = 0; s < 2; ++s) {
            int e  = s * 256 + tid;
            int r  = e >> 2;
            int c8 = (e & 3) * 8;
            const unsigned short* ga = A + (size_t)(bm + r) * K + k0 + c8;
            const unsigned short* gb = B + (size_t)(bn + r) * K + k0 + c8;
            unsigned short* la = As + (size_t)(s * 256 + wave * 64) * 8;
            unsigned short* lb = Bs + (size_t)(s * 256 + wave * 64) * 8;
            __builtin_amdgcn_global_load_lds(
                (const __attribute__((address_space(1))) void*)ga,
                (__attribute__((address_space(3))) void*)la, 16, 0, 0);
            __builtin_amdgcn_global_load_lds(
                (const __attribute__((address_space(1))) void*)gb,
                (__attribute__((address_space(3))) void*)lb, 16, 0, 0);
        }
        __syncthreads();

        bf16x8 a[4], b[4];
        #pragma unroll
        for (int f = 0; f < 4; ++f) {
            a[f] = *(const bf16x8*)&As[(wr + f * 16 + fr) * 32 + kg * 8];
            b[f] = *(const bf16x8*)&Bs[(wc + f * 16 + fr) * 32 + kg * 8];
        }
        #pragma unroll
        for (int fm = 0; fm < 4; ++fm)
            #pragma unroll
            for (int fn = 0; fn < 4; ++fn)
                acc[fm][fn] = __builtin_amdgcn_mfma_f32_16x16x32_bf16(
                    a[fm], b[fn], acc[fm][fn], 0, 0, 0);
        __syncthreads();
    }

    #pragma unroll
    for (int fm = 0; fm < 4; ++fm)
        #pragma unroll
        for (int fn = 0; fn < 4; ++fn) {
            int col = bn + wc + fn * 16 + fr;
            #pragma unroll
            for (int i = 0; i < 4; ++i) {
                int row = bm + wr + fm * 16 + kg * 4 + i;
                C[(size_t)row * N + col] = acc[fm][fn][i];
            }
        }
}

// ---------------------------------------------------------------------------
// Small projections a,b -> graw (log-decay g), beta. grid (ROWS,12), 64 thr.
// ---------------------------------------------------------------------------
__global__ __launch_bounds__(64) void proj_ab(
    const float* __restrict__ x, const float* __restrict__ Wa, const float* __restrict__ Wb,
    const float* __restrict__ A_log, const float* __restrict__ dt_bias,
    float* __restrict__ beta, float* __restrict__ graw)
{
    const int row = blockIdx.x;
    const int j   = blockIdx.y;
    const bool is_a = (j < NH);
    const int h = is_a ? j : j - NH;
    const float* wrow = (is_a ? Wa : Wb) + (size_t)h * HID;
    const float4* x4 = (const float4*)(x + (size_t)row * HID);
    const float4* w4 = (const float4*)wrow;
    float s = 0.f;
    for (int i = threadIdx.x; i < HID/4; i += 64) {
        float4 a = x4[i], b = w4[i];
        s += a.x*b.x + a.y*b.y + a.z*b.z + a.w*b.w;
    }
    #pragma unroll
    for (int off = 32; off >= 1; off >>= 1) s += __shfl_xor(s, off);
    if (threadIdx.x == 0) {
        if (is_a) {
            float a  = s + dt_bias[h];
            float sp = (a > 20.f) ? a : log1pf(expf(a));
            graw[(size_t)row * NH + h] = -expf(A_log[h]) * sp;
        } else {
            beta[(size_t)row * NH + h] = 1.f / (1.f + expf(-s));
        }
    }
}

// ---------------------------------------------------------------------------
// Pointwise prep: silu(q,k), q-correction, l2norm (q scaled K^-0.5), silu(v).
// Reads the fused qkvg buffer [row][9216]: q@0, k@1536, v@3072.
// Writes bf16 per-group layouts: qb,kb [g][t][256], bvb = beta*silu(v).
// ---------------------------------------------------------------------------
__global__ __launch_bounds__(256) void prep_norm(
    const float* __restrict__ qkvg,
    const float* __restrict__ decay, const float* __restrict__ D,
    const float* __restrict__ beta,
    unsigned short* __restrict__ qb, unsigned short* __restrict__ kb,
    unsigned short* __restrict__ bvb)
{
    const int row  = blockIdx.x;
    const int b    = row >> 9, t = row & 511;
    const int tid  = threadIdx.x;
    const int lane = tid & 63, wid = tid >> 6;
    __shared__ float red[8];
    #pragma unroll 1
    for (int h = 0; h < NH; ++h) {
        size_t base = (size_t)row * QKVG + h * DK + tid;
        float qr = qkvg[base];
        float kr = qkvg[base + KEY_DIM];
        float ksil = kr / (1.f + expf(-kr));
        float qsil = qr / (1.f + expf(-qr));
        float coef = D[h] * (1.f / (1.f + expf(-decay[h])));
        float qc = qsil - coef * ksil;
        float sq = qc*qc, sk = ksil*ksil;
        #pragma unroll
        for (int off = 32; off >= 1; off >>= 1) {
            sq += __shfl_xor(sq, off);
            sk += __shfl_xor(sk, off);
        }
        if (lane == 0) { red[wid] = sq; red[4+wid] = sk; }
        __syncthreads();
        sq = red[0]+red[1]+red[2]+red[3];
        sk = red[4]+red[5]+red[6]+red[7];
        __syncthreads();
        float qinv = 0.0625f / fmaxf(sqrtf(sq), 1e-12f);
        float kinv = 1.f     / fmaxf(sqrtf(sk), 1e-12f);
        size_t gidx = (((size_t)(b*NH + h)) * TT + t) * DK + tid;
        qb[gidx] = f2bf(qc   * qinv);
        kb[gidx] = f2bf(ksil * kinv);
    }
    for (int jj = tid; jj < VAL_DIM; jj += 256) {
        int h2 = jj >> 9, dv = jj & 511;
        float xv = qkvg[(size_t)row * QKVG + 2*KEY_DIM + jj];
        float sv = xv / (1.f + expf(-xv));
        float bt = beta[(size_t)row * NH + h2];
        bvb[(((size_t)(b*NH + h2)) * TT + t) * DV + dv] = f2bf(bt * sv);
    }
}

// ---------------------------------------------------------------------------
// Per-group cumulative log-decay + beta repack. 24 blocks x 64 threads.
// ---------------------------------------------------------------------------
__global__ __launch_bounds__(64) void cumsum_pack(
    const float* __restrict__ graw, const float* __restrict__ beta,
    float* __restrict__ cinc, float* __restrict__ cexc, float* __restrict__ barr)
{
    const int g = blockIdx.x;
    const int b = g / NH, h = g % NH;
    const int lane = threadIdx.x;
    float carry = 0.f;
    for (int c0 = 0; c0 < TT; c0 += 64) {
        int t = c0 + lane;
        size_t rowi = ((size_t)(b*TT + t)) * NH + h;
        float gv = graw[rowi];
        float x = gv;
        #pragma unroll
        for (int off = 1; off < 64; off <<= 1) {
            float n = __shfl_up(x, off);
            if (lane >= off) x += n;
        }
        float inc = carry + x;
        cinc[(size_t)g*TT + t] = inc;
        cexc[(size_t)g*TT + t] = inc - gv;
        barr[(size_t)g*TT + t] = beta[rowi];
        carry = __shfl(inc, 63);
    }
}

// ---------------------------------------------------------------------------
// A-matrix tiles: A[i,j] = beta_i * exp(cexc_i - cinc_j) * (k_i . k_j), j<i.
// grid = 24 groups x 36 lower-tri chunk pairs; batched fragment loads.
// Diagonal tiles have exact 0 for j>=i (minv_kern relies on this).
// ---------------------------------------------------------------------------
__global__ __launch_bounds__(256) void a_mat(
    const unsigned short* __restrict__ kb, const float* __restrict__ cinc,
    const float* __restrict__ cexc, const float* __restrict__ barr,
    unsigned short* __restrict__ Ab)
{
    const int blk = blockIdx.x;
    const int g = blk / 36;
    int p = blk % 36, m = 0, acc0 = 0;
    while (p >= acc0 + m + 1) { acc0 += m + 1; ++m; }
    const int l = p - acc0;
    const int tid = threadIdx.x, lane = tid & 63, w = tid >> 6;
    const int fr = lane & 15, kg = lane >> 4;
    const unsigned short* Km = kb + (((size_t)g*TT) + m*CL) * DK;
    const unsigned short* Kl = kb + (((size_t)g*TT) + l*CL) * DK;
    f32x4 acc[4] = {};
    #pragma unroll
    for (int ks = 0; ks < 8; ++ks) {
        bf16x8 a = *(const bf16x8*)(Km + (size_t)(w*16 + fr)*DK + ks*32 + kg*8);
        bf16x8 bb[4];
        #pragma unroll
        for (int fn = 0; fn < 4; ++fn)
            bb[fn] = *(const bf16x8*)(Kl + (size_t)(fn*16 + fr)*DK + ks*32 + kg*8);
        #pragma unroll
        for (int fn = 0; fn < 4; ++fn)
            acc[fn] = __builtin_amdgcn_mfma_f32_16x16x32_bf16(a, bb[fn], acc[fn], 0, 0, 0);
    }
    const float* ci = cinc + (size_t)g*TT;
    const float* ce = cexc + (size_t)g*TT;
    const float* bb2 = barr + (size_t)g*TT;
    #pragma unroll
    for (int fn = 0; fn < 4; ++fn) {
        int tj = l*CL + fn*16 + fr;
        float cj = ci[tj];
        #pragma unroll
        for (int r = 0; r < 4; ++r) {
            int ti = m*CL + w*16 + kg*4 + r;
            float val = 0.f;
            if (tj < ti) val = bb2[ti] * __expf(ce[ti] - cj) * acc[fn][r];
            Ab[((size_t)g*TT + ti)*TT + tj] = f2bf(val);
        }
    }
}

// ---------------------------------------------------------------------------
// Unit-lower-triangular inverse of (I + A_mm), 64x64, forward substitution.
// Wave-synchronous, fully LDS-resident; lane col owns column col of X.
// ---------------------------------------------------------------------------
__global__ __launch_bounds__(64) void minv_kern(
    const unsigned short* __restrict__ Ab, unsigned short* __restrict__ Minvb)
{
    const int blk = blockIdx.x;
    const int g = blk >> 3, m = blk & 7;
    const int col = threadIdx.x;
    __shared__ __align__(16) unsigned short Asub[64][72];
    __shared__ __align__(16) float Xt[64][68];

    const unsigned short* Am = Ab + (((size_t)g*TT) + m*CL)*TT + m*CL;
    #pragma unroll 4
    for (int r = 0; r < 64; ++r)
        Asub[r][col] = Am[(size_t)r*TT + col];
    #pragma unroll
    for (int t4 = 0; t4 < 17; ++t4)
        *(float4*)&Xt[col][t4*4] = make_float4(0.f, 0.f, 0.f, 0.f);
    Xt[col][col] = 1.f;
    __syncthreads();

    #pragma unroll 1
    for (int i = 1; i < 64; ++i) {
        const int nch = (i + 7) >> 3;
        float s = 0.f;
        #pragma unroll 1
        for (int c8 = 0; c8 < nch; ++c8) {
            ushort4 a0 = *(const ushort4*)&Asub[i][c8*8];
            ushort4 a1 = *(const ushort4*)&Asub[i][c8*8 + 4];
            float4  x0 = *(const float4*)&Xt[col][c8*8];
            float4  x1 = *(const float4*)&Xt[col][c8*8 + 4];
            s += b2f(a0.x)*x0.x; s += b2f(a0.y)*x0.y;
            s += b2f(a0.z)*x0.z; s += b2f(a0.w)*x0.w;
            s += b2f(a1.x)*x1.x; s += b2f(a1.y)*x1.y;
            s += b2f(a1.z)*x1.z; s += b2f(a1.w)*x1.w;
        }
        if (col < i) Xt[col][i] = -s;
    }

    unsigned short* out = Minvb + (size_t)blk * 4096;
    #pragma unroll 4
    for (int r = 0; r < 64; ++r)
        out[(size_t)r*64 + col] = f2bf(Xt[col][r]);
}

// ---------------------------------------------------------------------------
// U-solve: (I+A) U = beta*V, block forward substitution over 8 chunks.
// grid = 24 groups x 8 v-slices(64). U stored transposed Utb[g][v][t] bf16.
// ---------------------------------------------------------------------------
__global__ __launch_bounds__(256) void usolve(
    const unsigned short* __restrict__ Ab, const unsigned short* __restrict__ Minvb,
    const unsigned short* __restrict__ bvb, unsigned short* __restrict__ Utb)
{
    const int blk = blockIdx.x;
    const int g = blk >> 3, vs = blk & 7;
    const int tid = threadIdx.x, lane = tid & 63, w = tid >> 6;
    const int fr = lane & 15, kg = lane >> 4;
    __shared__ __align__(16) unsigned short TACC[2][64][40];

    for (int m = 0; m < NC; ++m) {
        f32x4 acc[4] = {};
        for (int l = 0; l < m; ++l) {
            const unsigned short* Aml = Ab + (((size_t)g*TT) + m*CL)*TT + l*CL;
            const unsigned short* Ul  = Utb + (((size_t)g*TT) + vs*64)*TT + l*CL;
            #pragma unroll
            for (int ks = 0; ks < 2; ++ks) {
                bf16x8 a = *(const bf16x8*)(Aml + (size_t)(w*16 + fr)*TT + ks*32 + kg*8);
                bf16x8 bb[4];
                #pragma unroll
                for (int fn = 0; fn < 4; ++fn)
                    bb[fn] = *(const bf16x8*)(Ul + (size_t)(fn*16 + fr)*TT + ks*32 + kg*8);
                #pragma unroll
                for (int fn = 0; fn < 4; ++fn)
                    acc[fn] = __builtin_amdgcn_mfma_f32_16x16x32_bf16(a, bb[fn], acc[fn], 0, 0, 0);
            }
        }
        __syncthreads();
        const unsigned short* bvg = bvb + (((size_t)g*TT) + m*CL)*DV + vs*64;
        #pragma unroll
        for (int fn = 0; fn < 4; ++fn) {
            int v = fn*16 + fr;
            #pragma unroll
            for (int r = 0; r < 4; ++r) {
                int i = w*16 + kg*4 + r;
                float rhs = b2f(bvg[(size_t)i*DV + v]) - acc[fn][r];
                TACC[i >> 5][v][i & 31] = f2bf(rhs);
            }
        }
        __syncthreads();
        const unsigned short* Mi = Minvb + (size_t)(g*8 + m) * 4096;
        f32x4 acc2[4] = {};
        #pragma unroll
        for (int ks = 0; ks < 2; ++ks) {
            bf16x8 a = *(const bf16x8*)(Mi + (size_t)(w*16 + fr)*64 + ks*32 + kg*8);
            bf16x8 bb[4];
            #pragma unroll
            for (int fn = 0; fn < 4; ++fn)
                bb[fn] = *(const bf16x8*)&TACC[ks][fn*16 + fr][kg*8];
            #pragma unroll
            for (int fn = 0; fn < 4; ++fn)
                acc2[fn] = __builtin_amdgcn_mfma_f32_16x16x32_bf16(a, bb[fn], acc2[fn], 0, 0, 0);
        }
        unsigned short* Um = Utb + (((size_t)g*TT) + vs*64)*TT + m*CL;
        #pragma unroll
        for (int fn = 0; fn < 4; ++fn) {
            int v = fn*16 + fr;
            #pragma unroll
            for (int r = 0; r < 4; ++r) {
                int i = w*16 + kg*4 + r;
                Um[(size_t)v*TT + i] = f2bf(acc2[fn][r]);
            }
        }
        __syncthreads();
    }
}

// ---------------------------------------------------------------------------
// Output: o_i = sum_{j<=i} exp(c_i - c_j)*(q_i . k_j) * u_j.
// Block = (g, m-pair {p, 7-p}, v-quarter 128). 9 balanced l-iters per block.
// K/U tiles async-staged into double-buffered swizzled LDS; Q in registers.
// Writes o fp32 into the fused qkvg buffer's (dead) v columns @3072.
// ---------------------------------------------------------------------------
__global__ __launch_bounds__(256) void o_kern(
    const unsigned short* __restrict__ qb, const unsigned short* __restrict__ kb,
    const unsigned short* __restrict__ Utb, const float* __restrict__ cinc,
    float* __restrict__ qkvg)
{
    __shared__ __align__(16) unsigned short Kls[2][64*256];   // 64 KB
    __shared__ __align__(16) unsigned short Uls[2][128*64];   // 32 KB
    __shared__ __align__(16) unsigned short Ps[2][64][40];    // 10 KB
    __shared__ float cgl[TT];                                 // 2 KB

    const int blk = blockIdx.x;
    const int g  = blk >> 4;
    const int rm = blk & 15;
    const int pr = rm >> 2;
    const int vq = rm & 3;
    const int b = g / NH, h = g % NH;
    const int tid = threadIdx.x, lane = tid & 63, w = tid >> 6;
    const int fr = lane & 15, kg = lane >> 4;

    const unsigned short* kgrp = kb  + (size_t)g*TT*DK;
    const unsigned short* ugrp = Utb + ((size_t)g*TT + vq*128)*TT;

#define STAGE_K(buf, l) do { \
    _Pragma("unroll") \
    for (int s_ = 0; s_ < 8; ++s_) { \
        int slot_ = s_*256 + tid; \
        int gc_ = slot_ ^ ((slot_ >> 5) & 7); \
        const unsigned short* ga_ = kgrp + (size_t)(l)*CL*DK + gc_*8; \
        __builtin_amdgcn_global_load_lds( \
            (const __attribute__((address_space(1))) void*)ga_, \
            (__attribute__((address_space(3))) void*)&Kls[buf][slot_*8], 16, 0, 0); \
    } \
} while (0)

#define STAGE_U(buf, l) do { \
    _Pragma("unroll") \
    for (int s_ = 0; s_ < 4; ++s_) { \
        int slot_ = s_*256 + tid; \
        int gc_ = slot_ ^ ((slot_ >> 3) & 7); \
        const unsigned short* ga_ = ugrp + (size_t)(gc_ >> 3)*TT + (l)*CL + (gc_ & 7)*8; \
        __builtin_amdgcn_global_load_lds( \
            (const __attribute__((address_space(1))) void*)ga_, \
            (__attribute__((address_space(3))) void*)&Uls[buf][slot_*8], 16, 0, 0); \
    } \
} while (0)

    cgl[tid]       = cinc[(size_t)g*TT + tid];
    cgl[tid + 256] = cinc[(size_t)g*TT + tid + 256];
    STAGE_K(0, 0);
    STAGE_U(0, 0);
    __syncthreads();

    int cur = 0;
    #pragma unroll 1
    for (int mi_idx = 0; mi_idx < 2; ++mi_idx) {
        const int mi = mi_idx ? (7 - pr) : pr;
        const unsigned short* Qm = qb + (((size_t)g*TT) + mi*CL) * DK + (size_t)(w*16 + fr)*DK;
        bf16x8 qf[8];
        #pragma unroll
        for (int ks = 0; ks < 8; ++ks) qf[ks] = *(const bf16x8*)(Qm + ks*32 + kg*8);

        f32x4 acc[8] = {};
        #pragma unroll 1
        for (int l = 0; l <= mi; ++l) {
            if (l < mi)            { STAGE_K(cur^1, l+1); STAGE_U(cur^1, l+1); }
            else if (mi_idx == 0)  { STAGE_K(cur^1, 0);   STAGE_U(cur^1, 0);   }

            f32x4 sacc[4] = {};
            #pragma unroll
            for (int ks = 0; ks < 8; ++ks) {
                bf16x8 bbf[4];
                #pragma unroll
                for (int fn = 0; fn < 4; ++fn) {
                    int row = fn*16 + fr;
                    int slot = (row*32 + ks*4 + kg) ^ (row & 7);
                    bbf[fn] = *(const bf16x8*)&Kls[cur][slot*8];
                }
                #pragma unroll
                for (int fn = 0; fn < 4; ++fn)
                    sacc[fn] = __builtin_amdgcn_mfma_f32_16x16x32_bf16(qf[ks], bbf[fn], sacc[fn], 0, 0, 0);
            }
            __syncthreads();

            #pragma unroll
            for (int fn = 0; fn < 4; ++fn) {
                int jl = fn*16 + fr;
                float cjv = cgl[l*CL + jl];
                #pragma unroll
                for (int r = 0; r < 4; ++r) {
                    int il = w*16 + kg*4 + r;
                    float val = ((l*CL + jl) <= (mi*CL + il))
                              ? sacc[fn][r] * __expf(cgl[mi*CL + il] - cjv) : 0.f;
                    Ps[jl >> 5][il][jl & 31] = f2bf(val);
                }
            }
            __syncthreads();

            #pragma unroll
            for (int ks = 0; ks < 2; ++ks) {
                bf16x8 a = *(const bf16x8*)&Ps[ks][w*16 + fr][kg*8];
                bf16x8 bbf[8];
                #pragma unroll
                for (int fn = 0; fn < 8; ++fn) {
                    int vrow = fn*16 + fr;
                    int slot = (vrow*8 + ks*4 + kg) ^ (vrow & 7);
                    bbf[fn] = *(const bf16x8*)&Uls[cur][slot*8];
                }
                #pragma unroll
                for (int fn = 0; fn < 8; ++fn)
                    acc[fn] = __builtin_amdgcn_mfma_f32_16x16x32_bf16(a, bbf[fn], acc[fn], 0, 0, 0);
            }
            __syncthreads();
            cur ^= 1;
        }

        // store o into fused buffer (dead v columns): [row][9216] @ 3072
        float* ob = qkvg + ((size_t)(b*TT + mi*CL)) * QKVG + 2*KEY_DIM + h*DV + vq*128;
        #pragma unroll
        for (int fn = 0; fn < 8; ++fn) {
            int v = fn*16 + fr;
            #pragma unroll
            for (int r = 0; r < 4; ++r) {
                int il = w*16 + kg*4 + r;
                ob[(size_t)il*QKVG + v] = acc[fn][r];
            }
        }
    }
#undef STAGE_K
#undef STAGE_U
}

// ---------------------------------------------------------------------------
// Gated RMSNorm epilogue: reads o (fused @3072) and gate (fused @6144),
// writes gated-normed o directly as bf16 [row][VAL_DIM] for the Wo GEMM.
// ---------------------------------------------------------------------------
__global__ __launch_bounds__(256) void epilogue(
    const float* __restrict__ qkvg, const float* __restrict__ wnorm,
    unsigned short* __restrict__ ob)
{
    const int row  = blockIdx.x;
    const int tid  = threadIdx.x;
    const int lane = tid & 63, wid = tid >> 6;
    __shared__ float red[4];
    #pragma unroll 1
    for (int h = 0; h < NH; ++h) {
        size_t base = (size_t)row * QKVG + 2*KEY_DIM + h * DV;
        float o0 = qkvg[base + tid], o1 = qkvg[base + 256 + tid];
        float ss = o0*o0 + o1*o1;
        #pragma unroll
        for (int off = 32; off >= 1; off >>= 1) ss += __shfl_xor(ss, off);
        if (lane == 0) red[wid] = ss;
        __syncthreads();
        ss = red[0] + red[1] + red[2] + red[3];
        __syncthreads();
        float irms = rsqrtf(ss * (1.f / DV) + 1e-6f);
        size_t gbase = (size_t)row * QKVG + 2*KEY_DIM + VAL_DIM + h * DV;
        float g0 = qkvg[gbase + tid], g1 = qkvg[gbase + 256 + tid];
        size_t obase = (size_t)row * VAL_DIM + h * DV;
        ob[obase + tid]       = f2bf(o0 * irms * wnorm[tid]       * (1.f / (1.f + expf(-g0))));
        ob[obase + 256 + tid] = f2bf(o1 * irms * wnorm[256 + tid] * (1.f / (1.f + expf(-g1))));
    }
}

// ---------------------------------------------------------------------------
extern "C" void kernel_launch(void* const* d_in, const int* in_sizes, int n_in,
                              void* d_out, int out_size, void* d_ws, size_t ws_size,
                              hipStream_t stream)
{
    const float* x     = (const float*)d_in[0];
    const float* Wq    = (const float*)d_in[1];
    const float* Wk    = (const float*)d_in[2];
    const float* Wv    = (const float*)d_in[3];
    const float* Wa    = (const float*)d_in[4];
    const float* Wb    = (const float*)d_in[5];
    const float* decay = (const float*)d_in[6];
    const float* Dp    = (const float*)d_in[7];
    const float* A_log = (const float*)d_in[8];
    const float* dtb   = (const float*)d_in[9];
    const float* Wg    = (const float*)d_in[10];
    const float* Wo    = (const float*)d_in[11];
    const float* onw   = (const float*)d_in[12];
    float* out = (float*)d_out;

    float* ws   = (float*)d_ws;
    float* qkvg = ws;                                   // ROWS*9216 fp32 (q|k|v->o|gate)
    float* beta = qkvg + (size_t)ROWS * QKVG;           // ROWS*NH
    float* graw = beta + (size_t)ROWS * NH;             // ROWS*NH
    float* cinc = graw + (size_t)ROWS * NH;             // NG*TT
    float* cexc = cinc + (size_t)NG * TT;
    float* barr = cexc + (size_t)NG * TT;
    unsigned short* bf = (unsigned short*)(barr + (size_t)NG * TT);

    // phase 1 (projections): weight block Wqb..Wgb is one contiguous
    // [9216][2048] bf16 matrix (order q,k,v,g).
    unsigned short* xb  = bf;                                   // ROWS*HID
    unsigned short* Wqb = xb  + (size_t)ROWS * HID;
    unsigned short* Wkb = Wqb + (size_t)KEY_DIM * HID;
    unsigned short* Wvb = Wkb + (size_t)KEY_DIM * HID;
    unsigned short* Wgb = Wvb + (size_t)VAL_DIM * HID;
    // phase R (chunked recurrence) — aliases phase 1 (dead by then)
    unsigned short* qb    = bf;                                 // NG*TT*DK
    unsigned short* kb    = qb  + (size_t)NG*TT*DK;
    unsigned short* bvb   = kb  + (size_t)NG*TT*DK;             // NG*TT*DV
    unsigned short* Ab    = bvb + (size_t)NG*TT*DV;             // NG*TT*TT
    unsigned short* Utb   = Ab  + (size_t)NG*TT*TT;             // NG*TT*TT (transposed)
    unsigned short* Minvb = Utb + (size_t)NG*TT*TT;             // NG*8*64*64
    // phase 2 (output projection): ob aliases qb+kb (dead after o_kern);
    // Wob aliases bvb (dead after usolve).
    unsigned short* ob  = bf;                                   // ROWS*VAL_DIM
    unsigned short* Wob = bvb;                                  // HID*VAL_DIM

    dim3 blk(256);
    auto cblocks = [](size_t n) { size_t b = (n / 4 + 255) / 256; return (int)(b > 4096 ? 4096 : b); };

    cast_f32_bf16<<<cblocks((size_t)ROWS*HID),    blk, 0, stream>>>(x,  xb,  ROWS*HID/4);
    cast_f32_bf16<<<cblocks((size_t)KEY_DIM*HID), blk, 0, stream>>>(Wq, Wqb, KEY_DIM*HID/4);
    cast_f32_bf16<<<cblocks((size_t)KEY_DIM*HID), blk, 0, stream>>>(Wk, Wkb, KEY_DIM*HID/4);
    cast_f32_bf16<<<cblocks((size_t)VAL_DIM*HID), blk, 0, stream>>>(Wv, Wvb, VAL_DIM*HID/4);
    cast_f32_bf16<<<cblocks((size_t)VAL_DIM*HID), blk, 0, stream>>>(Wg, Wgb, VAL_DIM*HID/4);

    // fused q|k|v|gate projection: N=9216 -> 72x16 = 1152 blocks
    gemm_nt_bf16<<<dim3(QKVG/128, ROWS/128), blk, 0, stream>>>(xb, Wqb, qkvg, ROWS, QKVG, HID);
    proj_ab<<<dim3(ROWS, 12), dim3(64), 0, stream>>>(x, Wa, Wb, A_log, dtb, beta, graw);

    prep_norm<<<dim3(ROWS), blk, 0, stream>>>(qkvg, decay, Dp, beta, qb, kb, bvb);
    cumsum_pack<<<dim3(NG), dim3(64), 0, stream>>>(graw, beta, cinc, cexc, barr);
    a_mat<<<dim3(NG*36), blk, 0, stream>>>(kb, cinc, cexc, barr, Ab);
    minv_kern<<<dim3(NG*8), dim3(64), 0, stream>>>(Ab, Minvb);
    usolve<<<dim3(NG*8), blk, 0, stream>>>(Ab, Minvb, bvb, Utb);
    o_kern<<<dim3(NG*16), blk, 0, stream>>>(qb, kb, Utb, cinc, qkvg);
    epilogue<<<dim3(ROWS), blk, 0, stream>>>(qkvg, onw, ob);

    cast_f32_bf16<<<cblocks((size_t)HID*VAL_DIM), blk, 0, stream>>>(Wo, Wob, HID*VAL_DIM/4);
    gemm_nt_bf16<<<dim3(HID/128, ROWS/128), blk, 0, stream>>>(ob, Wob, out, ROWS, HID, VAL_DIM);
}

// Round 9
// 430.468 us; speedup vs baseline: 6.2422x; 1.0151x over previous
//
#include <hip/hip_runtime.h>
#include <hip/hip_bf16.h>
#include <math.h>

#define BB 4
#define TT 512
#define HID 2048
#define NH 6
#define DK 256
#define DV 512
#define ROWS (BB*TT)          /* 2048 */
#define KEY_DIM (NH*DK)       /* 1536 */
#define VAL_DIM (NH*DV)       /* 3072 */
#define NG (BB*NH)            /* 24 groups */
#define NC 8                  /* chunks */
#define CL 64                 /* chunk length */
#define QKVG 9216             /* fused projection width: q|k|v|gate */

typedef __bf16 bf16x8 __attribute__((ext_vector_type(8)));
typedef float  f32x4  __attribute__((ext_vector_type(4)));

__device__ __forceinline__ unsigned short f2bf(float f) {
    unsigned int u = __float_as_uint(f);
    u = (u + 0x7FFFu + ((u >> 16) & 1u)) >> 16;
    return (unsigned short)u;
}
__device__ __forceinline__ float b2f(unsigned short u) {
    return __uint_as_float(((unsigned int)u) << 16);
}

// ---------------------------------------------------------------------------
// fp32 -> bf16 cast (RNE), vectorized. Single-source variant (Wo).
// ---------------------------------------------------------------------------
__global__ __launch_bounds__(256) void cast_f32_bf16(
    const float* __restrict__ src, unsigned short* __restrict__ dst, int n4)
{
    int stride = gridDim.x * 256;
    for (int i = blockIdx.x * 256 + threadIdx.x; i < n4; i += stride) {
        float4 v = ((const float4*)src)[i];
        ushort4 o;
        o.x = f2bf(v.x); o.y = f2bf(v.y); o.z = f2bf(v.z); o.w = f2bf(v.w);
        ((ushort4*)dst)[i] = o;
    }
}

// ---------------------------------------------------------------------------
// Multi-source fp32 -> bf16 cast: 5 sources, one contiguous destination.
// ---------------------------------------------------------------------------
struct Cast5 {
    const float* src[5];
    int start4[6];           // cumulative float4 offsets into dst
};
__global__ __launch_bounds__(256) void cast_multi(Cast5 c, unsigned short* __restrict__ dst)
{
    const int total = c.start4[5];
    int stride = gridDim.x * 256;
    for (int i = blockIdx.x * 256 + threadIdx.x; i < total; i += stride) {
        int s = 0;
        while (i >= c.start4[s + 1]) ++s;
        float4 v = ((const float4*)c.src[s])[i - c.start4[s]];
        ushort4 o;
        o.x = f2bf(v.x); o.y = f2bf(v.y); o.z = f2bf(v.z); o.w = f2bf(v.w);
        ((ushort4*)dst)[i] = o;
    }
}

// ---------------------------------------------------------------------------
// bf16 NT GEMM: C[m,n] = sum_k A[m*K+k]*B[n*K+k], fp32 accumulate/output.
// 128x128 tile, BK=32, 256 threads = 4 waves in 2x2; 4x4 mfma 16x16x32 each.
// v2: double-buffered LDS (2-phase): next tile's global_load_lds issued
// BEFORE current tile's MFMA; one __syncthreads per K-step drains vmcnt
// (exactly the one in-flight buffer) + guards buffer swap.
// ---------------------------------------------------------------------------
__global__ __launch_bounds__(256) void gemm_nt_bf16(
    const unsigned short* __restrict__ A, const unsigned short* __restrict__ B,
    float* __restrict__ C, int M, int N, int K)
{
    __shared__ __align__(16) unsigned short As[2][128 * 32];
    __shared__ __align__(16) unsigned short Bs[2][128 * 32];
    const int tid  = threadIdx.x;
    const int lane = tid & 63;
    const int wave = tid >> 6;
    const int bm = blockIdx.y * 128;
    const int bn = blockIdx.x * 128;
    const int wr = (wave >> 1) * 64;
    const int wc = (wave & 1) * 64;
    const int fr = lane & 15;
    const int kg = lane >> 4;

    f32x4 acc[4][4] = {};

#define GSTAGE(buf, k0) do { \
    _Pragma("unroll") \
    for (int s_ = 0; s_ < 2; ++s_) { \
        int e_  = s_ * 256 + tid; \
        int r_  = e_ >> 2; \
        int c8_ = (e_ & 3) * 8; \
        const unsigned short* ga_ = A + (size_t)(bm + r_) * K + (k0) + c8_; \
        const unsigned short* gb_ = B + (size_t)(bn + r_) * K + (k0) + c8_; \
        unsigned short* la_ = As[buf] + (size_t)(s_ * 256 + wave * 64) * 8; \
        unsigned short* lb_ = Bs[buf] + (size_t)(s_ * 256 + wave * 64) * 8; \
        __builtin_amdgcn_global_load_lds( \
            (const __attribute__((address_space(1))) void*)ga_, \
            (__attribute__((address_space(3))) void*)la_, 16, 0, 0); \
        __builtin_amdgcn_global_load_lds( \
            (const __attribute__((address_space(1))) void*)gb_, \
            (__attribute__((address_space(3))) void*)lb_, 16, 0, 0); \
    } \
} while (0)

    GSTAGE(0, 0);
    __syncthreads();

    int cur = 0;
    for (int k0 = 0; k0 < K; k0 += 32) {
        if (k0 + 32 < K) GSTAGE(cur ^ 1, k0 + 32);   // in flight during MFMA

        bf16x8 a[4], b[4];
        #pragma unroll
        for (int f = 0; f < 4; ++f) {
            a[f] = *(const bf16x8*)&As[cur][(wr + f * 16 + fr) * 32 + kg * 8];
            b[f] = *(const bf16x8*)&Bs[cur][(wc + f * 16 + fr) * 32 + kg * 8];
        }
        #pragma unroll
        for (int fm = 0; fm < 4; ++fm)
            #pragma unroll
            for (int fn = 0; fn < 4; ++fn)
                acc[fm][fn] = __builtin_amdgcn_mfma_f32_16x16x32_bf16(
                    a[fm], b[fn], acc[fm][fn], 0, 0, 0);

        __syncthreads();   // drains next-tile loads + guards swap
        cur ^= 1;
    }
#undef GSTAGE

    #pragma unroll
    for (int fm = 0; fm < 4; ++fm)
        #pragma unroll
        for (int fn = 0; fn < 4; ++fn) {
            int col = bn + wc + fn * 16 + fr;
            #pragma unroll
            for (int i = 0; i < 4; ++i) {
                int row = bm + wr + fm * 16 + kg * 4 + i;
                C[(size_t)row * N + col] = acc[fm][fn][i];
            }
        }
}

// ---------------------------------------------------------------------------
// Small projections a,b -> graw (log-decay g), beta. grid (ROWS,12), 64 thr.
// ---------------------------------------------------------------------------
__global__ __launch_bounds__(64) void proj_ab(
    const float* __restrict__ x, const float* __restrict__ Wa, const float* __restrict__ Wb,
    const float* __restrict__ A_log, const float* __restrict__ dt_bias,
    float* __restrict__ beta, float* __restrict__ graw)
{
    const int row = blockIdx.x;
    const int j   = blockIdx.y;
    const bool is_a = (j < NH);
    const int h = is_a ? j : j - NH;
    const float* wrow = (is_a ? Wa : Wb) + (size_t)h * HID;
    const float4* x4 = (const float4*)(x + (size_t)row * HID);
    const float4* w4 = (const float4*)wrow;
    float s = 0.f;
    for (int i = threadIdx.x; i < HID/4; i += 64) {
        float4 a = x4[i], b = w4[i];
        s += a.x*b.x + a.y*b.y + a.z*b.z + a.w*b.w;
    }
    #pragma unroll
    for (int off = 32; off >= 1; off >>= 1) s += __shfl_xor(s, off);
    if (threadIdx.x == 0) {
        if (is_a) {
            float a  = s + dt_bias[h];
            float sp = (a > 20.f) ? a : log1pf(expf(a));
            graw[(size_t)row * NH + h] = -expf(A_log[h]) * sp;
        } else {
            beta[(size_t)row * NH + h] = 1.f / (1.f + expf(-s));
        }
    }
}

// ---------------------------------------------------------------------------
// Pointwise prep: silu(q,k), q-correction, l2norm (q scaled K^-0.5), silu(v).
// Reads the fused qkvg buffer [row][9216]: q@0, k@1536, v@3072.
// Writes bf16 per-group layouts: qb,kb [g][t][256], bvb = beta*silu(v).
// ---------------------------------------------------------------------------
__global__ __launch_bounds__(256) void prep_norm(
    const float* __restrict__ qkvg,
    const float* __restrict__ decay, const float* __restrict__ D,
    const float* __restrict__ beta,
    unsigned short* __restrict__ qb, unsigned short* __restrict__ kb,
    unsigned short* __restrict__ bvb)
{
    const int row  = blockIdx.x;
    const int b    = row >> 9, t = row & 511;
    const int tid  = threadIdx.x;
    const int lane = tid & 63, wid = tid >> 6;
    __shared__ float red[8];
    #pragma unroll 1
    for (int h = 0; h < NH; ++h) {
        size_t base = (size_t)row * QKVG + h * DK + tid;
        float qr = qkvg[base];
        float kr = qkvg[base + KEY_DIM];
        float ksil = kr / (1.f + expf(-kr));
        float qsil = qr / (1.f + expf(-qr));
        float coef = D[h] * (1.f / (1.f + expf(-decay[h])));
        float qc = qsil - coef * ksil;
        float sq = qc*qc, sk = ksil*ksil;
        #pragma unroll
        for (int off = 32; off >= 1; off >>= 1) {
            sq += __shfl_xor(sq, off);
            sk += __shfl_xor(sk, off);
        }
        if (lane == 0) { red[wid] = sq; red[4+wid] = sk; }
        __syncthreads();
        sq = red[0]+red[1]+red[2]+red[3];
        sk = red[4]+red[5]+red[6]+red[7];
        __syncthreads();
        float qinv = 0.0625f / fmaxf(sqrtf(sq), 1e-12f);
        float kinv = 1.f     / fmaxf(sqrtf(sk), 1e-12f);
        size_t gidx = (((size_t)(b*NH + h)) * TT + t) * DK + tid;
        qb[gidx] = f2bf(qc   * qinv);
        kb[gidx] = f2bf(ksil * kinv);
    }
    for (int jj = tid; jj < VAL_DIM; jj += 256) {
        int h2 = jj >> 9, dv = jj & 511;
        float xv = qkvg[(size_t)row * QKVG + 2*KEY_DIM + jj];
        float sv = xv / (1.f + expf(-xv));
        float bt = beta[(size_t)row * NH + h2];
        bvb[(((size_t)(b*NH + h2)) * TT + t) * DV + dv] = f2bf(bt * sv);
    }
}

// ---------------------------------------------------------------------------
// Per-group cumulative log-decay + beta repack. 24 blocks x 64 threads.
// ---------------------------------------------------------------------------
__global__ __launch_bounds__(64) void cumsum_pack(
    const float* __restrict__ graw, const float* __restrict__ beta,
    float* __restrict__ cinc, float* __restrict__ cexc, float* __restrict__ barr)
{
    const int g = blockIdx.x;
    const int b = g / NH, h = g % NH;
    const int lane = threadIdx.x;
    float carry = 0.f;
    for (int c0 = 0; c0 < TT; c0 += 64) {
        int t = c0 + lane;
        size_t rowi = ((size_t)(b*TT + t)) * NH + h;
        float gv = graw[rowi];
        float x = gv;
        #pragma unroll
        for (int off = 1; off < 64; off <<= 1) {
            float n = __shfl_up(x, off);
            if (lane >= off) x += n;
        }
        float inc = carry + x;
        cinc[(size_t)g*TT + t] = inc;
        cexc[(size_t)g*TT + t] = inc - gv;
        barr[(size_t)g*TT + t] = beta[rowi];
        carry = __shfl(inc, 63);
    }
}

// ---------------------------------------------------------------------------
// A-matrix tiles: A[i,j] = beta_i * exp(cexc_i - cinc_j) * (k_i . k_j), j<i.
// grid = 24 groups x 36 lower-tri chunk pairs; batched fragment loads.
// Diagonal tiles have exact 0 for j>=i (minv_kern relies on this).
// ---------------------------------------------------------------------------
__global__ __launch_bounds__(256) void a_mat(
    const unsigned short* __restrict__ kb, const float* __restrict__ cinc,
    const float* __restrict__ cexc, const float* __restrict__ barr,
    unsigned short* __restrict__ Ab)
{
    const int blk = blockIdx.x;
    const int g = blk / 36;
    int p = blk % 36, m = 0, acc0 = 0;
    while (p >= acc0 + m + 1) { acc0 += m + 1; ++m; }
    const int l = p - acc0;
    const int tid = threadIdx.x, lane = tid & 63, w = tid >> 6;
    const int fr = lane & 15, kg = lane >> 4;
    const unsigned short* Km = kb + (((size_t)g*TT) + m*CL) * DK;
    const unsigned short* Kl = kb + (((size_t)g*TT) + l*CL) * DK;
    f32x4 acc[4] = {};
    #pragma unroll
    for (int ks = 0; ks < 8; ++ks) {
        bf16x8 a = *(const bf16x8*)(Km + (size_t)(w*16 + fr)*DK + ks*32 + kg*8);
        bf16x8 bb[4];
        #pragma unroll
        for (int fn = 0; fn < 4; ++fn)
            bb[fn] = *(const bf16x8*)(Kl + (size_t)(fn*16 + fr)*DK + ks*32 + kg*8);
        #pragma unroll
        for (int fn = 0; fn < 4; ++fn)
            acc[fn] = __builtin_amdgcn_mfma_f32_16x16x32_bf16(a, bb[fn], acc[fn], 0, 0, 0);
    }
    const float* ci = cinc + (size_t)g*TT;
    const float* ce = cexc + (size_t)g*TT;
    const float* bb2 = barr + (size_t)g*TT;
    #pragma unroll
    for (int fn = 0; fn < 4; ++fn) {
        int tj = l*CL + fn*16 + fr;
        float cj = ci[tj];
        #pragma unroll
        for (int r = 0; r < 4; ++r) {
            int ti = m*CL + w*16 + kg*4 + r;
            float val = 0.f;
            if (tj < ti) val = bb2[ti] * __expf(ce[ti] - cj) * acc[fn][r];
            Ab[((size_t)g*TT + ti)*TT + tj] = f2bf(val);
        }
    }
}

// ---------------------------------------------------------------------------
// Unit-lower-triangular inverse of (I + A_mm), 64x64, forward substitution.
// Wave-synchronous, fully LDS-resident; lane col owns column col of X.
// ---------------------------------------------------------------------------
__global__ __launch_bounds__(64) void minv_kern(
    const unsigned short* __restrict__ Ab, unsigned short* __restrict__ Minvb)
{
    const int blk = blockIdx.x;
    const int g = blk >> 3, m = blk & 7;
    const int col = threadIdx.x;
    __shared__ __align__(16) unsigned short Asub[64][72];
    __shared__ __align__(16) float Xt[64][68];

    const unsigned short* Am = Ab + (((size_t)g*TT) + m*CL)*TT + m*CL;
    #pragma unroll 4
    for (int r = 0; r < 64; ++r)
        Asub[r][col] = Am[(size_t)r*TT + col];
    #pragma unroll
    for (int t4 = 0; t4 < 17; ++t4)
        *(float4*)&Xt[col][t4*4] = make_float4(0.f, 0.f, 0.f, 0.f);
    Xt[col][col] = 1.f;
    __syncthreads();

    #pragma unroll 1
    for (int i = 1; i < 64; ++i) {
        const int nch = (i + 7) >> 3;
        float s = 0.f;
        #pragma unroll 1
        for (int c8 = 0; c8 < nch; ++c8) {
            ushort4 a0 = *(const ushort4*)&Asub[i][c8*8];
            ushort4 a1 = *(const ushort4*)&Asub[i][c8*8 + 4];
            float4  x0 = *(const float4*)&Xt[col][c8*8];
            float4  x1 = *(const float4*)&Xt[col][c8*8 + 4];
            s += b2f(a0.x)*x0.x; s += b2f(a0.y)*x0.y;
            s += b2f(a0.z)*x0.z; s += b2f(a0.w)*x0.w;
            s += b2f(a1.x)*x1.x; s += b2f(a1.y)*x1.y;
            s += b2f(a1.z)*x1.z; s += b2f(a1.w)*x1.w;
        }
        if (col < i) Xt[col][i] = -s;
    }

    unsigned short* out = Minvb + (size_t)blk * 4096;
    #pragma unroll 4
    for (int r = 0; r < 64; ++r)
        out[(size_t)r*64 + col] = f2bf(Xt[col][r]);
}

// ---------------------------------------------------------------------------
// U-solve: (I+A) U = beta*V, block forward substitution over 8 chunks.
// grid = 24 groups x 8 v-slices(64). U stored transposed Utb[g][v][t] bf16.
// ---------------------------------------------------------------------------
__global__ __launch_bounds__(256) void usolve(
    const unsigned short* __restrict__ Ab, const unsigned short* __restrict__ Minvb,
    const unsigned short* __restrict__ bvb, unsigned short* __restrict__ Utb)
{
    const int blk = blockIdx.x;
    const int g = blk >> 3, vs = blk & 7;
    const int tid = threadIdx.x, lane = tid & 63, w = tid >> 6;
    const int fr = lane & 15, kg = lane >> 4;
    __shared__ __align__(16) unsigned short TACC[2][64][40];

    for (int m = 0; m < NC; ++m) {
        f32x4 acc[4] = {};
        for (int l = 0; l < m; ++l) {
            const unsigned short* Aml = Ab + (((size_t)g*TT) + m*CL)*TT + l*CL;
            const unsigned short* Ul  = Utb + (((size_t)g*TT) + vs*64)*TT + l*CL;
            #pragma unroll
            for (int ks = 0; ks < 2; ++ks) {
                bf16x8 a = *(const bf16x8*)(Aml + (size_t)(w*16 + fr)*TT + ks*32 + kg*8);
                bf16x8 bb[4];
                #pragma unroll
                for (int fn = 0; fn < 4; ++fn)
                    bb[fn] = *(const bf16x8*)(Ul + (size_t)(fn*16 + fr)*TT + ks*32 + kg*8);
                #pragma unroll
                for (int fn = 0; fn < 4; ++fn)
                    acc[fn] = __builtin_amdgcn_mfma_f32_16x16x32_bf16(a, bb[fn], acc[fn], 0, 0, 0);
            }
        }
        __syncthreads();
        const unsigned short* bvg = bvb + (((size_t)g*TT) + m*CL)*DV + vs*64;
        #pragma unroll
        for (int fn = 0; fn < 4; ++fn) {
            int v = fn*16 + fr;
            #pragma unroll
            for (int r = 0; r < 4; ++r) {
                int i = w*16 + kg*4 + r;
                float rhs = b2f(bvg[(size_t)i*DV + v]) - acc[fn][r];
                TACC[i >> 5][v][i & 31] = f2bf(rhs);
            }
        }
        __syncthreads();
        const unsigned short* Mi = Minvb + (size_t)(g*8 + m) * 4096;
        f32x4 acc2[4] = {};
        #pragma unroll
        for (int ks = 0; ks < 2; ++ks) {
            bf16x8 a = *(const bf16x8*)(Mi + (size_t)(w*16 + fr)*64 + ks*32 + kg*8);
            bf16x8 bb[4];
            #pragma unroll
            for (int fn = 0; fn < 4; ++fn)
                bb[fn] = *(const bf16x8*)&TACC[ks][fn*16 + fr][kg*8];
            #pragma unroll
            for (int fn = 0; fn < 4; ++fn)
                acc2[fn] = __builtin_amdgcn_mfma_f32_16x16x32_bf16(a, bb[fn], acc2[fn], 0, 0, 0);
        }
        unsigned short* Um = Utb + (((size_t)g*TT) + vs*64)*TT + m*CL;
        #pragma unroll
        for (int fn = 0; fn < 4; ++fn) {
            int v = fn*16 + fr;
            #pragma unroll
            for (int r = 0; r < 4; ++r) {
                int i = w*16 + kg*4 + r;
                Um[(size_t)v*TT + i] = f2bf(acc2[fn][r]);
            }
        }
        __syncthreads();
    }
}

// ---------------------------------------------------------------------------
// Output: o_i = sum_{j<=i} exp(c_i - c_j)*(q_i . k_j) * u_j.
// Block = (g, m-pair {p, 7-p}, v-quarter 128). 9 balanced l-iters per block.
// K/U tiles async-staged into double-buffered swizzled LDS; Q in registers.
// Writes o fp32 into the fused qkvg buffer's (dead) v columns @3072.
// ---------------------------------------------------------------------------
__global__ __launch_bounds__(256) void o_kern(
    const unsigned short* __restrict__ qb, const unsigned short* __restrict__ kb,
    const unsigned short* __restrict__ Utb, const float* __restrict__ cinc,
    float* __restrict__ qkvg)
{
    __shared__ __align__(16) unsigned short Kls[2][64*256];   // 64 KB
    __shared__ __align__(16) unsigned short Uls[2][128*64];   // 32 KB
    __shared__ __align__(16) unsigned short Ps[2][64][40];    // 10 KB
    __shared__ float cgl[TT];                                 // 2 KB

    const int blk = blockIdx.x;
    const int g  = blk >> 4;
    const int rm = blk & 15;
    const int pr = rm >> 2;
    const int vq = rm & 3;
    const int b = g / NH, h = g % NH;
    const int tid = threadIdx.x, lane = tid & 63, w = tid >> 6;
    const int fr = lane & 15, kg = lane >> 4;

    const unsigned short* kgrp = kb  + (size_t)g*TT*DK;
    const unsigned short* ugrp = Utb + ((size_t)g*TT + vq*128)*TT;

#define STAGE_K(buf, l) do { \
    _Pragma("unroll") \
    for (int s_ = 0; s_ < 8; ++s_) { \
        int slot_ = s_*256 + tid; \
        int gc_ = slot_ ^ ((slot_ >> 5) & 7); \
        const unsigned short* ga_ = kgrp + (size_t)(l)*CL*DK + gc_*8; \
        __builtin_amdgcn_global_load_lds( \
            (const __attribute__((address_space(1))) void*)ga_, \
            (__attribute__((address_space(3))) void*)&Kls[buf][slot_*8], 16, 0, 0); \
    } \
} while (0)

#define STAGE_U(buf, l) do { \
    _Pragma("unroll") \
    for (int s_ = 0; s_ < 4; ++s_) { \
        int slot_ = s_*256 + tid; \
        int gc_ = slot_ ^ ((slot_ >> 3) & 7); \
        const unsigned short* ga_ = ugrp + (size_t)(gc_ >> 3)*TT + (l)*CL + (gc_ & 7)*8; \
        __builtin_amdgcn_global_load_lds( \
            (const __attribute__((address_space(1))) void*)ga_, \
            (__attribute__((address_space(3))) void*)&Uls[buf][slot_*8], 16, 0, 0); \
    } \
} while (0)

    cgl[tid]       = cinc[(size_t)g*TT + tid];
    cgl[tid + 256] = cinc[(size_t)g*TT + tid + 256];
    STAGE_K(0, 0);
    STAGE_U(0, 0);
    __syncthreads();

    int cur = 0;
    #pragma unroll 1
    for (int mi_idx = 0; mi_idx < 2; ++mi_idx) {
        const int mi = mi_idx ? (7 - pr) : pr;
        const unsigned short* Qm = qb + (((size_t)g*TT) + mi*CL) * DK + (size_t)(w*16 + fr)*DK;
        bf16x8 qf[8];
        #pragma unroll
        for (int ks = 0; ks < 8; ++ks) qf[ks] = *(const bf16x8*)(Qm + ks*32 + kg*8);

        f32x4 acc[8] = {};
        #pragma unroll 1
        for (int l = 0; l <= mi; ++l) {
            if (l < mi)            { STAGE_K(cur^1, l+1); STAGE_U(cur^1, l+1); }
            else if (mi_idx == 0)  { STAGE_K(cur^1, 0);   STAGE_U(cur^1, 0);   }

            f32x4 sacc[4] = {};
            #pragma unroll
            for (int ks = 0; ks < 8; ++ks) {
                bf16x8 bbf[4];
                #pragma unroll
                for (int fn = 0; fn < 4; ++fn) {
                    int row = fn*16 + fr;
                    int slot = (row*32 + ks*4 + kg) ^ (row & 7);
                    bbf[fn] = *(const bf16x8*)&Kls[cur][slot*8];
                }
                #pragma unroll
                for (int fn = 0; fn < 4; ++fn)
                    sacc[fn] = __builtin_amdgcn_mfma_f32_16x16x32_bf16(qf[ks], bbf[fn], sacc[fn], 0, 0, 0);
            }
            __syncthreads();

            #pragma unroll
            for (int fn = 0; fn < 4; ++fn) {
                int jl = fn*16 + fr;
                float cjv = cgl[l*CL + jl];
                #pragma unroll
                for (int r = 0; r < 4; ++r) {
                    int il = w*16 + kg*4 + r;
                    float val = ((l*CL + jl) <= (mi*CL + il))
                              ? sacc[fn][r] * __expf(cgl[mi*CL + il] - cjv) : 0.f;
                    Ps[jl >> 5][il][jl & 31] = f2bf(val);
                }
            }
            __syncthreads();

            #pragma unroll
            for (int ks = 0; ks < 2; ++ks) {
                bf16x8 a = *(const bf16x8*)&Ps[ks][w*16 + fr][kg*8];
                bf16x8 bbf[8];
                #pragma unroll
                for (int fn = 0; fn < 8; ++fn) {
                    int vrow = fn*16 + fr;
                    int slot = (vrow*8 + ks*4 + kg) ^ (vrow & 7);
                    bbf[fn] = *(const bf16x8*)&Uls[cur][slot*8];
                }
                #pragma unroll
                for (int fn = 0; fn < 8; ++fn)
                    acc[fn] = __builtin_amdgcn_mfma_f32_16x16x32_bf16(a, bbf[fn], acc[fn], 0, 0, 0);
            }
            __syncthreads();
            cur ^= 1;
        }

        // store o into fused buffer (dead v columns): [row][9216] @ 3072
        float* ob = qkvg + ((size_t)(b*TT + mi*CL)) * QKVG + 2*KEY_DIM + h*DV + vq*128;
        #pragma unroll
        for (int fn = 0; fn < 8; ++fn) {
            int v = fn*16 + fr;
            #pragma unroll
            for (int r = 0; r < 4; ++r) {
                int il = w*16 + kg*4 + r;
                ob[(size_t)il*QKVG + v] = acc[fn][r];
            }
        }
    }
#undef STAGE_K
#undef STAGE_U
}

// ---------------------------------------------------------------------------
// Gated RMSNorm epilogue: reads o (fused @3072) and gate (fused @6144),
// writes gated-normed o directly as bf16 [row][VAL_DIM] for the Wo GEMM.
// ---------------------------------------------------------------------------
__global__ __launch_bounds__(256) void epilogue(
    const float* __restrict__ qkvg, const float* __restrict__ wnorm,
    unsigned short* __restrict__ ob)
{
    const int row  = blockIdx.x;
    const int tid  = threadIdx.x;
    const int lane = tid & 63, wid = tid >> 6;
    __shared__ float red[4];
    #pragma unroll 1
    for (int h = 0; h < NH; ++h) {
        size_t base = (size_t)row * QKVG + 2*KEY_DIM + h * DV;
        float o0 = qkvg[base + tid], o1 = qkvg[base + 256 + tid];
        float ss = o0*o0 + o1*o1;
        #pragma unroll
        for (int off = 32; off >= 1; off >>= 1) ss += __shfl_xor(ss, off);
        if (lane == 0) red[wid] = ss;
        __syncthreads();
        ss = red[0] + red[1] + red[2] + red[3];
        __syncthreads();
        float irms = rsqrtf(ss * (1.f / DV) + 1e-6f);
        size_t gbase = (size_t)row * QKVG + 2*KEY_DIM + VAL_DIM + h * DV;
        float g0 = qkvg[gbase + tid], g1 = qkvg[gbase + 256 + tid];
        size_t obase = (size_t)row * VAL_DIM + h * DV;
        ob[obase + tid]       = f2bf(o0 * irms * wnorm[tid]       * (1.f / (1.f + expf(-g0))));
        ob[obase + 256 + tid] = f2bf(o1 * irms * wnorm[256 + tid] * (1.f / (1.f + expf(-g1))));
    }
}

// ---------------------------------------------------------------------------
extern "C" void kernel_launch(void* const* d_in, const int* in_sizes, int n_in,
                              void* d_out, int out_size, void* d_ws, size_t ws_size,
                              hipStream_t stream)
{
    const float* x     = (const float*)d_in[0];
    const float* Wq    = (const float*)d_in[1];
    const float* Wk    = (const float*)d_in[2];
    const float* Wv    = (const float*)d_in[3];
    const float* Wa    = (const float*)d_in[4];
    const float* Wb    = (const float*)d_in[5];
    const float* decay = (const float*)d_in[6];
    const float* Dp    = (const float*)d_in[7];
    const float* A_log = (const float*)d_in[8];
    const float* dtb   = (const float*)d_in[9];
    const float* Wg    = (const float*)d_in[10];
    const float* Wo    = (const float*)d_in[11];
    const float* onw   = (const float*)d_in[12];
    float* out = (float*)d_out;

    float* ws   = (float*)d_ws;
    float* qkvg = ws;                                   // ROWS*9216 fp32 (q|k|v->o|gate)
    float* beta = qkvg + (size_t)ROWS * QKVG;           // ROWS*NH
    float* graw = beta + (size_t)ROWS * NH;             // ROWS*NH
    float* cinc = graw + (size_t)ROWS * NH;             // NG*TT
    float* cexc = cinc + (size_t)NG * TT;
    float* barr = cexc + (size_t)NG * TT;
    unsigned short* bf = (unsigned short*)(barr + (size_t)NG * TT);

    // phase 1 (projections): weight block Wqb..Wgb is one contiguous
    // [9216][2048] bf16 matrix (order q,k,v,g).
    unsigned short* xb  = bf;                                   // ROWS*HID
    unsigned short* Wqb = xb  + (size_t)ROWS * HID;
    // phase R (chunked recurrence) — aliases phase 1 (dead by then)
    unsigned short* qb    = bf;                                 // NG*TT*DK
    unsigned short* kb    = qb  + (size_t)NG*TT*DK;
    unsigned short* bvb   = kb  + (size_t)NG*TT*DK;             // NG*TT*DV
    unsigned short* Ab    = bvb + (size_t)NG*TT*DV;             // NG*TT*TT
    unsigned short* Utb   = Ab  + (size_t)NG*TT*TT;             // NG*TT*TT (transposed)
    unsigned short* Minvb = Utb + (size_t)NG*TT*TT;             // NG*8*64*64
    // phase 2 (output projection): ob aliases qb+kb (dead after o_kern);
    // Wob aliases bvb (dead after usolve).
    unsigned short* ob  = bf;                                   // ROWS*VAL_DIM
    unsigned short* Wob = bvb;                                  // HID*VAL_DIM

    dim3 blk(256);
    auto cblocks = [](size_t n) { size_t b = (n / 4 + 255) / 256; return (int)(b > 4096 ? 4096 : b); };

    // fused cast: x|Wq|Wk|Wv|Wg -> contiguous bf16 block at xb
    Cast5 c5;
    c5.src[0] = x;  c5.src[1] = Wq; c5.src[2] = Wk; c5.src[3] = Wv; c5.src[4] = Wg;
    c5.start4[0] = 0;
    c5.start4[1] = c5.start4[0] + ROWS*HID/4;
    c5.start4[2] = c5.start4[1] + KEY_DIM*HID/4;
    c5.start4[3] = c5.start4[2] + KEY_DIM*HID/4;
    c5.start4[4] = c5.start4[3] + VAL_DIM*HID/4;
    c5.start4[5] = c5.start4[4] + VAL_DIM*HID/4;
    cast_multi<<<dim3(2048), blk, 0, stream>>>(c5, xb);

    // fused q|k|v|gate projection: N=9216 -> 72x16 = 1152 blocks
    gemm_nt_bf16<<<dim3(QKVG/128, ROWS/128), blk, 0, stream>>>(xb, Wqb, qkvg, ROWS, QKVG, HID);
    proj_ab<<<dim3(ROWS, 12), dim3(64), 0, stream>>>(x, Wa, Wb, A_log, dtb, beta, graw);

    prep_norm<<<dim3(ROWS), blk, 0, stream>>>(qkvg, decay, Dp, beta, qb, kb, bvb);
    cumsum_pack<<<dim3(NG), dim3(64), 0, stream>>>(graw, beta, cinc, cexc, barr);
    a_mat<<<dim3(NG*36), blk, 0, stream>>>(kb, cinc, cexc, barr, Ab);
    minv_kern<<<dim3(NG*8), dim3(64), 0, stream>>>(Ab, Minvb);
    usolve<<<dim3(NG*8), blk, 0, stream>>>(Ab, Minvb, bvb, Utb);
    o_kern<<<dim3(NG*16), blk, 0, stream>>>(qb, kb, Utb, cinc, qkvg);
    epilogue<<<dim3(ROWS), blk, 0, stream>>>(qkvg, onw, ob);

    cast_f32_bf16<<<cblocks((size_t)HID*VAL_DIM), blk, 0, stream>>>(Wo, Wob, HID*VAL_DIM/4);
    gemm_nt_bf16<<<dim3(HID/128, ROWS/128), blk, 0, stream>>>(ob, Wob, out, ROWS, HID, VAL_DIM);
}